// Round 10
// baseline (633.636 us; speedup 1.0000x reference)
//
#include <hip/hip_runtime.h>
#include <hip/hip_bf16.h>

// ---------------------------------------------------------------------------
// DeltaNet forward, round 17:
//  - Base: r16 (chain + FIR + convT + x->gin copy + v-stats all in one grid).
//  - ONE change: delta_fir's static LDS raised 72704 -> 86016 bytes so only
//    ONE block fits per CU (2x86016 > 160KiB). r16's +11us chain regression
//    is hypothesized to be shadow blocks co-residing on chain CUs (2 blocks
//    of 72704 fit in 160KiB) and stealing issue slots; exclusivity restores
//    the chain's private CUs while shadow work sequences through the rest.
//    Zero math change.
// ---------------------------------------------------------------------------

#define DEVI __device__ __forceinline__
typedef unsigned int u32;
typedef unsigned short ushort_t;
typedef __attribute__((ext_vector_type(8))) short short8;
typedef __attribute__((ext_vector_type(4))) float floatx4;

constexpr int Ls = 2048, NH = 4;

// workspace offsets (floats)
constexpr size_t off_xq   = 0;         // x3 [m][3072] cols 0-1023 -> kn_bf -> firs
constexpr size_t off_xk   = 4194304;   // x3 cols 1024-2047 -> firl
constexpr size_t off_xv   = 8388608;   // x3 cols 2048-3071 -> u -> o_bf
constexpr size_t off_q    = 12582912;  // qn -> delta
constexpr size_t off_k    = 16777216;  // kn (dead after chunk_prep) -> w1_t
constexpr size_t off_v    = 20971520;  // v (alive to the end)
constexpr size_t off_beta = 25165824;  // beta (dead after conv_prep)
constexpr size_t off_attn = 25182208;  // attn (read by chain)
constexpr size_t off_firs = 25706496;  // x_bf -> {wn_bf, q_bf} (bf16)
constexpr size_t off_firl = 29900800;  // Wqkv_t -> knT_bf (bf16)
constexpr size_t off_gin  = 34095104;  // kb (f32) -> gin_bf (partial during chain)
constexpr size_t off_mlph = 38420480;  // vb (f32) -> mlph_bf
constexpr size_t off_wot  = 42614784;  // Wo_t (bf16, 0.52M fl) - never-aliased
constexpr size_t off_xy   = 43139072;  // X_g (262144) + Y_g (262144) - never-aliased
constexpr size_t off_gates= 46809088;  // gates

DEVI float sigmoidf_(float x) { return 1.f / (1.f + expf(-x)); }
DEVI float siluf_(float x) { return x / (1.f + expf(-x)); }
DEVI float geluf_(float x) { return 0.5f * x * (1.f + erff(x * 0.7071067811865476f)); }
DEVI ushort_t f2bf(float f) {
  union { float f; u32 u; } c{f};
  u32 r = (c.u + 0x7fffu + ((c.u >> 16) & 1u)) >> 16;
  return (ushort_t)r;
}
DEVI float bf2f(ushort_t h) {
  union { u32 u; float f; } c; c.u = ((u32)h) << 16; return c.f;
}
DEVI void cvt8(float4 a, float4 b, short8& hi, short8& lo) {
  float f[8] = {a.x,a.y,a.z,a.w,b.x,b.y,b.z,b.w};
#pragma unroll
  for (int j = 0; j < 8; ++j) {
    ushort_t h = f2bf(f[j]);
    hi[j] = (short)h;
    lo[j] = (short)f2bf(f[j] - bf2f(h));
  }
}
DEVI void async16(const void* g, void* l) {
  __builtin_amdgcn_global_load_lds(
      (const u32 __attribute__((address_space(1)))*)g,
      (u32 __attribute__((address_space(3)))*)l, 16, 0, 0);
}
// Raw workgroup barrier: waits LDS ops only (lgkmcnt), leaves global
// loads/stores (vmcnt) in flight. All cross-wave deps in the chain loop are
// LDS-only, and global data has no in-kernel consumers.
DEVI void wave_barrier() {
  __builtin_amdgcn_sched_barrier(0);
  asm volatile("s_waitcnt lgkmcnt(0)" ::: "memory");
  __builtin_amdgcn_s_barrier();
  __builtin_amdgcn_sched_barrier(0);
}

// ---------------- f32 -> bf16 ----------------------------------------------
__global__ __launch_bounds__(256) void to_bf16(
    const float* __restrict__ in, ushort_t* __restrict__ out, int n)
{
  int i = (blockIdx.x * 256 + threadIdx.x) * 8;
  if (i >= n) return;
  float4 a = *(const float4*)(in + i);
  float4 b = *(const float4*)(in + i + 4);
  ushort_t o[8] = { f2bf(a.x), f2bf(a.y), f2bf(a.z), f2bf(a.w),
                    f2bf(b.x), f2bf(b.y), f2bf(b.z), f2bf(b.w) };
  *(uint4*)(out + i) = *(uint4*)o;
}

// ---------------- f32 [K][N] -> bf16 [N][K] --------------------------------
__global__ __launch_bounds__(256) void convT(
    const float* __restrict__ W, ushort_t* __restrict__ out, int Kq, int Nq)
{
  __shared__ ushort_t tile[32][33];
  int n0 = blockIdx.x * 32, k0 = blockIdx.y * 32;
  int tx = threadIdx.x & 31, ty = threadIdx.x >> 5;
#pragma unroll
  for (int r = 0; r < 32; r += 8)
    tile[ty + r][tx] = f2bf(W[(size_t)(k0 + ty + r) * Nq + n0 + tx]);
  __syncthreads();
#pragma unroll
  for (int r = 0; r < 32; r += 8)
    out[(size_t)(n0 + ty + r) * Kq + k0 + tx] = tile[tx][ty + r];
}

// ---------------- bf16 MFMA GEMM -------------------------------------------
__global__ __launch_bounds__(256) void gemm_bf16(
    const ushort_t* __restrict__ A, const ushort_t* __restrict__ Bt,
    float* __restrict__ C, int Nq, int Kq,
    const float* __restrict__ bias, int act, int outbf)
{
  __shared__ ushort_t As[128 * 32];
  __shared__ ushort_t Bs[128 * 32];
  int t = threadIdx.x;
  int w = t >> 6, lane = t & 63;
  int m0 = blockIdx.y * 128, n0 = blockIdx.x * 128;
  floatx4 acc[4][4];
#pragma unroll
  for (int i = 0; i < 4; ++i)
#pragma unroll
    for (int j = 0; j < 4; ++j)
#pragma unroll
      for (int r = 0; r < 4; ++r) acc[i][j][r] = 0.f;

  int lrow = lane >> 2, lk8 = (lane & 3) * 8;
  for (int kt = 0; kt < Kq; kt += 32) {
#pragma unroll
    for (int r = 0; r < 2; ++r) {
      int seg = w * 2 + r;
      int row = seg * 16 + lrow;
      async16(A  + (size_t)(m0 + row) * Kq + kt + lk8, &As[seg * 512]);
      async16(Bt + (size_t)(n0 + row) * Kq + kt + lk8, &Bs[seg * 512]);
    }
    __syncthreads();
    short8 af[4], bf[4];
#pragma unroll
    for (int i = 0; i < 4; ++i) {
      int row = (w >> 1) * 64 + i * 16 + (lane & 15);
      af[i] = *(const short8*)&As[row * 32 + (lane >> 4) * 8];
    }
#pragma unroll
    for (int j = 0; j < 4; ++j) {
      int col = (w & 1) * 64 + j * 16 + (lane & 15);
      bf[j] = *(const short8*)&Bs[col * 32 + (lane >> 4) * 8];
    }
#pragma unroll
    for (int i = 0; i < 4; ++i)
#pragma unroll
      for (int j = 0; j < 4; ++j)
        acc[i][j] = __builtin_amdgcn_mfma_f32_16x16x32_bf16(af[i], bf[j], acc[i][j], 0, 0, 0);
    __syncthreads();
  }
#pragma unroll
  for (int i = 0; i < 4; ++i) {
    int rbase = m0 + (w >> 1) * 64 + i * 16 + ((lane >> 4) << 2);
#pragma unroll
    for (int j = 0; j < 4; ++j) {
      int col = n0 + (w & 1) * 64 + j * 16 + (lane & 15);
      float bv = act ? bias[col] : 0.f;
#pragma unroll
      for (int r = 0; r < 4; ++r) {
        float v = acc[i][j][r];
        if (act) v = geluf_(v + bv);
        if (outbf) ((ushort_t*)C)[(size_t)(rbase + r) * Nq + col] = f2bf(v);
        else       C[(size_t)(rbase + r) * Nq + col] = v;
      }
    }
  }
}

// ---------------- beta = sigmoid(x @ Wb) -----------------------------------
__global__ __launch_bounds__(256) void beta_sigmoid(
    const float* __restrict__ x, const float* __restrict__ Wb,
    float* __restrict__ beta)
{
  int mtok = blockIdx.x, t = threadIdx.x;
  int b = mtok >> 11, l = mtok & 2047;
  float a0 = 0, a1 = 0, a2 = 0, a3 = 0;
  for (int k = t; k < 1024; k += 256) {
    float xv = x[(size_t)mtok * 1024 + k];
    float4 w4 = *(const float4*)(Wb + k * 4);
    a0 = fmaf(xv, w4.x, a0); a1 = fmaf(xv, w4.y, a1);
    a2 = fmaf(xv, w4.z, a2); a3 = fmaf(xv, w4.w, a3);
  }
#pragma unroll
  for (int off = 32; off; off >>= 1) {
    a0 += __shfl_down(a0, off); a1 += __shfl_down(a1, off);
    a2 += __shfl_down(a2, off); a3 += __shfl_down(a3, off);
  }
  __shared__ float red[4][4];
  int w = t >> 6;
  if ((t & 63) == 0) { red[w][0] = a0; red[w][1] = a1; red[w][2] = a2; red[w][3] = a3; }
  __syncthreads();
  if (t < 4) {
    float s = red[0][t] + red[1][t] + red[2][t] + red[3][t];
    beta[((size_t)(b * NH + t)) * Ls + l] = sigmoidf_(s);
  }
}

// ------- fused conv4+silu (from fused x3 [m][3072]) + l2norm + beta --------
__global__ __launch_bounds__(256) void conv_prep(
    const float* __restrict__ x3, const float* __restrict__ wq,
    const float* __restrict__ wk, const float* __restrict__ wv,
    const float* __restrict__ beta_g,
    float* __restrict__ qn, float* __restrict__ kn,
    float* __restrict__ kb, float* __restrict__ vb,
    float* __restrict__ v_out)
{
  int i = blockIdx.x;              // bh*Ls + l
  int t = threadIdx.x;
  int l = i & 2047, bh = i >> 11;
  int b = bh >> 2, h = bh & 3;
  int c = h * 256 + t;
  const float* p = x3 + ((size_t)b * Ls) * 3072 + c;
  float4 wq4 = *(const float4*)(wq + c * 4);
  float4 wk4 = *(const float4*)(wk + c * 4);
  float4 wv4 = *(const float4*)(wv + c * 4);
  float qw[4] = {wq4.x, wq4.y, wq4.z, wq4.w};
  float kw[4] = {wk4.x, wk4.y, wk4.z, wk4.w};
  float vw[4] = {wv4.x, wv4.y, wv4.z, wv4.w};
  float aq = 0.f, ak = 0.f, av = 0.f;
#pragma unroll
  for (int j = 0; j < 4; ++j) {
    int ls = l - 3 + j;
    if (ls >= 0) {
      size_t rb = (size_t)ls * 3072;
      aq = fmaf(qw[j], p[rb], aq);
      ak = fmaf(kw[j], p[rb + 1024], ak);
      av = fmaf(vw[j], p[rb + 2048], av);
    }
  }
  float qv = siluf_(aq), kv = siluf_(ak), vv = siluf_(av);
  float sq = qv * qv, sk = kv * kv;
#pragma unroll
  for (int off = 32; off; off >>= 1) {
    sq += __shfl_down(sq, off);
    sk += __shfl_down(sk, off);
  }
  __shared__ float rq_[4], rk_[4];
  int w = t >> 6;
  if ((t & 63) == 0) { rq_[w] = sq; rk_[w] = sk; }
  __syncthreads();
  sq = rq_[0] + rq_[1] + rq_[2] + rq_[3];
  sk = rk_[0] + rk_[1] + rk_[2] + rk_[3];
  float rq = rsqrtf(sq + 1e-6f), rk = rsqrtf(sk + 1e-6f);
  float bt = beta_g[i];
  size_t base = (size_t)i * 256 + t;
  qn[base] = qv * rq;
  kn[base] = kv * rk;
  kb[base] = kv * rk * bt;
  vb[base] = vv * bt;
  v_out[base] = vv;
}

// ------- per (b,h,chunk) MFMA: Gram, substitution, w/u applies -------------
__global__ __launch_bounds__(256) void chunk_prep(
    const float* __restrict__ kb, const float* __restrict__ kn,
    const float* __restrict__ qn, const float* __restrict__ vb,
    float* __restrict__ attn_g, float* __restrict__ u_out,
    ushort_t* __restrict__ wn_bf, ushort_t* __restrict__ q_bf,
    ushort_t* __restrict__ knT_bf, ushort_t* __restrict__ kn_bf)
{
  __shared__ float Am[32][33];
  __shared__ float Tm[32][36];
  __shared__ ushort_t KT_hi[256][40];
  __shared__ ushort_t KT_lo[256][40];
  int t = threadIdx.x;
  int cc = blockIdx.x & 63, bh = blockIdx.x >> 6;
  size_t gbase = ((size_t)bh * Ls + cc * 32) * 256;
  int wv = t >> 6, lane = t & 63;
  int l16 = lane & 15, quad = lane >> 4;
  int mi = wv >> 1, ni = wv & 1;

  floatx4 Aacc = {0.f,0.f,0.f,0.f}, Qacc = {0.f,0.f,0.f,0.f};
  {
    int mrow = mi * 16 + l16, nrow = ni * 16 + l16;
    const float* kbp = kb + gbase + (size_t)mrow * 256;
    const float* qnp = qn + gbase + (size_t)mrow * 256;
    const float* knp = kn + gbase + (size_t)nrow * 256;
#pragma unroll
    for (int ks = 0; ks < 8; ++ks) {
      int koff = ks * 32 + quad * 8;
      short8 kbh, kbl, qnh, qnl, knh, knl;
      cvt8(*(const float4*)(kbp + koff), *(const float4*)(kbp + koff + 4), kbh, kbl);
      cvt8(*(const float4*)(qnp + koff), *(const float4*)(qnp + koff + 4), qnh, qnl);
      cvt8(*(const float4*)(knp + koff), *(const float4*)(knp + koff + 4), knh, knl);
      Aacc = __builtin_amdgcn_mfma_f32_16x16x32_bf16(kbh, knh, Aacc, 0, 0, 0);
      Aacc = __builtin_amdgcn_mfma_f32_16x16x32_bf16(kbh, knl, Aacc, 0, 0, 0);
      Aacc = __builtin_amdgcn_mfma_f32_16x16x32_bf16(kbl, knh, Aacc, 0, 0, 0);
      Qacc = __builtin_amdgcn_mfma_f32_16x16x32_bf16(qnh, knh, Qacc, 0, 0, 0);
      Qacc = __builtin_amdgcn_mfma_f32_16x16x32_bf16(qnh, knl, Qacc, 0, 0, 0);
      Qacc = __builtin_amdgcn_mfma_f32_16x16x32_bf16(qnl, knh, Qacc, 0, 0, 0);
      if (ni == 0)
        *(uint4*)(q_bf + gbase + (size_t)mrow * 256 + koff) = *(uint4*)&qnh;
      if (mi == 0)
        *(uint4*)(kn_bf + gbase + (size_t)nrow * 256 + koff) = *(uint4*)&knh;
    }
  }
  float* ag = attn_g + ((size_t)bh * 64 + cc) * 1024;
#pragma unroll
  for (int r = 0; r < 4; ++r) {
    int row = mi * 16 + quad * 4 + r, col = ni * 16 + l16;
    Am[row][col] = (col < row) ? Aacc[r] : 0.f;
    ag[row * 32 + col] = (col <= row) ? Qacc[r] : 0.f;
  }
  __syncthreads();

  if (wv == 0) {
    if (t < 32) {
#pragma unroll
      for (int i = 0; i < 32; ++i) Tm[i][t] = (i == t) ? 1.f : 0.f;
      for (int i2 = 1; i2 < 32; ++i2) {
        if (t < i2) {
          float s = 0.f;
          for (int m2 = t; m2 < i2; ++m2) s = fmaf(Am[i2][m2], Tm[m2][t], s);
          Tm[i2][t] = -s;
        }
      }
    }
  } else {
    int base = t - 64;
#pragma unroll
    for (int pass = 0; pass < 2; ++pass) {
      int d = base + pass * 192;
      if (d < 256) {
        u32 hp[16], lp[16], kp2[16];
#pragma unroll
        for (int m2 = 0; m2 < 16; ++m2) {
          float f0 = kb[gbase + (size_t)(2 * m2) * 256 + d];
          float f1 = kb[gbase + (size_t)(2 * m2 + 1) * 256 + d];
          ushort_t h0 = f2bf(f0), h1 = f2bf(f1);
          hp[m2] = (u32)h0 | ((u32)h1 << 16);
          lp[m2] = (u32)f2bf(f0 - bf2f(h0)) | ((u32)f2bf(f1 - bf2f(h1)) << 16);
          float g0 = kn[gbase + (size_t)(2 * m2) * 256 + d];
          float g1 = kn[gbase + (size_t)(2 * m2 + 1) * 256 + d];
          kp2[m2] = (u32)f2bf(g0) | ((u32)f2bf(g1) << 16);
        }
#pragma unroll
        for (int q2 = 0; q2 < 4; ++q2) {
          *(uint4*)&KT_hi[d][q2 * 8] = *(uint4*)&hp[q2 * 4];
          *(uint4*)&KT_lo[d][q2 * 8] = *(uint4*)&lp[q2 * 4];
          *(uint4*)(knT_bf + gbase + (size_t)d * 32 + q2 * 8) = *(uint4*)&kp2[q2 * 4];
        }
      }
    }
  }
  __syncthreads();

  int lt = wv & 1, dgrp = wv >> 1;
  short8 Th, Tl;
  {
    int lrow = lt * 16 + l16;
    cvt8(*(const float4*)&Tm[lrow][quad * 8],
         *(const float4*)&Tm[lrow][quad * 8 + 4], Th, Tl);
  }
#pragma unroll
  for (int j = 0; j < 8; ++j) {
    int dt = dgrp * 8 + j;
    short8 Bh = *(const short8*)&KT_hi[dt * 16 + l16][quad * 8];
    short8 Bl = *(const short8*)&KT_lo[dt * 16 + l16][quad * 8];
    floatx4 acc = {0.f,0.f,0.f,0.f};
    acc = __builtin_amdgcn_mfma_f32_16x16x32_bf16(Th, Bh, acc, 0, 0, 0);
    acc = __builtin_amdgcn_mfma_f32_16x16x32_bf16(Th, Bl, acc, 0, 0, 0);
    acc = __builtin_amdgcn_mfma_f32_16x16x32_bf16(Tl, Bh, acc, 0, 0, 0);
#pragma unroll
    for (int r = 0; r < 4; ++r) {
      int row = lt * 16 + quad * 4 + r;
      wn_bf[gbase + (size_t)row * 256 + dt * 16 + l16] = f2bf(-acc[r]);
    }
  }
  __syncthreads();

  {
    int d = t;
    u32 hp[16], lp[16];
#pragma unroll
    for (int m2 = 0; m2 < 16; ++m2) {
      float f0 = vb[gbase + (size_t)(2 * m2) * 256 + d];
      float f1 = vb[gbase + (size_t)(2 * m2 + 1) * 256 + d];
      ushort_t h0 = f2bf(f0), h1 = f2bf(f1);
      hp[m2] = (u32)h0 | ((u32)h1 << 16);
      lp[m2] = (u32)f2bf(f0 - bf2f(h0)) | ((u32)f2bf(f1 - bf2f(h1)) << 16);
    }
#pragma unroll
    for (int q2 = 0; q2 < 4; ++q2) {
      *(uint4*)&KT_hi[d][q2 * 8] = *(uint4*)&hp[q2 * 4];
      *(uint4*)&KT_lo[d][q2 * 8] = *(uint4*)&lp[q2 * 4];
    }
  }
  __syncthreads();

#pragma unroll
  for (int j = 0; j < 8; ++j) {
    int dt = dgrp * 8 + j;
    short8 Bh = *(const short8*)&KT_hi[dt * 16 + l16][quad * 8];
    short8 Bl = *(const short8*)&KT_lo[dt * 16 + l16][quad * 8];
    floatx4 acc = {0.f,0.f,0.f,0.f};
    acc = __builtin_amdgcn_mfma_f32_16x16x32_bf16(Th, Bh, acc, 0, 0, 0);
    acc = __builtin_amdgcn_mfma_f32_16x16x32_bf16(Th, Bl, acc, 0, 0, 0);
    acc = __builtin_amdgcn_mfma_f32_16x16x32_bf16(Tl, Bh, acc, 0, 0, 0);
#pragma unroll
    for (int r = 0; r < 4; ++r) {
      int row = lt * 16 + quad * 4 + r;
      u_out[gbase + (size_t)row * 256 + dt * 16 + l16] = acc[r];
    }
  }
}

// ------- cross matrices per super-chunk: X = wn1 @ kn0^T, Y = q1 @ kn0^T ---
__global__ __launch_bounds__(256) void cross_prep(
    const ushort_t* __restrict__ wn_bf, const ushort_t* __restrict__ q_bf,
    const ushort_t* __restrict__ kn_bf,
    float* __restrict__ X_g, float* __restrict__ Y_g)
{
  int t = threadIdx.x;
  int sc = blockIdx.x & 31, bh = blockIdx.x >> 5;
  int wv = t >> 6, lane = t & 63;
  int l16 = lane & 15, quad = lane >> 4;
  int mi = wv >> 1, ni = wv & 1;
  size_t base = (size_t)bh * Ls * 256;
  size_t r1 = base + (size_t)(sc * 64 + 32 + mi * 16 + l16) * 256;  // chunk 2sc+1 rows
  size_t r0 = base + (size_t)(sc * 64 + ni * 16 + l16) * 256;       // chunk 2sc rows
  floatx4 Xacc = {0.f,0.f,0.f,0.f}, Yacc = {0.f,0.f,0.f,0.f};
#pragma unroll
  for (int ks = 0; ks < 8; ++ks) {
    int ko = ks * 32 + quad * 8;
    short8 aw = *(const short8*)(wn_bf + r1 + ko);
    short8 aq = *(const short8*)(q_bf  + r1 + ko);
    short8 bk = *(const short8*)(kn_bf + r0 + ko);
    Xacc = __builtin_amdgcn_mfma_f32_16x16x32_bf16(aw, bk, Xacc, 0, 0, 0);
    Yacc = __builtin_amdgcn_mfma_f32_16x16x32_bf16(aq, bk, Yacc, 0, 0, 0);
  }
  float* xo = X_g + ((size_t)bh * 32 + sc) * 1024;
  float* yo = Y_g + ((size_t)bh * 32 + sc) * 1024;
#pragma unroll
  for (int r = 0; r < 4; ++r) {
    int row = mi * 16 + quad * 4 + r, col = ni * 16 + l16;
    xo[row * 32 + col] = Xacc[r];
    yo[row * 32 + col] = Yacc[r];
  }
}

// ------- merged: chain (0-127) + FIR (128-2175) + convT (2176-5311)
//         + x->gin copy (5312-9407) + v-stats (9408-13503) ------------------
// LDS = 86016 B so exactly ONE block per CU (2x would exceed 160KiB):
// shadow blocks can never co-reside with (and slow) a chain block.
__global__ __launch_bounds__(256, 1) void delta_fir(
    const ushort_t* __restrict__ wn_bf, const ushort_t* __restrict__ q_bf,
    const ushort_t* __restrict__ knT_bf, const float* __restrict__ attn_g,
    const float* __restrict__ u_g, const float* __restrict__ X_g,
    const float* __restrict__ Y_g, float* __restrict__ delta_g,
    const float* __restrict__ v, const float* __restrict__ wlg,
    const float* __restrict__ wsg, float* __restrict__ firl,
    float* __restrict__ firs,
    const float* __restrict__ mlpw1, ushort_t* __restrict__ w1_t,
    const float* __restrict__ Wo, ushort_t* __restrict__ wo_t,
    const float* __restrict__ x, ushort_t* __restrict__ gin)
{
  __shared__ __attribute__((aligned(16))) char smem[86016];
  int t = threadIdx.x;

  if (blockIdx.x >= 9408) {
    // -------- v branch stats (br==3) on idle CUs --------
    int mtok = blockIdx.x - 9408;
    int b = mtok >> 11, l = mtok & 2047;
    int w = t >> 6, lane = t & 63;
    float s = 0.f, s2 = 0.f;
#pragma unroll
    for (int r = 0; r < 4; ++r) {
      int d = lane + r * 64;
      float val = v[(((size_t)(b * NH + w)) * Ls + l) * 256 + d];
      s += val; s2 = fmaf(val, val, s2);
    }
#pragma unroll
    for (int off = 32; off; off >>= 1) {
      s += __shfl_down(s, off);
      s2 += __shfl_down(s2, off);
    }
    if (lane == 0) {
      float mean = s * (1.f / 256.f);
      float var = s2 * (1.f / 256.f) - mean * mean;
      gin[(size_t)mtok * 1056 + 1024 + 24 + w] = f2bf(mean);
      gin[(size_t)mtok * 1056 + 1024 + 28 + w] = f2bf(sqrtf(fmaxf(var, 1e-6f)));
    }
    return;
  }

  if (blockIdx.x >= 5312) {
    // -------- x -> gin bf16 copy on idle CUs --------
    int mtok = blockIdx.x - 5312;
    float4 xv = *(const float4*)(x + (size_t)mtok * 1024 + t * 4);
    ushort4 xo = make_ushort4(f2bf(xv.x), f2bf(xv.y), f2bf(xv.z), f2bf(xv.w));
    *(ushort4*)(gin + (size_t)mtok * 1056 + t * 4) = xo;
    return;
  }

  if (blockIdx.x >= 2176) {
    // -------- input-only weight transposes on idle CUs --------
    ushort_t (*tile)[33] = (ushort_t(*)[33])smem;
    const float* W; ushort_t* out; int Kq, Nq, n0, k0;
    if (blockIdx.x < 4288) {          // mlpw1 [1056][2048] -> w1_t [2048][1056]
      int local = blockIdx.x - 2176;  // 64 x 33
      W = mlpw1; out = w1_t; Kq = 1056; Nq = 2048;
      n0 = (local & 63) * 32; k0 = (local >> 6) * 32;
    } else {                          // Wo [1024][1024] -> wo_t [1024][1024]
      int local = blockIdx.x - 4288;  // 32 x 32
      W = Wo; out = wo_t; Kq = 1024; Nq = 1024;
      n0 = (local & 31) * 32; k0 = (local >> 5) * 32;
    }
    int tx = t & 31, ty = t >> 5;
#pragma unroll
    for (int r = 0; r < 32; r += 8)
      tile[ty + r][tx] = f2bf(W[(size_t)(k0 + ty + r) * Nq + n0 + tx]);
    __syncthreads();
#pragma unroll
    for (int r = 0; r < 32; r += 8)
      out[(size_t)(n0 + ty + r) * Kq + k0 + tx] = tile[tx][ty + r];
    return;
  }

  if (blockIdx.x >= 128) {
    // ---------------- FIR part ----------------
    float (*vt)[71] = (float(*)[71])smem;
    int bid = blockIdx.x - 128;
    int lt = bid & 255;
    int bh = bid >> 8;
    int b = bh >> 2, h = bh & 3;
    int l0 = lt * 8;
    const float* vp = v + (size_t)bh * Ls * 256;
    for (int r = 0; r < 70; ++r) {
      int ls = l0 - 62 + r;
      vt[t][r] = (ls >= 0) ? vp[(size_t)ls * 256 + t] : 0.f;
    }
    float TL[63], TS3[3];
#pragma unroll
    for (int j = 0; j < 63; ++j) TL[j] = wlg[((size_t)h * 256 + t) * 63 + j];
#pragma unroll
    for (int j = 0; j < 3; ++j) TS3[j] = wsg[((size_t)h * 256 + t) * 3 + j];
    __syncthreads();
    float aL[8] = {0,0,0,0,0,0,0,0}, aS[8] = {0,0,0,0,0,0,0,0};
#pragma unroll
    for (int r = 0; r < 70; ++r) {
      float vm = vt[t][r];
#pragma unroll
      for (int p = 0; p < 8; ++p) {
        int jl = r - p;
        if (jl >= 0 && jl < 63) aL[p] = fmaf(vm, TL[jl], aL[p]);
        int jssrc = r - 60 - p;
        if (jssrc >= 0 && jssrc < 3) aS[p] = fmaf(vm, TS3[jssrc], aS[p]);
      }
    }
#pragma unroll
    for (int p = 0; p < 8; ++p) {
      int l = l0 + p;
      size_t ob = (((size_t)b * Ls + l) * NH + h) * 256 + t;
      firl[ob] = aL[p];
      firs[ob] = aS[p];
    }
    return;
  }

  // ---------------- chain part (m=2 super-chunks) ----------------
  ushort_t (*Shi)[264] = (ushort_t(*)[264])(smem);
  ushort_t (*Slo)[264] = (ushort_t(*)[264])(smem + 8448);
  float (*u2L0)[17] = (float(*)[17])(smem + 16896);
  float (*u2L1)[17] = (float(*)[17])(smem + 19072);
  int bh = blockIdx.x & 7, g = blockIdx.x >> 3;
  int b = bh >> 2, h = bh & 3;
  int wv = t >> 6, lane = t & 63;
  int lquad = lane >> 4, l16 = lane & 15;
  int j0 = g * 16;
  int Mt = wv & 1;
  bool isU = (wv < 2);
  const ushort_t* wp = wn_bf + (size_t)bh * Ls * 256;
  const ushort_t* qp = q_bf  + (size_t)bh * Ls * 256;
  const ushort_t* ap = (isU ? wp : qp) + (size_t)(Mt * 16 + l16) * 256;
  const ushort_t* kr = knT_bf + (size_t)bh * Ls * 256 + (size_t)l16 * 32 + lquad * 8;
  const float* urow = u_g + (size_t)bh * Ls * 256
                    + (size_t)(Mt * 16 + lquad * 4) * 256 + j0 + l16;
  const float* arp = attn_g + (size_t)bh * 64 * 1024
                   + (size_t)(Mt * 16 + l16) * 32 + lquad * 8;
  const float* xrp = (isU ? X_g : Y_g) + (size_t)bh * 32768
                   + (size_t)(Mt * 16 + l16) * 32 + lquad * 8;

  floatx4 Sacc[4], SaccL[4];
#pragma unroll
  for (int i = 0; i < 4; ++i)
#pragma unroll
    for (int r = 0; r < 4; ++r) { Sacc[i][r] = 0.f; SaccL[i][r] = 0.f; }
  for (int i = t; i < 4224; i += 256) ((u32*)smem)[i] = 0;

  // prologue: super-chunk 0, sub-chunk 0 operands
  short8 a0[8], k0[4];
  floatx4 u0 = {0.f, 0.f, 0.f, 0.f};
  float4 at0a = {0,0,0,0}, at0b = {0,0,0,0};
#pragma unroll
  for (int ks = 0; ks < 8; ++ks)
    a0[ks] = *(const short8*)(ap + ks * 32 + lquad * 8);
#pragma unroll
  for (int i = 0; i < 4; ++i)
    k0[i] = *(const short8*)(kr + (size_t)(wv * 4 + i) * 512);
  if (isU) {
#pragma unroll
    for (int r = 0; r < 4; ++r) u0[r] = urow[(size_t)r * 256];
  } else {
    at0a = *(const float4*)(arp);
    at0b = *(const float4*)(arp + 4);
  }
  wave_barrier();

  for (int sc = 0; sc < 32; ++sc) {
    size_t cb1 = (size_t)sc * 16384 + 8192;
    size_t nb0 = (size_t)(sc + 1) * 16384;
    bool hasN = (sc + 1 < 32);

    // sub-chunk1 operands + cross matrix (used mid-iteration; latency covered)
    short8 a1[8], k1[4];
    floatx4 u1 = {0.f, 0.f, 0.f, 0.f};
    float4 at1a = {0,0,0,0}, at1b = {0,0,0,0};
#pragma unroll
    for (int ks = 0; ks < 8; ++ks)
      a1[ks] = *(const short8*)(ap + cb1 + ks * 32 + lquad * 8);
#pragma unroll
    for (int i = 0; i < 4; ++i)
      k1[i] = *(const short8*)(kr + cb1 + (size_t)(wv * 4 + i) * 512);
    if (isU) {
#pragma unroll
      for (int r = 0; r < 4; ++r) u1[r] = urow[cb1 + (size_t)r * 256];
    } else {
      size_t na = (size_t)(2 * sc + 1) * 1024;
      at1a = *(const float4*)(arp + na);
      at1b = *(const float4*)(arp + na + 4);
    }
    float4 xa = *(const float4*)(xrp + (size_t)sc * 1024);
    float4 xb = *(const float4*)(xrp + (size_t)sc * 1024 + 4);

    // ---- sub-chunk 0: u2_0 (isU) / po_0 (o) against S0 ----
    floatx4 acc0;
    if (isU) {
      floatx4 A0 = u0, A1 = {0,0,0,0}, A2 = {0,0,0,0}, A3 = {0,0,0,0};
#pragma unroll
      for (int ks = 0; ks < 8; ++ks) {
        short8 sh = *(const short8*)&Shi[l16][ks * 32 + lquad * 8];
        short8 sl = *(const short8*)&Slo[l16][ks * 32 + lquad * 8];
        if (ks & 1) {
          A1 = __builtin_amdgcn_mfma_f32_16x16x32_bf16(a0[ks], sh, A1, 0, 0, 0);
          A3 = __builtin_amdgcn_mfma_f32_16x16x32_bf16(a0[ks], sl, A3, 0, 0, 0);
        } else {
          A0 = __builtin_amdgcn_mfma_f32_16x16x32_bf16(a0[ks], sh, A0, 0, 0, 0);
          A2 = __builtin_amdgcn_mfma_f32_16x16x32_bf16(a0[ks], sl, A2, 0, 0, 0);
        }
      }
#pragma unroll
      for (int r = 0; r < 4; ++r) acc0[r] = (A0[r] + A1[r]) + (A2[r] + A3[r]);
#pragma unroll
      for (int r = 0; r < 4; ++r)
        u2L0[Mt * 16 + lquad * 4 + r][l16] = acc0[r];
    } else {
      floatx4 A0 = {0,0,0,0}, A1 = {0,0,0,0};
#pragma unroll
      for (int ks = 0; ks < 8; ++ks) {
        short8 sh = *(const short8*)&Shi[l16][ks * 32 + lquad * 8];
        if (ks & 1) A1 = __builtin_amdgcn_mfma_f32_16x16x32_bf16(a0[ks], sh, A1, 0, 0, 0);
        else        A0 = __builtin_amdgcn_mfma_f32_16x16x32_bf16(a0[ks], sh, A0, 0, 0, 0);
      }
#pragma unroll
      for (int r = 0; r < 4; ++r) acc0[r] = A0[r] + A1[r];
    }
    // prefetch next-super-chunk a0 (a0 regs dead; stays in flight across
    // the raw barriers below -> ~full iteration of latency cover)
    if (hasN) {
#pragma unroll
      for (int ks = 0; ks < 8; ++ks)
        a0[ks] = *(const short8*)(ap + nb0 + ks * 32 + lquad * 8);
    }
    wave_barrier();                          // u2_0 visible

    short8 uh0, ul0;
#pragma unroll
    for (int j = 0; j < 8; ++j) {
      float f = u2L0[lquad * 8 + j][l16];
      ushort_t hi = f2bf(f);
      uh0[j] = (short)hi;
      ul0[j] = (short)f2bf(f - bf2f(hi));
    }
#pragma unroll
    for (int i = 0; i < 4; ++i) {
      Sacc[i]  = __builtin_amdgcn_mfma_f32_16x16x32_bf16(k0[i], uh0, Sacc[i], 0, 0, 0);
      SaccL[i] = __builtin_amdgcn_mfma_f32_16x16x32_bf16(k0[i], ul0, SaccL[i], 0, 0, 0);
    }
    if (hasN) {
#pragma unroll
      for (int i = 0; i < 4; ++i)
        k0[i] = *(const short8*)(kr + nb0 + (size_t)(wv * 4 + i) * 512);
    }

    // ---- sub-chunk 1: u2_1 = u1 + wn1@S0 + X@u2_0 / o path ----
    floatx4 acc1;
    if (isU) {
      floatx4 A0 = u1, A1 = {0,0,0,0}, A2 = {0,0,0,0}, A3 = {0,0,0,0};
#pragma unroll
      for (int ks = 0; ks < 8; ++ks) {
        short8 sh = *(const short8*)&Shi[l16][ks * 32 + lquad * 8];
        short8 sl = *(const short8*)&Slo[l16][ks * 32 + lquad * 8];
        if (ks & 1) {
          A1 = __builtin_amdgcn_mfma_f32_16x16x32_bf16(a1[ks], sh, A1, 0, 0, 0);
          A3 = __builtin_amdgcn_mfma_f32_16x16x32_bf16(a1[ks], sl, A3, 0, 0, 0);
        } else {
          A0 = __builtin_amdgcn_mfma_f32_16x16x32_bf16(a1[ks], sh, A0, 0, 0, 0);
          A2 = __builtin_amdgcn_mfma_f32_16x16x32_bf16(a1[ks], sl, A2, 0, 0, 0);
        }
      }
      short8 Xh, Xl;
      cvt8(xa, xb, Xh, Xl);
      A0 = __builtin_amdgcn_mfma_f32_16x16x32_bf16(Xh, uh0, A0, 0, 0, 0);
      A1 = __builtin_amdgcn_mfma_f32_16x16x32_bf16(Xh, ul0, A1, 0, 0, 0);
      A2 = __builtin_amdgcn_mfma_f32_16x16x32_bf16(Xl, uh0, A2, 0, 0, 0);
#pragma unroll
      for (int r = 0; r < 4; ++r) acc1[r] = (A0[r] + A1[r]) + (A2[r] + A3[r]);
#pragma unroll
      for (int r = 0; r < 4; ++r)
        u2L1[Mt * 16 + lquad * 4 + r][l16] = acc1[r];
      if (hasN) {
#pragma unroll
        for (int r = 0; r < 4; ++r) u0[r] = urow[nb0 + (size_t)r * 256];
      }
    } else {
      // o_0 = po_0 + attn_0 @ u2_0 -> store
      short8 ath, atl;
      cvt8(at0a, at0b, ath, atl);
      acc0 = __builtin_amdgcn_mfma_f32_16x16x32_bf16(ath, uh0, acc0, 0, 0, 0);
      acc0 = __builtin_amdgcn_mfma_f32_16x16x32_bf16(ath, ul0, acc0, 0, 0, 0);
      acc0 = __builtin_amdgcn_mfma_f32_16x16x32_bf16(atl, uh0, acc0, 0, 0, 0);
#pragma unroll
      for (int r = 0; r < 4; ++r) {
        int l = sc * 64 + Mt * 16 + lquad * 4 + r;
        delta_g[(((size_t)b * Ls + l) * NH + h) * 256 + j0 + l16] = acc0[r];
      }
      // po_1 = q1 @ Shi(S0) + Y @ u2_0
      floatx4 A0 = {0,0,0,0}, A1 = {0,0,0,0};
#pragma unroll
      for (int ks = 0; ks < 8; ++ks) {
        short8 sh = *(const short8*)&Shi[l16][ks * 32 + lquad * 8];
        if (ks & 1) A1 = __builtin_amdgcn_mfma_f32_16x16x32_bf16(a1[ks], sh, A1, 0, 0, 0);
        else        A0 = __builtin_amdgcn_mfma_f32_16x16x32_bf16(a1[ks], sh, A0, 0, 0, 0);
      }
      short8 Yh, Yl;
      cvt8(xa, xb, Yh, Yl);
      A0 = __builtin_amdgcn_mfma_f32_16x16x32_bf16(Yh, uh0, A0, 0, 0, 0);
      A1 = __builtin_amdgcn_mfma_f32_16x16x32_bf16(Yh, ul0, A1, 0, 0, 0);
      A0 = __builtin_amdgcn_mfma_f32_16x16x32_bf16(Yl, uh0, A0, 0, 0, 0);
#pragma unroll
      for (int r = 0; r < 4; ++r) acc1[r] = A0[r] + A1[r];
      if (hasN) {
        size_t na0 = (size_t)(2 * sc + 2) * 1024;
        at0a = *(const float4*)(arp + na0);
        at0b = *(const float4*)(arp + na0 + 4);
      }
    }
    wave_barrier();                          // u2_1 visible; all Shi/Slo reads done

    short8 uh1, ul1;
#pragma unroll
    for (int j = 0; j < 8; ++j) {
      float f = u2L1[lquad * 8 + j][l16];
      ushort_t hi = f2bf(f);
      uh1[j] = (short)hi;
      ul1[j] = (short)f2bf(f - bf2f(hi));
    }
#pragma unroll
    for (int i = 0; i < 4; ++i) {
      Sacc[i]  = __builtin_amdgcn_mfma_f32_16x16x32_bf16(k1[i], uh1, Sacc[i], 0, 0, 0);
      SaccL[i] = __builtin_amdgcn_mfma_f32_16x16x32_bf16(k1[i], ul1, SaccL[i], 0, 0, 0);
    }
    if (!isU) {
      short8 ath, atl;
      cvt8(at1a, at1b, ath, atl);
      acc1 = __builtin_amdgcn_mfma_f32_16x16x32_bf16(ath, uh1, acc1, 0, 0, 0);
      acc1 = __builtin_amdgcn_mfma_f32_16x16x32_bf16(ath, ul1, acc1, 0, 0, 0);
      acc1 = __builtin_amdgcn_mfma_f32_16x16x32_bf16(atl, uh1, acc1, 0, 0, 0);
#pragma unroll
      for (int r = 0; r < 4; ++r) {
        int l = sc * 64 + 32 + Mt * 16 + lquad * 4 + r;
        delta_g[(((size_t)b * Ls + l) * NH + h) * 256 + j0 + l16] = acc1[r];
      }
    }
    // S write-back (once per 64 tokens)
#pragma unroll
    for (int i = 0; i < 4; ++i) {
      int dk0 = (wv * 4 + i) * 16 + lquad * 4;
      ushort4 h4, l4;
      ushort_t* hp = (ushort_t*)&h4;
      ushort_t* lp = (ushort_t*)&l4;
#pragma unroll
      for (int r = 0; r < 4; ++r) {
        float sv = Sacc[i][r] + SaccL[i][r];
        ushort_t hi = f2bf(sv);
        hp[r] = hi;
        lp[r] = f2bf(sv - bf2f(hi));
      }
      *(ushort4*)&Shi[l16][dk0] = h4;
      *(ushort4*)&Slo[l16][dk0] = l4;
    }
    wave_barrier();                          // S visible
  }
}

// ------- gate_in stats (firs/firl/delta branches only) ---------------------
__global__ __launch_bounds__(256) void build_gate_in_bf(
    const float* __restrict__ firs, const float* __restrict__ firl,
    const float* __restrict__ delta, ushort_t* __restrict__ gin)
{
  int mtok = blockIdx.x, t = threadIdx.x;
  int w = t >> 6, lane = t & 63;
  for (int br = 0; br < 3; ++br) {
    float s = 0.f, s2 = 0.f;
#pragma unroll
    for (int r = 0; r < 4; ++r) {
      int d = lane + r * 64;
      float val;
      if (br == 0)      val = firs [(size_t)mtok * 1024 + w * 256 + d];
      else if (br == 1) val = firl [(size_t)mtok * 1024 + w * 256 + d];
      else              val = delta[(size_t)mtok * 1024 + w * 256 + d];
      s += val; s2 = fmaf(val, val, s2);
    }
#pragma unroll
    for (int off = 32; off; off >>= 1) {
      s += __shfl_down(s, off);
      s2 += __shfl_down(s2, off);
    }
    if (lane == 0) {
      float mean = s * (1.f / 256.f);
      float var = s2 * (1.f / 256.f) - mean * mean;
      gin[(size_t)mtok * 1056 + 1024 + br * 8 + w] = f2bf(mean);
      gin[(size_t)mtok * 1056 + 1024 + br * 8 + 4 + w] = f2bf(sqrtf(fmaxf(var, 1e-6f)));
    }
  }
}

// ------- logits -> gates (bf16 hidden input) -------------------------------
__global__ __launch_bounds__(256) void mlp2_gates(
    const ushort_t* __restrict__ mh, const float* __restrict__ W2,
    const float* __restrict__ b2, const float* __restrict__ glt,
    float* __restrict__ gates)
{
  int mtok = blockIdx.x, t = threadIdx.x;
  float p[16];
#pragma unroll
  for (int j = 0; j < 16; ++j) p[j] = 0.f;
  for (int k = t; k < 2048; k += 256) {
    float hv = bf2f(mh[(size_t)mtok * 2048 + k]);
    const float* wr = W2 + (size_t)k * 16;
#pragma unroll
    for (int j4 = 0; j4 < 4; ++j4) {
      float4 w4 = *(const float4*)(wr + j4 * 4);
      p[j4*4+0] = fmaf(hv, w4.x, p[j4*4+0]);
      p[j4*4+1] = fmaf(hv, w4.y, p[j4*4+1]);
      p[j4*4+2] = fmaf(hv, w4.z, p[j4*4+2]);
      p[j4*4+3] = fmaf(hv, w4.w, p[j4*4+3]);
    }
  }
#pragma unroll
  for (int j = 0; j < 16; ++j)
#pragma unroll
    for (int off = 32; off; off >>= 1) p[j] += __shfl_down(p[j], off);
  __shared__ float red[4][16];
  __shared__ float zl[16];
  int w = t >> 6;
  if ((t & 63) == 0) {
#pragma unroll
    for (int j = 0; j < 16; ++j) red[w][j] = p[j];
  }
  __syncthreads();
  if (t < 16) {
    float tot = red[0][t] + red[1][t] + red[2][t] + red[3][t] + b2[t];
    float tempv = log1pf(expf(glt[t >> 2])) + 1e-4f;
    zl[t] = tot / tempv;
  }
  __syncthreads();
  if (t < 4) {
    float z0 = zl[t*4], z1 = zl[t*4+1], z2 = zl[t*4+2], z3 = zl[t*4+3];
    float mx = fmaxf(fmaxf(z0, z1), fmaxf(z2, z3));
    float e0 = expf(z0 - mx), e1 = expf(z1 - mx), e2 = expf(z2 - mx), e3 = expf(z3 - mx);
    float inv = 1.f / (e0 + e1 + e2 + e3);
    gates[(size_t)mtok * 16 + t * 4 + 0] = e0 * inv;
    gates[(size_t)mtok * 16 + t * 4 + 1] = e1 * inv;
    gates[(size_t)mtok * 16 + t * 4 + 2] = e2 * inv;
    gates[(size_t)mtok * 16 + t * 4 + 3] = e3 * inv;
  }
}

// ------- o = gated mix, RMSNorm -> bf16 ------------------------------------
__global__ __launch_bounds__(256) void combine_norm_bf(
    const float* __restrict__ firs, const float* __restrict__ firl,
    const float* __restrict__ delta, const float* __restrict__ v,
    const float* __restrict__ gates, const float* __restrict__ onw,
    ushort_t* __restrict__ o)
{
  int mh = blockIdx.x;
  int mtok = mh >> 2, h = mh & 3;
  int t = threadIdx.x;
  int b = mtok >> 11, l = mtok & 2047;
  const float* g = gates + (size_t)mtok * 16 + h * 4;
  float w0 = g[0], w1 = g[1], w2 = g[2], w3 = g[3];
  size_t tb = (size_t)mtok * 1024 + h * 256 + t;
  float val = w0 * firs[tb] + w1 * firl[tb] + w2 * delta[tb]
            + w3 * v[(((size_t)(b * NH + h)) * Ls + l) * 256 + t];
  float s2 = val * val;
#pragma unroll
  for (int off = 32; off; off >>= 1) s2 += __shfl_down(s2, off);
  __shared__ float r4[4];
  if ((t & 63) == 0) r4[t >> 6] = s2;
  __syncthreads();
  float tot = r4[0] + r4[1] + r4[2] + r4[3];
  float rms = rsqrtf(tot * (1.f / 256.f) + 1e-5f);
  o[tb] = f2bf(val * rms * onw[t]);
}

// ---------------------------------------------------------------------------
extern "C" void kernel_launch(void* const* d_in, const int* in_sizes, int n_in,
                              void* d_out, int out_size, void* d_ws, size_t ws_size,
                              hipStream_t stream) {
  const float* x     = (const float*)d_in[0];
  const float* Wq    = (const float*)d_in[1];
  const float* Wk    = (const float*)d_in[2];
  const float* Wv    = (const float*)d_in[3];
  const float* Wb    = (const float*)d_in[4];
  const float* convq = (const float*)d_in[5];
  const float* convk = (const float*)d_in[6];
  const float* convv = (const float*)d_in[7];
  const float* firsw = (const float*)d_in[8];
  const float* firlw = (const float*)d_in[9];
  const float* mlpw1 = (const float*)d_in[10];
  const float* mlpb1 = (const float*)d_in[11];
  const float* mlpw2 = (const float*)d_in[12];
  const float* mlpb2 = (const float*)d_in[13];
  const float* glt   = (const float*)d_in[14];
  const float* onw   = (const float*)d_in[15];
  const float* Wo    = (const float*)d_in[16];
  float* ws = (float*)d_ws;

  ushort_t* x_bf   = (ushort_t*)(ws + off_firs);
  ushort_t* Wqkv_t = (ushort_t*)(ws + off_firl);  // 3 x [1024][1024] contiguous
  ushort_t* gin_bf = (ushort_t*)(ws + off_gin);
  ushort_t* w1_t   = (ushort_t*)(ws + off_k);     // kn dead after chunk_prep
  ushort_t* o_bf   = (ushort_t*)(ws + off_xv);
  ushort_t* Wo_t   = (ushort_t*)(ws + off_wot);   // never-aliased window
  ushort_t* mlph_bf= (ushort_t*)(ws + off_mlph);
  ushort_t* wn_bf  = (ushort_t*)(ws + off_firs);
  ushort_t* q_bf   = (ushort_t*)(ws + off_firs + 2097152);
  ushort_t* knT_bf = (ushort_t*)(ws + off_firl);
  ushort_t* kn_bf  = (ushort_t*)(ws + off_xq);    // x3 dead after conv_prep
  float* x3   = ws + off_xq;     // fused [4096][3072] spans xq/xk/xv
  float* kb_f = ws + off_gin;
  float* vb_f = ws + off_mlph;
  float* X_g  = ws + off_xy;             // never-aliased (gin written during chain)
  float* Y_g  = ws + off_xy + 262144;
  float* firs_f = ws + off_xq;   // x3/kn_bf dead after cross_prep
  float* firl_f = ws + off_xk;

  dim3 blk(256);
  // fused q/k/v projection (one N=3072 GEMM) + beta
  to_bf16<<<2048, blk, 0, stream>>>(x, x_bf, 4194304);
  convT<<<dim3(32, 32), blk, 0, stream>>>(Wq, Wqkv_t, 1024, 1024);
  convT<<<dim3(32, 32), blk, 0, stream>>>(Wk, Wqkv_t + 1048576, 1024, 1024);
  convT<<<dim3(32, 32), blk, 0, stream>>>(Wv, Wqkv_t + 2097152, 1024, 1024);
  gemm_bf16<<<dim3(24, 32), blk, 0, stream>>>(x_bf, Wqkv_t, x3, 3072, 1024, nullptr, 0, 0);
  beta_sigmoid<<<4096, blk, 0, stream>>>(x, Wb, ws + off_beta);
  // fused conv4+silu + l2norm + beta products
  conv_prep<<<16384, blk, 0, stream>>>(x3, convq, convk, convv, ws + off_beta,
                                       ws + off_q, ws + off_k, kb_f, vb_f, ws + off_v);
  // per-chunk T inverse, attn, u (->xv), bf16 {-w, q, knT, kn}
  chunk_prep<<<512, blk, 0, stream>>>(kb_f, ws + off_k, ws + off_q, vb_f,
                                      ws + off_attn, ws + off_xv, wn_bf, q_bf,
                                      knT_bf, kn_bf);
  // 32x32 cross matrices per super-chunk (X = wn1 kn0^T, Y = q1 kn0^T)
  cross_prep<<<256, blk, 0, stream>>>(wn_bf, q_bf, kn_bf, X_g, Y_g);
  // merged: chain + FIR + weight transposes + x->gin copy + v-stats (shadow,
  // 1 block/CU enforced via LDS so shadow never co-resides with chain)
  delta_fir<<<13504, blk, 0, stream>>>(wn_bf, q_bf, knT_bf, ws + off_attn,
                                       ws + off_xv, X_g, Y_g, ws + off_q,
                                       ws + off_v, firlw, firsw, firl_f, firs_f,
                                       mlpw1, w1_t, Wo, Wo_t, x, gin_bf);
  // gate stats (firs/firl/delta), MLP1 (MFMA, gelu, bf16 out), gates
  build_gate_in_bf<<<4096, blk, 0, stream>>>(firs_f, firl_f, ws + off_q, gin_bf);
  gemm_bf16<<<dim3(16, 32), blk, 0, stream>>>(gin_bf, w1_t, (float*)mlph_bf,
                                              2048, 1056, mlpb1, 1, 1);
  mlp2_gates<<<4096, blk, 0, stream>>>(mlph_bf, mlpw2, mlpb2, glt, ws + off_gates);
  // combine + RMSNorm -> bf16, output projection (MFMA)
  combine_norm_bf<<<16384, blk, 0, stream>>>(firs_f, firl_f, ws + off_q,
                                             ws + off_v, ws + off_gates, onw, o_bf);
  gemm_bf16<<<dim3(8, 32), blk, 0, stream>>>(o_bf, Wo_t, (float*)d_out, 1024, 1024, nullptr, 0, 0);
}

// Round 11
// 616.546 us; speedup vs baseline: 1.0277x; 1.0277x over previous
//
#include <hip/hip_runtime.h>
#include <hip/hip_bf16.h>

// ---------------------------------------------------------------------------
// DeltaNet forward, round 18 (= r15, the measured best at 543.2us):
//  - r16 (x->gin + v-stats in shadow) cost +11us chain via HBM contention;
//    r17 (1 block/CU exclusivity) serialized the shadow (247us chain) and
//    disproved the co-residency hypothesis. Shadow-fill ledger: weight
//    transposes (~6MB) are free; bulk tensor traffic (~40MB) contends.
//  - This is r15 verbatim: chain (0-127) + FIR (128-2175) + mlpw1/Wo
//    transposes (2176-5311) in delta_fir's grid; all else as r8.
// ---------------------------------------------------------------------------

#define DEVI __device__ __forceinline__
typedef unsigned int u32;
typedef unsigned short ushort_t;
typedef __attribute__((ext_vector_type(8))) short short8;
typedef __attribute__((ext_vector_type(4))) float floatx4;

constexpr int Ls = 2048, NH = 4;

// workspace offsets (floats)
constexpr size_t off_xq   = 0;         // x3 [m][3072] cols 0-1023 -> kn_bf -> firs
constexpr size_t off_xk   = 4194304;   // x3 cols 1024-2047 -> firl
constexpr size_t off_xv   = 8388608;   // x3 cols 2048-3071 -> u -> o_bf
constexpr size_t off_q    = 12582912;  // qn -> delta
constexpr size_t off_k    = 16777216;  // kn (dead after chunk_prep) -> w1_t
constexpr size_t off_v    = 20971520;  // v (alive to the end)
constexpr size_t off_beta = 25165824;  // beta (dead after conv_prep)
constexpr size_t off_attn = 25182208;  // attn (read by chain)
constexpr size_t off_firs = 25706496;  // x_bf -> {wn_bf, q_bf} (bf16)
constexpr size_t off_firl = 29900800;  // Wqkv_t -> knT_bf (bf16)
constexpr size_t off_gin  = 34095104;  // kb (f32) -> {X_g, Y_g} -> gin_bf
constexpr size_t off_mlph = 38420480;  // vb (f32) -> mlph_bf
constexpr size_t off_wot  = 42614784;  // Wo_t (bf16, 0.52M fl) - never-aliased
constexpr size_t off_gates= 46809088;  // gates

DEVI float sigmoidf_(float x) { return 1.f / (1.f + expf(-x)); }
DEVI float siluf_(float x) { return x / (1.f + expf(-x)); }
DEVI float geluf_(float x) { return 0.5f * x * (1.f + erff(x * 0.7071067811865476f)); }
DEVI ushort_t f2bf(float f) {
  union { float f; u32 u; } c{f};
  u32 r = (c.u + 0x7fffu + ((c.u >> 16) & 1u)) >> 16;
  return (ushort_t)r;
}
DEVI float bf2f(ushort_t h) {
  union { u32 u; float f; } c; c.u = ((u32)h) << 16; return c.f;
}
DEVI void cvt8(float4 a, float4 b, short8& hi, short8& lo) {
  float f[8] = {a.x,a.y,a.z,a.w,b.x,b.y,b.z,b.w};
#pragma unroll
  for (int j = 0; j < 8; ++j) {
    ushort_t h = f2bf(f[j]);
    hi[j] = (short)h;
    lo[j] = (short)f2bf(f[j] - bf2f(h));
  }
}
DEVI void async16(const void* g, void* l) {
  __builtin_amdgcn_global_load_lds(
      (const u32 __attribute__((address_space(1)))*)g,
      (u32 __attribute__((address_space(3)))*)l, 16, 0, 0);
}
// Raw workgroup barrier: waits LDS ops only (lgkmcnt), leaves global
// loads/stores (vmcnt) in flight. All cross-wave deps in the chain loop are
// LDS-only, and global data has no in-kernel consumers.
DEVI void wave_barrier() {
  __builtin_amdgcn_sched_barrier(0);
  asm volatile("s_waitcnt lgkmcnt(0)" ::: "memory");
  __builtin_amdgcn_s_barrier();
  __builtin_amdgcn_sched_barrier(0);
}

// ---------------- f32 -> bf16 ----------------------------------------------
__global__ __launch_bounds__(256) void to_bf16(
    const float* __restrict__ in, ushort_t* __restrict__ out, int n)
{
  int i = (blockIdx.x * 256 + threadIdx.x) * 8;
  if (i >= n) return;
  float4 a = *(const float4*)(in + i);
  float4 b = *(const float4*)(in + i + 4);
  ushort_t o[8] = { f2bf(a.x), f2bf(a.y), f2bf(a.z), f2bf(a.w),
                    f2bf(b.x), f2bf(b.y), f2bf(b.z), f2bf(b.w) };
  *(uint4*)(out + i) = *(uint4*)o;
}

// ---------------- f32 [K][N] -> bf16 [N][K] --------------------------------
__global__ __launch_bounds__(256) void convT(
    const float* __restrict__ W, ushort_t* __restrict__ out, int Kq, int Nq)
{
  __shared__ ushort_t tile[32][33];
  int n0 = blockIdx.x * 32, k0 = blockIdx.y * 32;
  int tx = threadIdx.x & 31, ty = threadIdx.x >> 5;
#pragma unroll
  for (int r = 0; r < 32; r += 8)
    tile[ty + r][tx] = f2bf(W[(size_t)(k0 + ty + r) * Nq + n0 + tx]);
  __syncthreads();
#pragma unroll
  for (int r = 0; r < 32; r += 8)
    out[(size_t)(n0 + ty + r) * Kq + k0 + tx] = tile[tx][ty + r];
}

// ---------------- bf16 MFMA GEMM -------------------------------------------
__global__ __launch_bounds__(256) void gemm_bf16(
    const ushort_t* __restrict__ A, const ushort_t* __restrict__ Bt,
    float* __restrict__ C, int Nq, int Kq,
    const float* __restrict__ bias, int act, int outbf)
{
  __shared__ ushort_t As[128 * 32];
  __shared__ ushort_t Bs[128 * 32];
  int t = threadIdx.x;
  int w = t >> 6, lane = t & 63;
  int m0 = blockIdx.y * 128, n0 = blockIdx.x * 128;
  floatx4 acc[4][4];
#pragma unroll
  for (int i = 0; i < 4; ++i)
#pragma unroll
    for (int j = 0; j < 4; ++j)
#pragma unroll
      for (int r = 0; r < 4; ++r) acc[i][j][r] = 0.f;

  int lrow = lane >> 2, lk8 = (lane & 3) * 8;
  for (int kt = 0; kt < Kq; kt += 32) {
#pragma unroll
    for (int r = 0; r < 2; ++r) {
      int seg = w * 2 + r;
      int row = seg * 16 + lrow;
      async16(A  + (size_t)(m0 + row) * Kq + kt + lk8, &As[seg * 512]);
      async16(Bt + (size_t)(n0 + row) * Kq + kt + lk8, &Bs[seg * 512]);
    }
    __syncthreads();
    short8 af[4], bf[4];
#pragma unroll
    for (int i = 0; i < 4; ++i) {
      int row = (w >> 1) * 64 + i * 16 + (lane & 15);
      af[i] = *(const short8*)&As[row * 32 + (lane >> 4) * 8];
    }
#pragma unroll
    for (int j = 0; j < 4; ++j) {
      int col = (w & 1) * 64 + j * 16 + (lane & 15);
      bf[j] = *(const short8*)&Bs[col * 32 + (lane >> 4) * 8];
    }
#pragma unroll
    for (int i = 0; i < 4; ++i)
#pragma unroll
      for (int j = 0; j < 4; ++j)
        acc[i][j] = __builtin_amdgcn_mfma_f32_16x16x32_bf16(af[i], bf[j], acc[i][j], 0, 0, 0);
    __syncthreads();
  }
#pragma unroll
  for (int i = 0; i < 4; ++i) {
    int rbase = m0 + (w >> 1) * 64 + i * 16 + ((lane >> 4) << 2);
#pragma unroll
    for (int j = 0; j < 4; ++j) {
      int col = n0 + (w & 1) * 64 + j * 16 + (lane & 15);
      float bv = act ? bias[col] : 0.f;
#pragma unroll
      for (int r = 0; r < 4; ++r) {
        float v = acc[i][j][r];
        if (act) v = geluf_(v + bv);
        if (outbf) ((ushort_t*)C)[(size_t)(rbase + r) * Nq + col] = f2bf(v);
        else       C[(size_t)(rbase + r) * Nq + col] = v;
      }
    }
  }
}

// ---------------- beta = sigmoid(x @ Wb) -----------------------------------
__global__ __launch_bounds__(256) void beta_sigmoid(
    const float* __restrict__ x, const float* __restrict__ Wb,
    float* __restrict__ beta)
{
  int mtok = blockIdx.x, t = threadIdx.x;
  int b = mtok >> 11, l = mtok & 2047;
  float a0 = 0, a1 = 0, a2 = 0, a3 = 0;
  for (int k = t; k < 1024; k += 256) {
    float xv = x[(size_t)mtok * 1024 + k];
    float4 w4 = *(const float4*)(Wb + k * 4);
    a0 = fmaf(xv, w4.x, a0); a1 = fmaf(xv, w4.y, a1);
    a2 = fmaf(xv, w4.z, a2); a3 = fmaf(xv, w4.w, a3);
  }
#pragma unroll
  for (int off = 32; off; off >>= 1) {
    a0 += __shfl_down(a0, off); a1 += __shfl_down(a1, off);
    a2 += __shfl_down(a2, off); a3 += __shfl_down(a3, off);
  }
  __shared__ float red[4][4];
  int w = t >> 6;
  if ((t & 63) == 0) { red[w][0] = a0; red[w][1] = a1; red[w][2] = a2; red[w][3] = a3; }
  __syncthreads();
  if (t < 4) {
    float s = red[0][t] + red[1][t] + red[2][t] + red[3][t];
    beta[((size_t)(b * NH + t)) * Ls + l] = sigmoidf_(s);
  }
}

// ------- fused conv4+silu (from fused x3 [m][3072]) + l2norm + beta --------
__global__ __launch_bounds__(256) void conv_prep(
    const float* __restrict__ x3, const float* __restrict__ wq,
    const float* __restrict__ wk, const float* __restrict__ wv,
    const float* __restrict__ beta_g,
    float* __restrict__ qn, float* __restrict__ kn,
    float* __restrict__ kb, float* __restrict__ vb,
    float* __restrict__ v_out)
{
  int i = blockIdx.x;              // bh*Ls + l
  int t = threadIdx.x;
  int l = i & 2047, bh = i >> 11;
  int b = bh >> 2, h = bh & 3;
  int c = h * 256 + t;
  const float* p = x3 + ((size_t)b * Ls) * 3072 + c;
  float4 wq4 = *(const float4*)(wq + c * 4);
  float4 wk4 = *(const float4*)(wk + c * 4);
  float4 wv4 = *(const float4*)(wv + c * 4);
  float qw[4] = {wq4.x, wq4.y, wq4.z, wq4.w};
  float kw[4] = {wk4.x, wk4.y, wk4.z, wk4.w};
  float vw[4] = {wv4.x, wv4.y, wv4.z, wv4.w};
  float aq = 0.f, ak = 0.f, av = 0.f;
#pragma unroll
  for (int j = 0; j < 4; ++j) {
    int ls = l - 3 + j;
    if (ls >= 0) {
      size_t rb = (size_t)ls * 3072;
      aq = fmaf(qw[j], p[rb], aq);
      ak = fmaf(kw[j], p[rb + 1024], ak);
      av = fmaf(vw[j], p[rb + 2048], av);
    }
  }
  float qv = siluf_(aq), kv = siluf_(ak), vv = siluf_(av);
  float sq = qv * qv, sk = kv * kv;
#pragma unroll
  for (int off = 32; off; off >>= 1) {
    sq += __shfl_down(sq, off);
    sk += __shfl_down(sk, off);
  }
  __shared__ float rq_[4], rk_[4];
  int w = t >> 6;
  if ((t & 63) == 0) { rq_[w] = sq; rk_[w] = sk; }
  __syncthreads();
  sq = rq_[0] + rq_[1] + rq_[2] + rq_[3];
  sk = rk_[0] + rk_[1] + rk_[2] + rk_[3];
  float rq = rsqrtf(sq + 1e-6f), rk = rsqrtf(sk + 1e-6f);
  float bt = beta_g[i];
  size_t base = (size_t)i * 256 + t;
  qn[base] = qv * rq;
  kn[base] = kv * rk;
  kb[base] = kv * rk * bt;
  vb[base] = vv * bt;
  v_out[base] = vv;
}

// ------- per (b,h,chunk) MFMA: Gram, substitution, w/u applies -------------
__global__ __launch_bounds__(256) void chunk_prep(
    const float* __restrict__ kb, const float* __restrict__ kn,
    const float* __restrict__ qn, const float* __restrict__ vb,
    float* __restrict__ attn_g, float* __restrict__ u_out,
    ushort_t* __restrict__ wn_bf, ushort_t* __restrict__ q_bf,
    ushort_t* __restrict__ knT_bf, ushort_t* __restrict__ kn_bf)
{
  __shared__ float Am[32][33];
  __shared__ float Tm[32][36];
  __shared__ ushort_t KT_hi[256][40];
  __shared__ ushort_t KT_lo[256][40];
  int t = threadIdx.x;
  int cc = blockIdx.x & 63, bh = blockIdx.x >> 6;
  size_t gbase = ((size_t)bh * Ls + cc * 32) * 256;
  int wv = t >> 6, lane = t & 63;
  int l16 = lane & 15, quad = lane >> 4;
  int mi = wv >> 1, ni = wv & 1;

  floatx4 Aacc = {0.f,0.f,0.f,0.f}, Qacc = {0.f,0.f,0.f,0.f};
  {
    int mrow = mi * 16 + l16, nrow = ni * 16 + l16;
    const float* kbp = kb + gbase + (size_t)mrow * 256;
    const float* qnp = qn + gbase + (size_t)mrow * 256;
    const float* knp = kn + gbase + (size_t)nrow * 256;
#pragma unroll
    for (int ks = 0; ks < 8; ++ks) {
      int koff = ks * 32 + quad * 8;
      short8 kbh, kbl, qnh, qnl, knh, knl;
      cvt8(*(const float4*)(kbp + koff), *(const float4*)(kbp + koff + 4), kbh, kbl);
      cvt8(*(const float4*)(qnp + koff), *(const float4*)(qnp + koff + 4), qnh, qnl);
      cvt8(*(const float4*)(knp + koff), *(const float4*)(knp + koff + 4), knh, knl);
      Aacc = __builtin_amdgcn_mfma_f32_16x16x32_bf16(kbh, knh, Aacc, 0, 0, 0);
      Aacc = __builtin_amdgcn_mfma_f32_16x16x32_bf16(kbh, knl, Aacc, 0, 0, 0);
      Aacc = __builtin_amdgcn_mfma_f32_16x16x32_bf16(kbl, knh, Aacc, 0, 0, 0);
      Qacc = __builtin_amdgcn_mfma_f32_16x16x32_bf16(qnh, knh, Qacc, 0, 0, 0);
      Qacc = __builtin_amdgcn_mfma_f32_16x16x32_bf16(qnh, knl, Qacc, 0, 0, 0);
      Qacc = __builtin_amdgcn_mfma_f32_16x16x32_bf16(qnl, knh, Qacc, 0, 0, 0);
      if (ni == 0)
        *(uint4*)(q_bf + gbase + (size_t)mrow * 256 + koff) = *(uint4*)&qnh;
      if (mi == 0)
        *(uint4*)(kn_bf + gbase + (size_t)nrow * 256 + koff) = *(uint4*)&knh;
    }
  }
  float* ag = attn_g + ((size_t)bh * 64 + cc) * 1024;
#pragma unroll
  for (int r = 0; r < 4; ++r) {
    int row = mi * 16 + quad * 4 + r, col = ni * 16 + l16;
    Am[row][col] = (col < row) ? Aacc[r] : 0.f;
    ag[row * 32 + col] = (col <= row) ? Qacc[r] : 0.f;
  }
  __syncthreads();

  if (wv == 0) {
    if (t < 32) {
#pragma unroll
      for (int i = 0; i < 32; ++i) Tm[i][t] = (i == t) ? 1.f : 0.f;
      for (int i2 = 1; i2 < 32; ++i2) {
        if (t < i2) {
          float s = 0.f;
          for (int m2 = t; m2 < i2; ++m2) s = fmaf(Am[i2][m2], Tm[m2][t], s);
          Tm[i2][t] = -s;
        }
      }
    }
  } else {
    int base = t - 64;
#pragma unroll
    for (int pass = 0; pass < 2; ++pass) {
      int d = base + pass * 192;
      if (d < 256) {
        u32 hp[16], lp[16], kp2[16];
#pragma unroll
        for (int m2 = 0; m2 < 16; ++m2) {
          float f0 = kb[gbase + (size_t)(2 * m2) * 256 + d];
          float f1 = kb[gbase + (size_t)(2 * m2 + 1) * 256 + d];
          ushort_t h0 = f2bf(f0), h1 = f2bf(f1);
          hp[m2] = (u32)h0 | ((u32)h1 << 16);
          lp[m2] = (u32)f2bf(f0 - bf2f(h0)) | ((u32)f2bf(f1 - bf2f(h1)) << 16);
          float g0 = kn[gbase + (size_t)(2 * m2) * 256 + d];
          float g1 = kn[gbase + (size_t)(2 * m2 + 1) * 256 + d];
          kp2[m2] = (u32)f2bf(g0) | ((u32)f2bf(g1) << 16);
        }
#pragma unroll
        for (int q2 = 0; q2 < 4; ++q2) {
          *(uint4*)&KT_hi[d][q2 * 8] = *(uint4*)&hp[q2 * 4];
          *(uint4*)&KT_lo[d][q2 * 8] = *(uint4*)&lp[q2 * 4];
          *(uint4*)(knT_bf + gbase + (size_t)d * 32 + q2 * 8) = *(uint4*)&kp2[q2 * 4];
        }
      }
    }
  }
  __syncthreads();

  int lt = wv & 1, dgrp = wv >> 1;
  short8 Th, Tl;
  {
    int lrow = lt * 16 + l16;
    cvt8(*(const float4*)&Tm[lrow][quad * 8],
         *(const float4*)&Tm[lrow][quad * 8 + 4], Th, Tl);
  }
#pragma unroll
  for (int j = 0; j < 8; ++j) {
    int dt = dgrp * 8 + j;
    short8 Bh = *(const short8*)&KT_hi[dt * 16 + l16][quad * 8];
    short8 Bl = *(const short8*)&KT_lo[dt * 16 + l16][quad * 8];
    floatx4 acc = {0.f,0.f,0.f,0.f};
    acc = __builtin_amdgcn_mfma_f32_16x16x32_bf16(Th, Bh, acc, 0, 0, 0);
    acc = __builtin_amdgcn_mfma_f32_16x16x32_bf16(Th, Bl, acc, 0, 0, 0);
    acc = __builtin_amdgcn_mfma_f32_16x16x32_bf16(Tl, Bh, acc, 0, 0, 0);
#pragma unroll
    for (int r = 0; r < 4; ++r) {
      int row = lt * 16 + quad * 4 + r;
      wn_bf[gbase + (size_t)row * 256 + dt * 16 + l16] = f2bf(-acc[r]);
    }
  }
  __syncthreads();

  {
    int d = t;
    u32 hp[16], lp[16];
#pragma unroll
    for (int m2 = 0; m2 < 16; ++m2) {
      float f0 = vb[gbase + (size_t)(2 * m2) * 256 + d];
      float f1 = vb[gbase + (size_t)(2 * m2 + 1) * 256 + d];
      ushort_t h0 = f2bf(f0), h1 = f2bf(f1);
      hp[m2] = (u32)h0 | ((u32)h1 << 16);
      lp[m2] = (u32)f2bf(f0 - bf2f(h0)) | ((u32)f2bf(f1 - bf2f(h1)) << 16);
    }
#pragma unroll
    for (int q2 = 0; q2 < 4; ++q2) {
      *(uint4*)&KT_hi[d][q2 * 8] = *(uint4*)&hp[q2 * 4];
      *(uint4*)&KT_lo[d][q2 * 8] = *(uint4*)&lp[q2 * 4];
    }
  }
  __syncthreads();

#pragma unroll
  for (int j = 0; j < 8; ++j) {
    int dt = dgrp * 8 + j;
    short8 Bh = *(const short8*)&KT_hi[dt * 16 + l16][quad * 8];
    short8 Bl = *(const short8*)&KT_lo[dt * 16 + l16][quad * 8];
    floatx4 acc = {0.f,0.f,0.f,0.f};
    acc = __builtin_amdgcn_mfma_f32_16x16x32_bf16(Th, Bh, acc, 0, 0, 0);
    acc = __builtin_amdgcn_mfma_f32_16x16x32_bf16(Th, Bl, acc, 0, 0, 0);
    acc = __builtin_amdgcn_mfma_f32_16x16x32_bf16(Tl, Bh, acc, 0, 0, 0);
#pragma unroll
    for (int r = 0; r < 4; ++r) {
      int row = lt * 16 + quad * 4 + r;
      u_out[gbase + (size_t)row * 256 + dt * 16 + l16] = acc[r];
    }
  }
}

// ------- cross matrices per super-chunk: X = wn1 @ kn0^T, Y = q1 @ kn0^T ---
__global__ __launch_bounds__(256) void cross_prep(
    const ushort_t* __restrict__ wn_bf, const ushort_t* __restrict__ q_bf,
    const ushort_t* __restrict__ kn_bf,
    float* __restrict__ X_g, float* __restrict__ Y_g)
{
  int t = threadIdx.x;
  int sc = blockIdx.x & 31, bh = blockIdx.x >> 5;
  int wv = t >> 6, lane = t & 63;
  int l16 = lane & 15, quad = lane >> 4;
  int mi = wv >> 1, ni = wv & 1;
  size_t base = (size_t)bh * Ls * 256;
  size_t r1 = base + (size_t)(sc * 64 + 32 + mi * 16 + l16) * 256;  // chunk 2sc+1 rows
  size_t r0 = base + (size_t)(sc * 64 + ni * 16 + l16) * 256;       // chunk 2sc rows
  floatx4 Xacc = {0.f,0.f,0.f,0.f}, Yacc = {0.f,0.f,0.f,0.f};
#pragma unroll
  for (int ks = 0; ks < 8; ++ks) {
    int ko = ks * 32 + quad * 8;
    short8 aw = *(const short8*)(wn_bf + r1 + ko);
    short8 aq = *(const short8*)(q_bf  + r1 + ko);
    short8 bk = *(const short8*)(kn_bf + r0 + ko);
    Xacc = __builtin_amdgcn_mfma_f32_16x16x32_bf16(aw, bk, Xacc, 0, 0, 0);
    Yacc = __builtin_amdgcn_mfma_f32_16x16x32_bf16(aq, bk, Yacc, 0, 0, 0);
  }
  float* xo = X_g + ((size_t)bh * 32 + sc) * 1024;
  float* yo = Y_g + ((size_t)bh * 32 + sc) * 1024;
#pragma unroll
  for (int r = 0; r < 4; ++r) {
    int row = mi * 16 + quad * 4 + r, col = ni * 16 + l16;
    xo[row * 32 + col] = Xacc[r];
    yo[row * 32 + col] = Yacc[r];
  }
}

// ------- merged: chain (0-127) + FIR (128-2175) + weight convT (2176+) -----
__global__ __launch_bounds__(256, 1) void delta_fir(
    const ushort_t* __restrict__ wn_bf, const ushort_t* __restrict__ q_bf,
    const ushort_t* __restrict__ knT_bf, const float* __restrict__ attn_g,
    const float* __restrict__ u_g, const float* __restrict__ X_g,
    const float* __restrict__ Y_g, float* __restrict__ delta_g,
    const float* __restrict__ v, const float* __restrict__ wlg,
    const float* __restrict__ wsg, float* __restrict__ firl,
    float* __restrict__ firs,
    const float* __restrict__ mlpw1, ushort_t* __restrict__ w1_t,
    const float* __restrict__ Wo, ushort_t* __restrict__ wo_t)
{
  __shared__ __attribute__((aligned(16))) char smem[72704];
  int t = threadIdx.x;

  if (blockIdx.x >= 2176) {
    // -------- input-only weight transposes on idle CUs --------
    ushort_t (*tile)[33] = (ushort_t(*)[33])smem;
    const float* W; ushort_t* out; int Kq, Nq, n0, k0;
    if (blockIdx.x < 4288) {          // mlpw1 [1056][2048] -> w1_t [2048][1056]
      int local = blockIdx.x - 2176;  // 64 x 33
      W = mlpw1; out = w1_t; Kq = 1056; Nq = 2048;
      n0 = (local & 63) * 32; k0 = (local >> 6) * 32;
    } else {                          // Wo [1024][1024] -> wo_t [1024][1024]
      int local = blockIdx.x - 4288;  // 32 x 32
      W = Wo; out = wo_t; Kq = 1024; Nq = 1024;
      n0 = (local & 31) * 32; k0 = (local >> 5) * 32;
    }
    int tx = t & 31, ty = t >> 5;
#pragma unroll
    for (int r = 0; r < 32; r += 8)
      tile[ty + r][tx] = f2bf(W[(size_t)(k0 + ty + r) * Nq + n0 + tx]);
    __syncthreads();
#pragma unroll
    for (int r = 0; r < 32; r += 8)
      out[(size_t)(n0 + ty + r) * Kq + k0 + tx] = tile[tx][ty + r];
    return;
  }

  if (blockIdx.x >= 128) {
    // ---------------- FIR part ----------------
    float (*vt)[71] = (float(*)[71])smem;
    int bid = blockIdx.x - 128;
    int lt = bid & 255;
    int bh = bid >> 8;
    int b = bh >> 2, h = bh & 3;
    int l0 = lt * 8;
    const float* vp = v + (size_t)bh * Ls * 256;
    for (int r = 0; r < 70; ++r) {
      int ls = l0 - 62 + r;
      vt[t][r] = (ls >= 0) ? vp[(size_t)ls * 256 + t] : 0.f;
    }
    float TL[63], TS3[3];
#pragma unroll
    for (int j = 0; j < 63; ++j) TL[j] = wlg[((size_t)h * 256 + t) * 63 + j];
#pragma unroll
    for (int j = 0; j < 3; ++j) TS3[j] = wsg[((size_t)h * 256 + t) * 3 + j];
    __syncthreads();
    float aL[8] = {0,0,0,0,0,0,0,0}, aS[8] = {0,0,0,0,0,0,0,0};
#pragma unroll
    for (int r = 0; r < 70; ++r) {
      float vm = vt[t][r];
#pragma unroll
      for (int p = 0; p < 8; ++p) {
        int jl = r - p;
        if (jl >= 0 && jl < 63) aL[p] = fmaf(vm, TL[jl], aL[p]);
        int jssrc = r - 60 - p;
        if (jssrc >= 0 && jssrc < 3) aS[p] = fmaf(vm, TS3[jssrc], aS[p]);
      }
    }
#pragma unroll
    for (int p = 0; p < 8; ++p) {
      int l = l0 + p;
      size_t ob = (((size_t)b * Ls + l) * NH + h) * 256 + t;
      firl[ob] = aL[p];
      firs[ob] = aS[p];
    }
    return;
  }

  // ---------------- chain part (m=2 super-chunks) ----------------
  ushort_t (*Shi)[264] = (ushort_t(*)[264])(smem);
  ushort_t (*Slo)[264] = (ushort_t(*)[264])(smem + 8448);
  float (*u2L0)[17] = (float(*)[17])(smem + 16896);
  float (*u2L1)[17] = (float(*)[17])(smem + 19072);
  int bh = blockIdx.x & 7, g = blockIdx.x >> 3;
  int b = bh >> 2, h = bh & 3;
  int wv = t >> 6, lane = t & 63;
  int lquad = lane >> 4, l16 = lane & 15;
  int j0 = g * 16;
  int Mt = wv & 1;
  bool isU = (wv < 2);
  const ushort_t* wp = wn_bf + (size_t)bh * Ls * 256;
  const ushort_t* qp = q_bf  + (size_t)bh * Ls * 256;
  const ushort_t* ap = (isU ? wp : qp) + (size_t)(Mt * 16 + l16) * 256;
  const ushort_t* kr = knT_bf + (size_t)bh * Ls * 256 + (size_t)l16 * 32 + lquad * 8;
  const float* urow = u_g + (size_t)bh * Ls * 256
                    + (size_t)(Mt * 16 + lquad * 4) * 256 + j0 + l16;
  const float* arp = attn_g + (size_t)bh * 64 * 1024
                   + (size_t)(Mt * 16 + l16) * 32 + lquad * 8;
  const float* xrp = (isU ? X_g : Y_g) + (size_t)bh * 32768
                   + (size_t)(Mt * 16 + l16) * 32 + lquad * 8;

  floatx4 Sacc[4], SaccL[4];
#pragma unroll
  for (int i = 0; i < 4; ++i)
#pragma unroll
    for (int r = 0; r < 4; ++r) { Sacc[i][r] = 0.f; SaccL[i][r] = 0.f; }
  for (int i = t; i < 4224; i += 256) ((u32*)smem)[i] = 0;

  // prologue: super-chunk 0, sub-chunk 0 operands
  short8 a0[8], k0[4];
  floatx4 u0 = {0.f, 0.f, 0.f, 0.f};
  float4 at0a = {0,0,0,0}, at0b = {0,0,0,0};
#pragma unroll
  for (int ks = 0; ks < 8; ++ks)
    a0[ks] = *(const short8*)(ap + ks * 32 + lquad * 8);
#pragma unroll
  for (int i = 0; i < 4; ++i)
    k0[i] = *(const short8*)(kr + (size_t)(wv * 4 + i) * 512);
  if (isU) {
#pragma unroll
    for (int r = 0; r < 4; ++r) u0[r] = urow[(size_t)r * 256];
  } else {
    at0a = *(const float4*)(arp);
    at0b = *(const float4*)(arp + 4);
  }
  wave_barrier();

  for (int sc = 0; sc < 32; ++sc) {
    size_t cb1 = (size_t)sc * 16384 + 8192;
    size_t nb0 = (size_t)(sc + 1) * 16384;
    bool hasN = (sc + 1 < 32);

    // sub-chunk1 operands + cross matrix (used mid-iteration; latency covered)
    short8 a1[8], k1[4];
    floatx4 u1 = {0.f, 0.f, 0.f, 0.f};
    float4 at1a = {0,0,0,0}, at1b = {0,0,0,0};
#pragma unroll
    for (int ks = 0; ks < 8; ++ks)
      a1[ks] = *(const short8*)(ap + cb1 + ks * 32 + lquad * 8);
#pragma unroll
    for (int i = 0; i < 4; ++i)
      k1[i] = *(const short8*)(kr + cb1 + (size_t)(wv * 4 + i) * 512);
    if (isU) {
#pragma unroll
      for (int r = 0; r < 4; ++r) u1[r] = urow[cb1 + (size_t)r * 256];
    } else {
      size_t na = (size_t)(2 * sc + 1) * 1024;
      at1a = *(const float4*)(arp + na);
      at1b = *(const float4*)(arp + na + 4);
    }
    float4 xa = *(const float4*)(xrp + (size_t)sc * 1024);
    float4 xb = *(const float4*)(xrp + (size_t)sc * 1024 + 4);

    // ---- sub-chunk 0: u2_0 (isU) / po_0 (o) against S0 ----
    floatx4 acc0;
    if (isU) {
      floatx4 A0 = u0, A1 = {0,0,0,0}, A2 = {0,0,0,0}, A3 = {0,0,0,0};
#pragma unroll
      for (int ks = 0; ks < 8; ++ks) {
        short8 sh = *(const short8*)&Shi[l16][ks * 32 + lquad * 8];
        short8 sl = *(const short8*)&Slo[l16][ks * 32 + lquad * 8];
        if (ks & 1) {
          A1 = __builtin_amdgcn_mfma_f32_16x16x32_bf16(a0[ks], sh, A1, 0, 0, 0);
          A3 = __builtin_amdgcn_mfma_f32_16x16x32_bf16(a0[ks], sl, A3, 0, 0, 0);
        } else {
          A0 = __builtin_amdgcn_mfma_f32_16x16x32_bf16(a0[ks], sh, A0, 0, 0, 0);
          A2 = __builtin_amdgcn_mfma_f32_16x16x32_bf16(a0[ks], sl, A2, 0, 0, 0);
        }
      }
#pragma unroll
      for (int r = 0; r < 4; ++r) acc0[r] = (A0[r] + A1[r]) + (A2[r] + A3[r]);
#pragma unroll
      for (int r = 0; r < 4; ++r)
        u2L0[Mt * 16 + lquad * 4 + r][l16] = acc0[r];
    } else {
      floatx4 A0 = {0,0,0,0}, A1 = {0,0,0,0};
#pragma unroll
      for (int ks = 0; ks < 8; ++ks) {
        short8 sh = *(const short8*)&Shi[l16][ks * 32 + lquad * 8];
        if (ks & 1) A1 = __builtin_amdgcn_mfma_f32_16x16x32_bf16(a0[ks], sh, A1, 0, 0, 0);
        else        A0 = __builtin_amdgcn_mfma_f32_16x16x32_bf16(a0[ks], sh, A0, 0, 0, 0);
      }
#pragma unroll
      for (int r = 0; r < 4; ++r) acc0[r] = A0[r] + A1[r];
    }
    // prefetch next-super-chunk a0 (a0 regs dead; stays in flight across
    // the raw barriers below -> ~full iteration of latency cover)
    if (hasN) {
#pragma unroll
      for (int ks = 0; ks < 8; ++ks)
        a0[ks] = *(const short8*)(ap + nb0 + ks * 32 + lquad * 8);
    }
    wave_barrier();                          // u2_0 visible

    short8 uh0, ul0;
#pragma unroll
    for (int j = 0; j < 8; ++j) {
      float f = u2L0[lquad * 8 + j][l16];
      ushort_t hi = f2bf(f);
      uh0[j] = (short)hi;
      ul0[j] = (short)f2bf(f - bf2f(hi));
    }
#pragma unroll
    for (int i = 0; i < 4; ++i) {
      Sacc[i]  = __builtin_amdgcn_mfma_f32_16x16x32_bf16(k0[i], uh0, Sacc[i], 0, 0, 0);
      SaccL[i] = __builtin_amdgcn_mfma_f32_16x16x32_bf16(k0[i], ul0, SaccL[i], 0, 0, 0);
    }
    if (hasN) {
#pragma unroll
      for (int i = 0; i < 4; ++i)
        k0[i] = *(const short8*)(kr + nb0 + (size_t)(wv * 4 + i) * 512);
    }

    // ---- sub-chunk 1: u2_1 = u1 + wn1@S0 + X@u2_0 / o path ----
    floatx4 acc1;
    if (isU) {
      floatx4 A0 = u1, A1 = {0,0,0,0}, A2 = {0,0,0,0}, A3 = {0,0,0,0};
#pragma unroll
      for (int ks = 0; ks < 8; ++ks) {
        short8 sh = *(const short8*)&Shi[l16][ks * 32 + lquad * 8];
        short8 sl = *(const short8*)&Slo[l16][ks * 32 + lquad * 8];
        if (ks & 1) {
          A1 = __builtin_amdgcn_mfma_f32_16x16x32_bf16(a1[ks], sh, A1, 0, 0, 0);
          A3 = __builtin_amdgcn_mfma_f32_16x16x32_bf16(a1[ks], sl, A3, 0, 0, 0);
        } else {
          A0 = __builtin_amdgcn_mfma_f32_16x16x32_bf16(a1[ks], sh, A0, 0, 0, 0);
          A2 = __builtin_amdgcn_mfma_f32_16x16x32_bf16(a1[ks], sl, A2, 0, 0, 0);
        }
      }
      short8 Xh, Xl;
      cvt8(xa, xb, Xh, Xl);
      A0 = __builtin_amdgcn_mfma_f32_16x16x32_bf16(Xh, uh0, A0, 0, 0, 0);
      A1 = __builtin_amdgcn_mfma_f32_16x16x32_bf16(Xh, ul0, A1, 0, 0, 0);
      A2 = __builtin_amdgcn_mfma_f32_16x16x32_bf16(Xl, uh0, A2, 0, 0, 0);
#pragma unroll
      for (int r = 0; r < 4; ++r) acc1[r] = (A0[r] + A1[r]) + (A2[r] + A3[r]);
#pragma unroll
      for (int r = 0; r < 4; ++r)
        u2L1[Mt * 16 + lquad * 4 + r][l16] = acc1[r];
      if (hasN) {
#pragma unroll
        for (int r = 0; r < 4; ++r) u0[r] = urow[nb0 + (size_t)r * 256];
      }
    } else {
      // o_0 = po_0 + attn_0 @ u2_0 -> store
      short8 ath, atl;
      cvt8(at0a, at0b, ath, atl);
      acc0 = __builtin_amdgcn_mfma_f32_16x16x32_bf16(ath, uh0, acc0, 0, 0, 0);
      acc0 = __builtin_amdgcn_mfma_f32_16x16x32_bf16(ath, ul0, acc0, 0, 0, 0);
      acc0 = __builtin_amdgcn_mfma_f32_16x16x32_bf16(atl, uh0, acc0, 0, 0, 0);
#pragma unroll
      for (int r = 0; r < 4; ++r) {
        int l = sc * 64 + Mt * 16 + lquad * 4 + r;
        delta_g[(((size_t)b * Ls + l) * NH + h) * 256 + j0 + l16] = acc0[r];
      }
      // po_1 = q1 @ Shi(S0) + Y @ u2_0
      floatx4 A0 = {0,0,0,0}, A1 = {0,0,0,0};
#pragma unroll
      for (int ks = 0; ks < 8; ++ks) {
        short8 sh = *(const short8*)&Shi[l16][ks * 32 + lquad * 8];
        if (ks & 1) A1 = __builtin_amdgcn_mfma_f32_16x16x32_bf16(a1[ks], sh, A1, 0, 0, 0);
        else        A0 = __builtin_amdgcn_mfma_f32_16x16x32_bf16(a1[ks], sh, A0, 0, 0, 0);
      }
      short8 Yh, Yl;
      cvt8(xa, xb, Yh, Yl);
      A0 = __builtin_amdgcn_mfma_f32_16x16x32_bf16(Yh, uh0, A0, 0, 0, 0);
      A1 = __builtin_amdgcn_mfma_f32_16x16x32_bf16(Yh, ul0, A1, 0, 0, 0);
      A0 = __builtin_amdgcn_mfma_f32_16x16x32_bf16(Yl, uh0, A0, 0, 0, 0);
#pragma unroll
      for (int r = 0; r < 4; ++r) acc1[r] = A0[r] + A1[r];
      if (hasN) {
        size_t na0 = (size_t)(2 * sc + 2) * 1024;
        at0a = *(const float4*)(arp + na0);
        at0b = *(const float4*)(arp + na0 + 4);
      }
    }
    wave_barrier();                          // u2_1 visible; all Shi/Slo reads done

    short8 uh1, ul1;
#pragma unroll
    for (int j = 0; j < 8; ++j) {
      float f = u2L1[lquad * 8 + j][l16];
      ushort_t hi = f2bf(f);
      uh1[j] = (short)hi;
      ul1[j] = (short)f2bf(f - bf2f(hi));
    }
#pragma unroll
    for (int i = 0; i < 4; ++i) {
      Sacc[i]  = __builtin_amdgcn_mfma_f32_16x16x32_bf16(k1[i], uh1, Sacc[i], 0, 0, 0);
      SaccL[i] = __builtin_amdgcn_mfma_f32_16x16x32_bf16(k1[i], ul1, SaccL[i], 0, 0, 0);
    }
    if (!isU) {
      short8 ath, atl;
      cvt8(at1a, at1b, ath, atl);
      acc1 = __builtin_amdgcn_mfma_f32_16x16x32_bf16(ath, uh1, acc1, 0, 0, 0);
      acc1 = __builtin_amdgcn_mfma_f32_16x16x32_bf16(ath, ul1, acc1, 0, 0, 0);
      acc1 = __builtin_amdgcn_mfma_f32_16x16x32_bf16(atl, uh1, acc1, 0, 0, 0);
#pragma unroll
      for (int r = 0; r < 4; ++r) {
        int l = sc * 64 + 32 + Mt * 16 + lquad * 4 + r;
        delta_g[(((size_t)b * Ls + l) * NH + h) * 256 + j0 + l16] = acc1[r];
      }
    }
    // S write-back (once per 64 tokens)
#pragma unroll
    for (int i = 0; i < 4; ++i) {
      int dk0 = (wv * 4 + i) * 16 + lquad * 4;
      ushort4 h4, l4;
      ushort_t* hp = (ushort_t*)&h4;
      ushort_t* lp = (ushort_t*)&l4;
#pragma unroll
      for (int r = 0; r < 4; ++r) {
        float sv = Sacc[i][r] + SaccL[i][r];
        ushort_t hi = f2bf(sv);
        hp[r] = hi;
        lp[r] = f2bf(sv - bf2f(hi));
      }
      *(ushort4*)&Shi[l16][dk0] = h4;
      *(ushort4*)&Slo[l16][dk0] = l4;
    }
    wave_barrier();                          // S visible
  }
}

// ------- gate_in (bf16) ----------------------------------------------------
__global__ __launch_bounds__(256) void build_gate_in_bf(
    const float* __restrict__ x, const float* __restrict__ firs,
    const float* __restrict__ firl, const float* __restrict__ delta,
    const float* __restrict__ v, ushort_t* __restrict__ gin)
{
  int mtok = blockIdx.x, t = threadIdx.x;
  int b = mtok >> 11, l = mtok & 2047;
  float4 xv = *(const float4*)(x + (size_t)mtok * 1024 + t * 4);
  ushort4 xo = make_ushort4(f2bf(xv.x), f2bf(xv.y), f2bf(xv.z), f2bf(xv.w));
  *(ushort4*)(gin + (size_t)mtok * 1056 + t * 4) = xo;
  int w = t >> 6, lane = t & 63;
  for (int br = 0; br < 4; ++br) {
    float s = 0.f, s2 = 0.f;
#pragma unroll
    for (int r = 0; r < 4; ++r) {
      int d = lane + r * 64;
      float val;
      if (br == 0)      val = firs [(size_t)mtok * 1024 + w * 256 + d];
      else if (br == 1) val = firl [(size_t)mtok * 1024 + w * 256 + d];
      else if (br == 2) val = delta[(size_t)mtok * 1024 + w * 256 + d];
      else              val = v[(((size_t)(b * NH + w)) * Ls + l) * 256 + d];
      s += val; s2 = fmaf(val, val, s2);
    }
#pragma unroll
    for (int off = 32; off; off >>= 1) {
      s += __shfl_down(s, off);
      s2 += __shfl_down(s2, off);
    }
    if (lane == 0) {
      float mean = s * (1.f / 256.f);
      float var = s2 * (1.f / 256.f) - mean * mean;
      gin[(size_t)mtok * 1056 + 1024 + br * 8 + w] = f2bf(mean);
      gin[(size_t)mtok * 1056 + 1024 + br * 8 + 4 + w] = f2bf(sqrtf(fmaxf(var, 1e-6f)));
    }
  }
}

// ------- logits -> gates (bf16 hidden input) -------------------------------
__global__ __launch_bounds__(256) void mlp2_gates(
    const ushort_t* __restrict__ mh, const float* __restrict__ W2,
    const float* __restrict__ b2, const float* __restrict__ glt,
    float* __restrict__ gates)
{
  int mtok = blockIdx.x, t = threadIdx.x;
  float p[16];
#pragma unroll
  for (int j = 0; j < 16; ++j) p[j] = 0.f;
  for (int k = t; k < 2048; k += 256) {
    float hv = bf2f(mh[(size_t)mtok * 2048 + k]);
    const float* wr = W2 + (size_t)k * 16;
#pragma unroll
    for (int j4 = 0; j4 < 4; ++j4) {
      float4 w4 = *(const float4*)(wr + j4 * 4);
      p[j4*4+0] = fmaf(hv, w4.x, p[j4*4+0]);
      p[j4*4+1] = fmaf(hv, w4.y, p[j4*4+1]);
      p[j4*4+2] = fmaf(hv, w4.z, p[j4*4+2]);
      p[j4*4+3] = fmaf(hv, w4.w, p[j4*4+3]);
    }
  }
#pragma unroll
  for (int j = 0; j < 16; ++j)
#pragma unroll
    for (int off = 32; off; off >>= 1) p[j] += __shfl_down(p[j], off);
  __shared__ float red[4][16];
  __shared__ float zl[16];
  int w = t >> 6;
  if ((t & 63) == 0) {
#pragma unroll
    for (int j = 0; j < 16; ++j) red[w][j] = p[j];
  }
  __syncthreads();
  if (t < 16) {
    float tot = red[0][t] + red[1][t] + red[2][t] + red[3][t] + b2[t];
    float tempv = log1pf(expf(glt[t >> 2])) + 1e-4f;
    zl[t] = tot / tempv;
  }
  __syncthreads();
  if (t < 4) {
    float z0 = zl[t*4], z1 = zl[t*4+1], z2 = zl[t*4+2], z3 = zl[t*4+3];
    float mx = fmaxf(fmaxf(z0, z1), fmaxf(z2, z3));
    float e0 = expf(z0 - mx), e1 = expf(z1 - mx), e2 = expf(z2 - mx), e3 = expf(z3 - mx);
    float inv = 1.f / (e0 + e1 + e2 + e3);
    gates[(size_t)mtok * 16 + t * 4 + 0] = e0 * inv;
    gates[(size_t)mtok * 16 + t * 4 + 1] = e1 * inv;
    gates[(size_t)mtok * 16 + t * 4 + 2] = e2 * inv;
    gates[(size_t)mtok * 16 + t * 4 + 3] = e3 * inv;
  }
}

// ------- o = gated mix, RMSNorm -> bf16 ------------------------------------
__global__ __launch_bounds__(256) void combine_norm_bf(
    const float* __restrict__ firs, const float* __restrict__ firl,
    const float* __restrict__ delta, const float* __restrict__ v,
    const float* __restrict__ gates, const float* __restrict__ onw,
    ushort_t* __restrict__ o)
{
  int mh = blockIdx.x;
  int mtok = mh >> 2, h = mh & 3;
  int t = threadIdx.x;
  int b = mtok >> 11, l = mtok & 2047;
  const float* g = gates + (size_t)mtok * 16 + h * 4;
  float w0 = g[0], w1 = g[1], w2 = g[2], w3 = g[3];
  size_t tb = (size_t)mtok * 1024 + h * 256 + t;
  float val = w0 * firs[tb] + w1 * firl[tb] + w2 * delta[tb]
            + w3 * v[(((size_t)(b * NH + h)) * Ls + l) * 256 + t];
  float s2 = val * val;
#pragma unroll
  for (int off = 32; off; off >>= 1) s2 += __shfl_down(s2, off);
  __shared__ float r4[4];
  if ((t & 63) == 0) r4[t >> 6] = s2;
  __syncthreads();
  float tot = r4[0] + r4[1] + r4[2] + r4[3];
  float rms = rsqrtf(tot * (1.f / 256.f) + 1e-5f);
  o[tb] = f2bf(val * rms * onw[t]);
}

// ---------------------------------------------------------------------------
extern "C" void kernel_launch(void* const* d_in, const int* in_sizes, int n_in,
                              void* d_out, int out_size, void* d_ws, size_t ws_size,
                              hipStream_t stream) {
  const float* x     = (const float*)d_in[0];
  const float* Wq    = (const float*)d_in[1];
  const float* Wk    = (const float*)d_in[2];
  const float* Wv    = (const float*)d_in[3];
  const float* Wb    = (const float*)d_in[4];
  const float* convq = (const float*)d_in[5];
  const float* convk = (const float*)d_in[6];
  const float* convv = (const float*)d_in[7];
  const float* firsw = (const float*)d_in[8];
  const float* firlw = (const float*)d_in[9];
  const float* mlpw1 = (const float*)d_in[10];
  const float* mlpb1 = (const float*)d_in[11];
  const float* mlpw2 = (const float*)d_in[12];
  const float* mlpb2 = (const float*)d_in[13];
  const float* glt   = (const float*)d_in[14];
  const float* onw   = (const float*)d_in[15];
  const float* Wo    = (const float*)d_in[16];
  float* ws = (float*)d_ws;

  ushort_t* x_bf   = (ushort_t*)(ws + off_firs);
  ushort_t* Wqkv_t = (ushort_t*)(ws + off_firl);  // 3 x [1024][1024] contiguous
  ushort_t* gin_bf = (ushort_t*)(ws + off_gin);
  ushort_t* w1_t   = (ushort_t*)(ws + off_k);     // kn dead after chunk_prep
  ushort_t* o_bf   = (ushort_t*)(ws + off_xv);
  ushort_t* Wo_t   = (ushort_t*)(ws + off_wot);   // never-aliased window
  ushort_t* mlph_bf= (ushort_t*)(ws + off_mlph);
  ushort_t* wn_bf  = (ushort_t*)(ws + off_firs);
  ushort_t* q_bf   = (ushort_t*)(ws + off_firs + 2097152);
  ushort_t* knT_bf = (ushort_t*)(ws + off_firl);
  ushort_t* kn_bf  = (ushort_t*)(ws + off_xq);    // x3 dead after conv_prep
  float* x3   = ws + off_xq;     // fused [4096][3072] spans xq/xk/xv
  float* kb_f = ws + off_gin;
  float* vb_f = ws + off_mlph;
  float* X_g  = ws + off_gin;            // kb dead after chunk_prep; 8*32*1024 f32
  float* Y_g  = ws + off_gin + 262144;
  float* firs_f = ws + off_xq;   // x3/kn_bf dead after cross_prep
  float* firl_f = ws + off_xk;

  dim3 blk(256);
  // fused q/k/v projection (one N=3072 GEMM) + beta
  to_bf16<<<2048, blk, 0, stream>>>(x, x_bf, 4194304);
  convT<<<dim3(32, 32), blk, 0, stream>>>(Wq, Wqkv_t, 1024, 1024);
  convT<<<dim3(32, 32), blk, 0, stream>>>(Wk, Wqkv_t + 1048576, 1024, 1024);
  convT<<<dim3(32, 32), blk, 0, stream>>>(Wv, Wqkv_t + 2097152, 1024, 1024);
  gemm_bf16<<<dim3(24, 32), blk, 0, stream>>>(x_bf, Wqkv_t, x3, 3072, 1024, nullptr, 0, 0);
  beta_sigmoid<<<4096, blk, 0, stream>>>(x, Wb, ws + off_beta);
  // fused conv4+silu + l2norm + beta products
  conv_prep<<<16384, blk, 0, stream>>>(x3, convq, convk, convv, ws + off_beta,
                                       ws + off_q, ws + off_k, kb_f, vb_f, ws + off_v);
  // per-chunk T inverse, attn, u (->xv), bf16 {-w, q, knT, kn}
  chunk_prep<<<512, blk, 0, stream>>>(kb_f, ws + off_k, ws + off_q, vb_f,
                                      ws + off_attn, ws + off_xv, wn_bf, q_bf,
                                      knT_bf, kn_bf);
  // 32x32 cross matrices per super-chunk (X = wn1 kn0^T, Y = q1 kn0^T)
  cross_prep<<<256, blk, 0, stream>>>(wn_bf, q_bf, kn_bf, X_g, Y_g);
  // merged serial MFMA scan + FIR + input-only weight transposes (idle CUs)
  delta_fir<<<5312, blk, 0, stream>>>(wn_bf, q_bf, knT_bf, ws + off_attn,
                                      ws + off_xv, X_g, Y_g, ws + off_q,
                                      ws + off_v, firlw, firsw, firl_f, firs_f,
                                      mlpw1, w1_t, Wo, Wo_t);
  // gate input (bf16), MLP1 (MFMA, gelu, bf16 out), gates
  build_gate_in_bf<<<4096, blk, 0, stream>>>(x, firs_f, firl_f, ws + off_q,
                                             ws + off_v, gin_bf);
  gemm_bf16<<<dim3(16, 32), blk, 0, stream>>>(gin_bf, w1_t, (float*)mlph_bf,
                                              2048, 1056, mlpb1, 1, 1);
  mlp2_gates<<<4096, blk, 0, stream>>>(mlph_bf, mlpw2, mlpb2, glt, ws + off_gates);
  // combine + RMSNorm -> bf16, output projection (MFMA)
  combine_norm_bf<<<16384, blk, 0, stream>>>(firs_f, firl_f, ws + off_q,
                                             ws + off_v, ws + off_gates, onw, o_bf);
  gemm_bf16<<<dim3(8, 32), blk, 0, stream>>>(o_bf, Wo_t, (float*)d_out, 1024, 1024, nullptr, 0, 0);
}

// Round 12
// 543.848 us; speedup vs baseline: 1.1651x; 1.1337x over previous
//
#include <hip/hip_runtime.h>
#include <hip/hip_bf16.h>

// ---------------------------------------------------------------------------
// DeltaNet forward, round 19:
//  - Base: r15/r18 (best measured 543.2us; r18 re-measure of same source hit
//    616.5 in a throttled session -> session variance ±13% dominates, so only
//    real-byte reductions are worth pursuing).
//  - NEW: producer-side branch stats. firs/firl stats computed in the FIR
//    shadow blocks (values in regs; block-reduce in reused LDS), v stats in
//    conv_prep (values in regs; piggybacks existing barrier). build_gate_in
//    shrinks to x-copy + delta-stats: 80MB -> 32MB of epilogue traffic.
//    gin relocated to the never-aliased window after Wo_t so shadow-time
//    stat writes can't collide with X/Y/kb at off_gin.
// ---------------------------------------------------------------------------

#define DEVI __device__ __forceinline__
typedef unsigned int u32;
typedef unsigned short ushort_t;
typedef __attribute__((ext_vector_type(8))) short short8;
typedef __attribute__((ext_vector_type(4))) float floatx4;

constexpr int Ls = 2048, NH = 4;

// workspace offsets (floats)
constexpr size_t off_xq   = 0;         // x3 [m][3072] cols 0-1023 -> kn_bf -> firs
constexpr size_t off_xk   = 4194304;   // x3 cols 1024-2047 -> firl
constexpr size_t off_xv   = 8388608;   // x3 cols 2048-3071 -> u -> o_bf
constexpr size_t off_q    = 12582912;  // qn -> delta
constexpr size_t off_k    = 16777216;  // kn (dead after chunk_prep) -> w1_t
constexpr size_t off_v    = 20971520;  // v (alive to the end)
constexpr size_t off_beta = 25165824;  // beta (dead after conv_prep)
constexpr size_t off_attn = 25182208;  // attn (read by chain)
constexpr size_t off_firs = 25706496;  // x_bf -> {wn_bf, q_bf} (bf16)
constexpr size_t off_firl = 29900800;  // Wqkv_t -> knT_bf (bf16)
constexpr size_t off_gin  = 34095104;  // kb (f32) -> {X_g, Y_g}
constexpr size_t off_mlph = 38420480;  // vb (f32) -> mlph_bf
constexpr size_t off_wot  = 42614784;  // Wo_t (bf16, 0.52M fl) - never-aliased
constexpr size_t off_gin2 = 43139072;  // gin_bf (2.16M fl) - never-aliased
constexpr size_t off_gates= 46809088;  // gates

DEVI float sigmoidf_(float x) { return 1.f / (1.f + expf(-x)); }
DEVI float siluf_(float x) { return x / (1.f + expf(-x)); }
DEVI float geluf_(float x) { return 0.5f * x * (1.f + erff(x * 0.7071067811865476f)); }
DEVI ushort_t f2bf(float f) {
  union { float f; u32 u; } c{f};
  u32 r = (c.u + 0x7fffu + ((c.u >> 16) & 1u)) >> 16;
  return (ushort_t)r;
}
DEVI float bf2f(ushort_t h) {
  union { u32 u; float f; } c; c.u = ((u32)h) << 16; return c.f;
}
DEVI void cvt8(float4 a, float4 b, short8& hi, short8& lo) {
  float f[8] = {a.x,a.y,a.z,a.w,b.x,b.y,b.z,b.w};
#pragma unroll
  for (int j = 0; j < 8; ++j) {
    ushort_t h = f2bf(f[j]);
    hi[j] = (short)h;
    lo[j] = (short)f2bf(f[j] - bf2f(h));
  }
}
DEVI void async16(const void* g, void* l) {
  __builtin_amdgcn_global_load_lds(
      (const u32 __attribute__((address_space(1)))*)g,
      (u32 __attribute__((address_space(3)))*)l, 16, 0, 0);
}
// Raw workgroup barrier: waits LDS ops only (lgkmcnt), leaves global
// loads/stores (vmcnt) in flight. All cross-wave deps in the chain loop are
// LDS-only, and global data has no in-kernel consumers.
DEVI void wave_barrier() {
  __builtin_amdgcn_sched_barrier(0);
  asm volatile("s_waitcnt lgkmcnt(0)" ::: "memory");
  __builtin_amdgcn_s_barrier();
  __builtin_amdgcn_sched_barrier(0);
}

// ---------------- f32 -> bf16 ----------------------------------------------
__global__ __launch_bounds__(256) void to_bf16(
    const float* __restrict__ in, ushort_t* __restrict__ out, int n)
{
  int i = (blockIdx.x * 256 + threadIdx.x) * 8;
  if (i >= n) return;
  float4 a = *(const float4*)(in + i);
  float4 b = *(const float4*)(in + i + 4);
  ushort_t o[8] = { f2bf(a.x), f2bf(a.y), f2bf(a.z), f2bf(a.w),
                    f2bf(b.x), f2bf(b.y), f2bf(b.z), f2bf(b.w) };
  *(uint4*)(out + i) = *(uint4*)o;
}

// ---------------- f32 [K][N] -> bf16 [N][K] --------------------------------
__global__ __launch_bounds__(256) void convT(
    const float* __restrict__ W, ushort_t* __restrict__ out, int Kq, int Nq)
{
  __shared__ ushort_t tile[32][33];
  int n0 = blockIdx.x * 32, k0 = blockIdx.y * 32;
  int tx = threadIdx.x & 31, ty = threadIdx.x >> 5;
#pragma unroll
  for (int r = 0; r < 32; r += 8)
    tile[ty + r][tx] = f2bf(W[(size_t)(k0 + ty + r) * Nq + n0 + tx]);
  __syncthreads();
#pragma unroll
  for (int r = 0; r < 32; r += 8)
    out[(size_t)(n0 + ty + r) * Kq + k0 + tx] = tile[tx][ty + r];
}

// ---------------- bf16 MFMA GEMM -------------------------------------------
__global__ __launch_bounds__(256) void gemm_bf16(
    const ushort_t* __restrict__ A, const ushort_t* __restrict__ Bt,
    float* __restrict__ C, int Nq, int Kq,
    const float* __restrict__ bias, int act, int outbf)
{
  __shared__ ushort_t As[128 * 32];
  __shared__ ushort_t Bs[128 * 32];
  int t = threadIdx.x;
  int w = t >> 6, lane = t & 63;
  int m0 = blockIdx.y * 128, n0 = blockIdx.x * 128;
  floatx4 acc[4][4];
#pragma unroll
  for (int i = 0; i < 4; ++i)
#pragma unroll
    for (int j = 0; j < 4; ++j)
#pragma unroll
      for (int r = 0; r < 4; ++r) acc[i][j][r] = 0.f;

  int lrow = lane >> 2, lk8 = (lane & 3) * 8;
  for (int kt = 0; kt < Kq; kt += 32) {
#pragma unroll
    for (int r = 0; r < 2; ++r) {
      int seg = w * 2 + r;
      int row = seg * 16 + lrow;
      async16(A  + (size_t)(m0 + row) * Kq + kt + lk8, &As[seg * 512]);
      async16(Bt + (size_t)(n0 + row) * Kq + kt + lk8, &Bs[seg * 512]);
    }
    __syncthreads();
    short8 af[4], bf[4];
#pragma unroll
    for (int i = 0; i < 4; ++i) {
      int row = (w >> 1) * 64 + i * 16 + (lane & 15);
      af[i] = *(const short8*)&As[row * 32 + (lane >> 4) * 8];
    }
#pragma unroll
    for (int j = 0; j < 4; ++j) {
      int col = (w & 1) * 64 + j * 16 + (lane & 15);
      bf[j] = *(const short8*)&Bs[col * 32 + (lane >> 4) * 8];
    }
#pragma unroll
    for (int i = 0; i < 4; ++i)
#pragma unroll
      for (int j = 0; j < 4; ++j)
        acc[i][j] = __builtin_amdgcn_mfma_f32_16x16x32_bf16(af[i], bf[j], acc[i][j], 0, 0, 0);
    __syncthreads();
  }
#pragma unroll
  for (int i = 0; i < 4; ++i) {
    int rbase = m0 + (w >> 1) * 64 + i * 16 + ((lane >> 4) << 2);
#pragma unroll
    for (int j = 0; j < 4; ++j) {
      int col = n0 + (w & 1) * 64 + j * 16 + (lane & 15);
      float bv = act ? bias[col] : 0.f;
#pragma unroll
      for (int r = 0; r < 4; ++r) {
        float v = acc[i][j][r];
        if (act) v = geluf_(v + bv);
        if (outbf) ((ushort_t*)C)[(size_t)(rbase + r) * Nq + col] = f2bf(v);
        else       C[(size_t)(rbase + r) * Nq + col] = v;
      }
    }
  }
}

// ---------------- beta = sigmoid(x @ Wb) -----------------------------------
__global__ __launch_bounds__(256) void beta_sigmoid(
    const float* __restrict__ x, const float* __restrict__ Wb,
    float* __restrict__ beta)
{
  int mtok = blockIdx.x, t = threadIdx.x;
  int b = mtok >> 11, l = mtok & 2047;
  float a0 = 0, a1 = 0, a2 = 0, a3 = 0;
  for (int k = t; k < 1024; k += 256) {
    float xv = x[(size_t)mtok * 1024 + k];
    float4 w4 = *(const float4*)(Wb + k * 4);
    a0 = fmaf(xv, w4.x, a0); a1 = fmaf(xv, w4.y, a1);
    a2 = fmaf(xv, w4.z, a2); a3 = fmaf(xv, w4.w, a3);
  }
#pragma unroll
  for (int off = 32; off; off >>= 1) {
    a0 += __shfl_down(a0, off); a1 += __shfl_down(a1, off);
    a2 += __shfl_down(a2, off); a3 += __shfl_down(a3, off);
  }
  __shared__ float red[4][4];
  int w = t >> 6;
  if ((t & 63) == 0) { red[w][0] = a0; red[w][1] = a1; red[w][2] = a2; red[w][3] = a3; }
  __syncthreads();
  if (t < 4) {
    float s = red[0][t] + red[1][t] + red[2][t] + red[3][t];
    beta[((size_t)(b * NH + t)) * Ls + l] = sigmoidf_(s);
  }
}

// ------- fused conv4+silu + l2norm + beta + v-stats ------------------------
__global__ __launch_bounds__(256) void conv_prep(
    const float* __restrict__ x3, const float* __restrict__ wq,
    const float* __restrict__ wk, const float* __restrict__ wv,
    const float* __restrict__ beta_g,
    float* __restrict__ qn, float* __restrict__ kn,
    float* __restrict__ kb, float* __restrict__ vb,
    float* __restrict__ v_out, ushort_t* __restrict__ gin)
{
  int i = blockIdx.x;              // bh*Ls + l
  int t = threadIdx.x;
  int l = i & 2047, bh = i >> 11;
  int b = bh >> 2, h = bh & 3;
  int c = h * 256 + t;
  const float* p = x3 + ((size_t)b * Ls) * 3072 + c;
  float4 wq4 = *(const float4*)(wq + c * 4);
  float4 wk4 = *(const float4*)(wk + c * 4);
  float4 wv4 = *(const float4*)(wv + c * 4);
  float qw[4] = {wq4.x, wq4.y, wq4.z, wq4.w};
  float kw[4] = {wk4.x, wk4.y, wk4.z, wk4.w};
  float vw[4] = {wv4.x, wv4.y, wv4.z, wv4.w};
  float aq = 0.f, ak = 0.f, av = 0.f;
#pragma unroll
  for (int j = 0; j < 4; ++j) {
    int ls = l - 3 + j;
    if (ls >= 0) {
      size_t rb = (size_t)ls * 3072;
      aq = fmaf(qw[j], p[rb], aq);
      ak = fmaf(kw[j], p[rb + 1024], ak);
      av = fmaf(vw[j], p[rb + 2048], av);
    }
  }
  float qv = siluf_(aq), kv = siluf_(ak), vv = siluf_(av);
  float sq = qv * qv, sk = kv * kv;
  float sv = vv, s2v = vv * vv;
#pragma unroll
  for (int off = 32; off; off >>= 1) {
    sq += __shfl_down(sq, off);
    sk += __shfl_down(sk, off);
    sv += __shfl_down(sv, off);
    s2v += __shfl_down(s2v, off);
  }
  __shared__ float rq_[4], rk_[4], rv_[4][2];
  int w = t >> 6;
  if ((t & 63) == 0) {
    rq_[w] = sq; rk_[w] = sk;
    rv_[w][0] = sv; rv_[w][1] = s2v;
  }
  __syncthreads();
  sq = rq_[0] + rq_[1] + rq_[2] + rq_[3];
  sk = rk_[0] + rk_[1] + rk_[2] + rk_[3];
  float rq = rsqrtf(sq + 1e-6f), rk = rsqrtf(sk + 1e-6f);
  float bt = beta_g[i];
  size_t base = (size_t)i * 256 + t;
  qn[base] = qv * rq;
  kn[base] = kv * rk;
  kb[base] = kv * rk * bt;
  vb[base] = vv * bt;
  v_out[base] = vv;
  if (t == 0) {
    float svt  = rv_[0][0] + rv_[1][0] + rv_[2][0] + rv_[3][0];
    float s2vt = rv_[0][1] + rv_[1][1] + rv_[2][1] + rv_[3][1];
    float mean = svt * (1.f / 256.f);
    float var  = s2vt * (1.f / 256.f) - mean * mean;
    size_t gb = (size_t)(b * Ls + l) * 1056 + 1024;
    gin[gb + 24 + h] = f2bf(mean);
    gin[gb + 28 + h] = f2bf(sqrtf(fmaxf(var, 1e-6f)));
  }
}

// ------- per (b,h,chunk) MFMA: Gram, substitution, w/u applies -------------
__global__ __launch_bounds__(256) void chunk_prep(
    const float* __restrict__ kb, const float* __restrict__ kn,
    const float* __restrict__ qn, const float* __restrict__ vb,
    float* __restrict__ attn_g, float* __restrict__ u_out,
    ushort_t* __restrict__ wn_bf, ushort_t* __restrict__ q_bf,
    ushort_t* __restrict__ knT_bf, ushort_t* __restrict__ kn_bf)
{
  __shared__ float Am[32][33];
  __shared__ float Tm[32][36];
  __shared__ ushort_t KT_hi[256][40];
  __shared__ ushort_t KT_lo[256][40];
  int t = threadIdx.x;
  int cc = blockIdx.x & 63, bh = blockIdx.x >> 6;
  size_t gbase = ((size_t)bh * Ls + cc * 32) * 256;
  int wv = t >> 6, lane = t & 63;
  int l16 = lane & 15, quad = lane >> 4;
  int mi = wv >> 1, ni = wv & 1;

  floatx4 Aacc = {0.f,0.f,0.f,0.f}, Qacc = {0.f,0.f,0.f,0.f};
  {
    int mrow = mi * 16 + l16, nrow = ni * 16 + l16;
    const float* kbp = kb + gbase + (size_t)mrow * 256;
    const float* qnp = qn + gbase + (size_t)mrow * 256;
    const float* knp = kn + gbase + (size_t)nrow * 256;
#pragma unroll
    for (int ks = 0; ks < 8; ++ks) {
      int koff = ks * 32 + quad * 8;
      short8 kbh, kbl, qnh, qnl, knh, knl;
      cvt8(*(const float4*)(kbp + koff), *(const float4*)(kbp + koff + 4), kbh, kbl);
      cvt8(*(const float4*)(qnp + koff), *(const float4*)(qnp + koff + 4), qnh, qnl);
      cvt8(*(const float4*)(knp + koff), *(const float4*)(knp + koff + 4), knh, knl);
      Aacc = __builtin_amdgcn_mfma_f32_16x16x32_bf16(kbh, knh, Aacc, 0, 0, 0);
      Aacc = __builtin_amdgcn_mfma_f32_16x16x32_bf16(kbh, knl, Aacc, 0, 0, 0);
      Aacc = __builtin_amdgcn_mfma_f32_16x16x32_bf16(kbl, knh, Aacc, 0, 0, 0);
      Qacc = __builtin_amdgcn_mfma_f32_16x16x32_bf16(qnh, knh, Qacc, 0, 0, 0);
      Qacc = __builtin_amdgcn_mfma_f32_16x16x32_bf16(qnh, knl, Qacc, 0, 0, 0);
      Qacc = __builtin_amdgcn_mfma_f32_16x16x32_bf16(qnl, knh, Qacc, 0, 0, 0);
      if (ni == 0)
        *(uint4*)(q_bf + gbase + (size_t)mrow * 256 + koff) = *(uint4*)&qnh;
      if (mi == 0)
        *(uint4*)(kn_bf + gbase + (size_t)nrow * 256 + koff) = *(uint4*)&knh;
    }
  }
  float* ag = attn_g + ((size_t)bh * 64 + cc) * 1024;
#pragma unroll
  for (int r = 0; r < 4; ++r) {
    int row = mi * 16 + quad * 4 + r, col = ni * 16 + l16;
    Am[row][col] = (col < row) ? Aacc[r] : 0.f;
    ag[row * 32 + col] = (col <= row) ? Qacc[r] : 0.f;
  }
  __syncthreads();

  if (wv == 0) {
    if (t < 32) {
#pragma unroll
      for (int i = 0; i < 32; ++i) Tm[i][t] = (i == t) ? 1.f : 0.f;
      for (int i2 = 1; i2 < 32; ++i2) {
        if (t < i2) {
          float s = 0.f;
          for (int m2 = t; m2 < i2; ++m2) s = fmaf(Am[i2][m2], Tm[m2][t], s);
          Tm[i2][t] = -s;
        }
      }
    }
  } else {
    int base = t - 64;
#pragma unroll
    for (int pass = 0; pass < 2; ++pass) {
      int d = base + pass * 192;
      if (d < 256) {
        u32 hp[16], lp[16], kp2[16];
#pragma unroll
        for (int m2 = 0; m2 < 16; ++m2) {
          float f0 = kb[gbase + (size_t)(2 * m2) * 256 + d];
          float f1 = kb[gbase + (size_t)(2 * m2 + 1) * 256 + d];
          ushort_t h0 = f2bf(f0), h1 = f2bf(f1);
          hp[m2] = (u32)h0 | ((u32)h1 << 16);
          lp[m2] = (u32)f2bf(f0 - bf2f(h0)) | ((u32)f2bf(f1 - bf2f(h1)) << 16);
          float g0 = kn[gbase + (size_t)(2 * m2) * 256 + d];
          float g1 = kn[gbase + (size_t)(2 * m2 + 1) * 256 + d];
          kp2[m2] = (u32)f2bf(g0) | ((u32)f2bf(g1) << 16);
        }
#pragma unroll
        for (int q2 = 0; q2 < 4; ++q2) {
          *(uint4*)&KT_hi[d][q2 * 8] = *(uint4*)&hp[q2 * 4];
          *(uint4*)&KT_lo[d][q2 * 8] = *(uint4*)&lp[q2 * 4];
          *(uint4*)(knT_bf + gbase + (size_t)d * 32 + q2 * 8) = *(uint4*)&kp2[q2 * 4];
        }
      }
    }
  }
  __syncthreads();

  int lt = wv & 1, dgrp = wv >> 1;
  short8 Th, Tl;
  {
    int lrow = lt * 16 + l16;
    cvt8(*(const float4*)&Tm[lrow][quad * 8],
         *(const float4*)&Tm[lrow][quad * 8 + 4], Th, Tl);
  }
#pragma unroll
  for (int j = 0; j < 8; ++j) {
    int dt = dgrp * 8 + j;
    short8 Bh = *(const short8*)&KT_hi[dt * 16 + l16][quad * 8];
    short8 Bl = *(const short8*)&KT_lo[dt * 16 + l16][quad * 8];
    floatx4 acc = {0.f,0.f,0.f,0.f};
    acc = __builtin_amdgcn_mfma_f32_16x16x32_bf16(Th, Bh, acc, 0, 0, 0);
    acc = __builtin_amdgcn_mfma_f32_16x16x32_bf16(Th, Bl, acc, 0, 0, 0);
    acc = __builtin_amdgcn_mfma_f32_16x16x32_bf16(Tl, Bh, acc, 0, 0, 0);
#pragma unroll
    for (int r = 0; r < 4; ++r) {
      int row = lt * 16 + quad * 4 + r;
      wn_bf[gbase + (size_t)row * 256 + dt * 16 + l16] = f2bf(-acc[r]);
    }
  }
  __syncthreads();

  {
    int d = t;
    u32 hp[16], lp[16];
#pragma unroll
    for (int m2 = 0; m2 < 16; ++m2) {
      float f0 = vb[gbase + (size_t)(2 * m2) * 256 + d];
      float f1 = vb[gbase + (size_t)(2 * m2 + 1) * 256 + d];
      ushort_t h0 = f2bf(f0), h1 = f2bf(f1);
      hp[m2] = (u32)h0 | ((u32)h1 << 16);
      lp[m2] = (u32)f2bf(f0 - bf2f(h0)) | ((u32)f2bf(f1 - bf2f(h1)) << 16);
    }
#pragma unroll
    for (int q2 = 0; q2 < 4; ++q2) {
      *(uint4*)&KT_hi[d][q2 * 8] = *(uint4*)&hp[q2 * 4];
      *(uint4*)&KT_lo[d][q2 * 8] = *(uint4*)&lp[q2 * 4];
    }
  }
  __syncthreads();

#pragma unroll
  for (int j = 0; j < 8; ++j) {
    int dt = dgrp * 8 + j;
    short8 Bh = *(const short8*)&KT_hi[dt * 16 + l16][quad * 8];
    short8 Bl = *(const short8*)&KT_lo[dt * 16 + l16][quad * 8];
    floatx4 acc = {0.f,0.f,0.f,0.f};
    acc = __builtin_amdgcn_mfma_f32_16x16x32_bf16(Th, Bh, acc, 0, 0, 0);
    acc = __builtin_amdgcn_mfma_f32_16x16x32_bf16(Th, Bl, acc, 0, 0, 0);
    acc = __builtin_amdgcn_mfma_f32_16x16x32_bf16(Tl, Bh, acc, 0, 0, 0);
#pragma unroll
    for (int r = 0; r < 4; ++r) {
      int row = lt * 16 + quad * 4 + r;
      u_out[gbase + (size_t)row * 256 + dt * 16 + l16] = acc[r];
    }
  }
}

// ------- cross matrices per super-chunk: X = wn1 @ kn0^T, Y = q1 @ kn0^T ---
__global__ __launch_bounds__(256) void cross_prep(
    const ushort_t* __restrict__ wn_bf, const ushort_t* __restrict__ q_bf,
    const ushort_t* __restrict__ kn_bf,
    float* __restrict__ X_g, float* __restrict__ Y_g)
{
  int t = threadIdx.x;
  int sc = blockIdx.x & 31, bh = blockIdx.x >> 5;
  int wv = t >> 6, lane = t & 63;
  int l16 = lane & 15, quad = lane >> 4;
  int mi = wv >> 1, ni = wv & 1;
  size_t base = (size_t)bh * Ls * 256;
  size_t r1 = base + (size_t)(sc * 64 + 32 + mi * 16 + l16) * 256;  // chunk 2sc+1 rows
  size_t r0 = base + (size_t)(sc * 64 + ni * 16 + l16) * 256;       // chunk 2sc rows
  floatx4 Xacc = {0.f,0.f,0.f,0.f}, Yacc = {0.f,0.f,0.f,0.f};
#pragma unroll
  for (int ks = 0; ks < 8; ++ks) {
    int ko = ks * 32 + quad * 8;
    short8 aw = *(const short8*)(wn_bf + r1 + ko);
    short8 aq = *(const short8*)(q_bf  + r1 + ko);
    short8 bk = *(const short8*)(kn_bf + r0 + ko);
    Xacc = __builtin_amdgcn_mfma_f32_16x16x32_bf16(aw, bk, Xacc, 0, 0, 0);
    Yacc = __builtin_amdgcn_mfma_f32_16x16x32_bf16(aq, bk, Yacc, 0, 0, 0);
  }
  float* xo = X_g + ((size_t)bh * 32 + sc) * 1024;
  float* yo = Y_g + ((size_t)bh * 32 + sc) * 1024;
#pragma unroll
  for (int r = 0; r < 4; ++r) {
    int row = mi * 16 + quad * 4 + r, col = ni * 16 + l16;
    xo[row * 32 + col] = Xacc[r];
    yo[row * 32 + col] = Yacc[r];
  }
}

// ------- merged: chain (0-127) + FIR+stats (128-2175) + weight convT -------
__global__ __launch_bounds__(256, 1) void delta_fir(
    const ushort_t* __restrict__ wn_bf, const ushort_t* __restrict__ q_bf,
    const ushort_t* __restrict__ knT_bf, const float* __restrict__ attn_g,
    const float* __restrict__ u_g, const float* __restrict__ X_g,
    const float* __restrict__ Y_g, float* __restrict__ delta_g,
    const float* __restrict__ v, const float* __restrict__ wlg,
    const float* __restrict__ wsg, float* __restrict__ firl,
    float* __restrict__ firs,
    const float* __restrict__ mlpw1, ushort_t* __restrict__ w1_t,
    const float* __restrict__ Wo, ushort_t* __restrict__ wo_t,
    ushort_t* __restrict__ gin)
{
  __shared__ __attribute__((aligned(16))) char smem[72704];
  int t = threadIdx.x;

  if (blockIdx.x >= 2176) {
    // -------- input-only weight transposes on idle CUs --------
    ushort_t (*tile)[33] = (ushort_t(*)[33])smem;
    const float* W; ushort_t* out; int Kq, Nq, n0, k0;
    if (blockIdx.x < 4288) {          // mlpw1 [1056][2048] -> w1_t [2048][1056]
      int local = blockIdx.x - 2176;  // 64 x 33
      W = mlpw1; out = w1_t; Kq = 1056; Nq = 2048;
      n0 = (local & 63) * 32; k0 = (local >> 6) * 32;
    } else {                          // Wo [1024][1024] -> wo_t [1024][1024]
      int local = blockIdx.x - 4288;  // 32 x 32
      W = Wo; out = wo_t; Kq = 1024; Nq = 1024;
      n0 = (local & 31) * 32; k0 = (local >> 5) * 32;
    }
    int tx = t & 31, ty = t >> 5;
#pragma unroll
    for (int r = 0; r < 32; r += 8)
      tile[ty + r][tx] = f2bf(W[(size_t)(k0 + ty + r) * Nq + n0 + tx]);
    __syncthreads();
#pragma unroll
    for (int r = 0; r < 32; r += 8)
      out[(size_t)(n0 + ty + r) * Kq + k0 + tx] = tile[tx][ty + r];
    return;
  }

  if (blockIdx.x >= 128) {
    // ---------------- FIR part + firs/firl stats ----------------
    float (*vt)[71] = (float(*)[71])smem;
    int bid = blockIdx.x - 128;
    int lt = bid & 255;
    int bh = bid >> 8;
    int b = bh >> 2, h = bh & 3;
    int l0 = lt * 8;
    const float* vp = v + (size_t)bh * Ls * 256;
    for (int r = 0; r < 70; ++r) {
      int ls = l0 - 62 + r;
      vt[t][r] = (ls >= 0) ? vp[(size_t)ls * 256 + t] : 0.f;
    }
    float TL[63], TS3[3];
#pragma unroll
    for (int j = 0; j < 63; ++j) TL[j] = wlg[((size_t)h * 256 + t) * 63 + j];
#pragma unroll
    for (int j = 0; j < 3; ++j) TS3[j] = wsg[((size_t)h * 256 + t) * 3 + j];
    __syncthreads();
    float aL[8] = {0,0,0,0,0,0,0,0}, aS[8] = {0,0,0,0,0,0,0,0};
#pragma unroll
    for (int r = 0; r < 70; ++r) {
      float vm = vt[t][r];
#pragma unroll
      for (int p = 0; p < 8; ++p) {
        int jl = r - p;
        if (jl >= 0 && jl < 63) aL[p] = fmaf(vm, TL[jl], aL[p]);
        int jssrc = r - 60 - p;
        if (jssrc >= 0 && jssrc < 3) aS[p] = fmaf(vm, TS3[jssrc], aS[p]);
      }
    }
#pragma unroll
    for (int p = 0; p < 8; ++p) {
      int l = l0 + p;
      size_t ob = (((size_t)b * Ls + l) * NH + h) * 256 + t;
      firl[ob] = aL[p];
      firs[ob] = aS[p];
    }
    // ---- producer-side stats (values in regs; vt dead -> reuse smem) ----
    __syncthreads();
    float (*red)[8][2][2] = (float(*)[8][2][2])smem;  // [wave][p][br][moment]
    int wv_ = t >> 6, lane_ = t & 63;
#pragma unroll
    for (int p = 0; p < 8; ++p) {
      float sS = aS[p], s2S = aS[p] * aS[p];
      float sL = aL[p], s2L = aL[p] * aL[p];
#pragma unroll
      for (int off = 32; off; off >>= 1) {
        sS += __shfl_down(sS, off);   s2S += __shfl_down(s2S, off);
        sL += __shfl_down(sL, off);   s2L += __shfl_down(s2L, off);
      }
      if (lane_ == 0) {
        red[wv_][p][0][0] = sS; red[wv_][p][0][1] = s2S;
        red[wv_][p][1][0] = sL; red[wv_][p][1][1] = s2L;
      }
    }
    __syncthreads();
    if (t < 16) {
      int p = t >> 1, br = t & 1;    // br0 = firs, br1 = firl
      float s = red[0][p][br][0] + red[1][p][br][0]
              + red[2][p][br][0] + red[3][p][br][0];
      float s2 = red[0][p][br][1] + red[1][p][br][1]
               + red[2][p][br][1] + red[3][p][br][1];
      float mean = s * (1.f / 256.f);
      float var = s2 * (1.f / 256.f) - mean * mean;
      int l = l0 + p;
      size_t gb = (size_t)(b * Ls + l) * 1056 + 1024 + br * 8;
      gin[gb + h] = f2bf(mean);
      gin[gb + 4 + h] = f2bf(sqrtf(fmaxf(var, 1e-6f)));
    }
    return;
  }

  // ---------------- chain part (m=2 super-chunks) ----------------
  ushort_t (*Shi)[264] = (ushort_t(*)[264])(smem);
  ushort_t (*Slo)[264] = (ushort_t(*)[264])(smem + 8448);
  float (*u2L0)[17] = (float(*)[17])(smem + 16896);
  float (*u2L1)[17] = (float(*)[17])(smem + 19072);
  int bh = blockIdx.x & 7, g = blockIdx.x >> 3;
  int b = bh >> 2, h = bh & 3;
  int wv = t >> 6, lane = t & 63;
  int lquad = lane >> 4, l16 = lane & 15;
  int j0 = g * 16;
  int Mt = wv & 1;
  bool isU = (wv < 2);
  const ushort_t* wp = wn_bf + (size_t)bh * Ls * 256;
  const ushort_t* qp = q_bf  + (size_t)bh * Ls * 256;
  const ushort_t* ap = (isU ? wp : qp) + (size_t)(Mt * 16 + l16) * 256;
  const ushort_t* kr = knT_bf + (size_t)bh * Ls * 256 + (size_t)l16 * 32 + lquad * 8;
  const float* urow = u_g + (size_t)bh * Ls * 256
                    + (size_t)(Mt * 16 + lquad * 4) * 256 + j0 + l16;
  const float* arp = attn_g + (size_t)bh * 64 * 1024
                   + (size_t)(Mt * 16 + l16) * 32 + lquad * 8;
  const float* xrp = (isU ? X_g : Y_g) + (size_t)bh * 32768
                   + (size_t)(Mt * 16 + l16) * 32 + lquad * 8;

  floatx4 Sacc[4], SaccL[4];
#pragma unroll
  for (int i = 0; i < 4; ++i)
#pragma unroll
    for (int r = 0; r < 4; ++r) { Sacc[i][r] = 0.f; SaccL[i][r] = 0.f; }
  for (int i = t; i < 4224; i += 256) ((u32*)smem)[i] = 0;

  // prologue: super-chunk 0, sub-chunk 0 operands
  short8 a0[8], k0[4];
  floatx4 u0 = {0.f, 0.f, 0.f, 0.f};
  float4 at0a = {0,0,0,0}, at0b = {0,0,0,0};
#pragma unroll
  for (int ks = 0; ks < 8; ++ks)
    a0[ks] = *(const short8*)(ap + ks * 32 + lquad * 8);
#pragma unroll
  for (int i = 0; i < 4; ++i)
    k0[i] = *(const short8*)(kr + (size_t)(wv * 4 + i) * 512);
  if (isU) {
#pragma unroll
    for (int r = 0; r < 4; ++r) u0[r] = urow[(size_t)r * 256];
  } else {
    at0a = *(const float4*)(arp);
    at0b = *(const float4*)(arp + 4);
  }
  wave_barrier();

  for (int sc = 0; sc < 32; ++sc) {
    size_t cb1 = (size_t)sc * 16384 + 8192;
    size_t nb0 = (size_t)(sc + 1) * 16384;
    bool hasN = (sc + 1 < 32);

    // sub-chunk1 operands + cross matrix (used mid-iteration; latency covered)
    short8 a1[8], k1[4];
    floatx4 u1 = {0.f, 0.f, 0.f, 0.f};
    float4 at1a = {0,0,0,0}, at1b = {0,0,0,0};
#pragma unroll
    for (int ks = 0; ks < 8; ++ks)
      a1[ks] = *(const short8*)(ap + cb1 + ks * 32 + lquad * 8);
#pragma unroll
    for (int i = 0; i < 4; ++i)
      k1[i] = *(const short8*)(kr + cb1 + (size_t)(wv * 4 + i) * 512);
    if (isU) {
#pragma unroll
      for (int r = 0; r < 4; ++r) u1[r] = urow[cb1 + (size_t)r * 256];
    } else {
      size_t na = (size_t)(2 * sc + 1) * 1024;
      at1a = *(const float4*)(arp + na);
      at1b = *(const float4*)(arp + na + 4);
    }
    float4 xa = *(const float4*)(xrp + (size_t)sc * 1024);
    float4 xb = *(const float4*)(xrp + (size_t)sc * 1024 + 4);

    // ---- sub-chunk 0: u2_0 (isU) / po_0 (o) against S0 ----
    floatx4 acc0;
    if (isU) {
      floatx4 A0 = u0, A1 = {0,0,0,0}, A2 = {0,0,0,0}, A3 = {0,0,0,0};
#pragma unroll
      for (int ks = 0; ks < 8; ++ks) {
        short8 sh = *(const short8*)&Shi[l16][ks * 32 + lquad * 8];
        short8 sl = *(const short8*)&Slo[l16][ks * 32 + lquad * 8];
        if (ks & 1) {
          A1 = __builtin_amdgcn_mfma_f32_16x16x32_bf16(a0[ks], sh, A1, 0, 0, 0);
          A3 = __builtin_amdgcn_mfma_f32_16x16x32_bf16(a0[ks], sl, A3, 0, 0, 0);
        } else {
          A0 = __builtin_amdgcn_mfma_f32_16x16x32_bf16(a0[ks], sh, A0, 0, 0, 0);
          A2 = __builtin_amdgcn_mfma_f32_16x16x32_bf16(a0[ks], sl, A2, 0, 0, 0);
        }
      }
#pragma unroll
      for (int r = 0; r < 4; ++r) acc0[r] = (A0[r] + A1[r]) + (A2[r] + A3[r]);
#pragma unroll
      for (int r = 0; r < 4; ++r)
        u2L0[Mt * 16 + lquad * 4 + r][l16] = acc0[r];
    } else {
      floatx4 A0 = {0,0,0,0}, A1 = {0,0,0,0};
#pragma unroll
      for (int ks = 0; ks < 8; ++ks) {
        short8 sh = *(const short8*)&Shi[l16][ks * 32 + lquad * 8];
        if (ks & 1) A1 = __builtin_amdgcn_mfma_f32_16x16x32_bf16(a0[ks], sh, A1, 0, 0, 0);
        else        A0 = __builtin_amdgcn_mfma_f32_16x16x32_bf16(a0[ks], sh, A0, 0, 0, 0);
      }
#pragma unroll
      for (int r = 0; r < 4; ++r) acc0[r] = A0[r] + A1[r];
    }
    // prefetch next-super-chunk a0 (a0 regs dead; stays in flight across
    // the raw barriers below -> ~full iteration of latency cover)
    if (hasN) {
#pragma unroll
      for (int ks = 0; ks < 8; ++ks)
        a0[ks] = *(const short8*)(ap + nb0 + ks * 32 + lquad * 8);
    }
    wave_barrier();                          // u2_0 visible

    short8 uh0, ul0;
#pragma unroll
    for (int j = 0; j < 8; ++j) {
      float f = u2L0[lquad * 8 + j][l16];
      ushort_t hi = f2bf(f);
      uh0[j] = (short)hi;
      ul0[j] = (short)f2bf(f - bf2f(hi));
    }
#pragma unroll
    for (int i = 0; i < 4; ++i) {
      Sacc[i]  = __builtin_amdgcn_mfma_f32_16x16x32_bf16(k0[i], uh0, Sacc[i], 0, 0, 0);
      SaccL[i] = __builtin_amdgcn_mfma_f32_16x16x32_bf16(k0[i], ul0, SaccL[i], 0, 0, 0);
    }
    if (hasN) {
#pragma unroll
      for (int i = 0; i < 4; ++i)
        k0[i] = *(const short8*)(kr + nb0 + (size_t)(wv * 4 + i) * 512);
    }

    // ---- sub-chunk 1: u2_1 = u1 + wn1@S0 + X@u2_0 / o path ----
    floatx4 acc1;
    if (isU) {
      floatx4 A0 = u1, A1 = {0,0,0,0}, A2 = {0,0,0,0}, A3 = {0,0,0,0};
#pragma unroll
      for (int ks = 0; ks < 8; ++ks) {
        short8 sh = *(const short8*)&Shi[l16][ks * 32 + lquad * 8];
        short8 sl = *(const short8*)&Slo[l16][ks * 32 + lquad * 8];
        if (ks & 1) {
          A1 = __builtin_amdgcn_mfma_f32_16x16x32_bf16(a1[ks], sh, A1, 0, 0, 0);
          A3 = __builtin_amdgcn_mfma_f32_16x16x32_bf16(a1[ks], sl, A3, 0, 0, 0);
        } else {
          A0 = __builtin_amdgcn_mfma_f32_16x16x32_bf16(a1[ks], sh, A0, 0, 0, 0);
          A2 = __builtin_amdgcn_mfma_f32_16x16x32_bf16(a1[ks], sl, A2, 0, 0, 0);
        }
      }
      short8 Xh, Xl;
      cvt8(xa, xb, Xh, Xl);
      A0 = __builtin_amdgcn_mfma_f32_16x16x32_bf16(Xh, uh0, A0, 0, 0, 0);
      A1 = __builtin_amdgcn_mfma_f32_16x16x32_bf16(Xh, ul0, A1, 0, 0, 0);
      A2 = __builtin_amdgcn_mfma_f32_16x16x32_bf16(Xl, uh0, A2, 0, 0, 0);
#pragma unroll
      for (int r = 0; r < 4; ++r) acc1[r] = (A0[r] + A1[r]) + (A2[r] + A3[r]);
#pragma unroll
      for (int r = 0; r < 4; ++r)
        u2L1[Mt * 16 + lquad * 4 + r][l16] = acc1[r];
      if (hasN) {
#pragma unroll
        for (int r = 0; r < 4; ++r) u0[r] = urow[nb0 + (size_t)r * 256];
      }
    } else {
      // o_0 = po_0 + attn_0 @ u2_0 -> store
      short8 ath, atl;
      cvt8(at0a, at0b, ath, atl);
      acc0 = __builtin_amdgcn_mfma_f32_16x16x32_bf16(ath, uh0, acc0, 0, 0, 0);
      acc0 = __builtin_amdgcn_mfma_f32_16x16x32_bf16(ath, ul0, acc0, 0, 0, 0);
      acc0 = __builtin_amdgcn_mfma_f32_16x16x32_bf16(atl, uh0, acc0, 0, 0, 0);
#pragma unroll
      for (int r = 0; r < 4; ++r) {
        int l = sc * 64 + Mt * 16 + lquad * 4 + r;
        delta_g[(((size_t)b * Ls + l) * NH + h) * 256 + j0 + l16] = acc0[r];
      }
      // po_1 = q1 @ Shi(S0) + Y @ u2_0
      floatx4 A0 = {0,0,0,0}, A1 = {0,0,0,0};
#pragma unroll
      for (int ks = 0; ks < 8; ++ks) {
        short8 sh = *(const short8*)&Shi[l16][ks * 32 + lquad * 8];
        if (ks & 1) A1 = __builtin_amdgcn_mfma_f32_16x16x32_bf16(a1[ks], sh, A1, 0, 0, 0);
        else        A0 = __builtin_amdgcn_mfma_f32_16x16x32_bf16(a1[ks], sh, A0, 0, 0, 0);
      }
      short8 Yh, Yl;
      cvt8(xa, xb, Yh, Yl);
      A0 = __builtin_amdgcn_mfma_f32_16x16x32_bf16(Yh, uh0, A0, 0, 0, 0);
      A1 = __builtin_amdgcn_mfma_f32_16x16x32_bf16(Yh, ul0, A1, 0, 0, 0);
      A0 = __builtin_amdgcn_mfma_f32_16x16x32_bf16(Yl, uh0, A0, 0, 0, 0);
#pragma unroll
      for (int r = 0; r < 4; ++r) acc1[r] = A0[r] + A1[r];
      if (hasN) {
        size_t na0 = (size_t)(2 * sc + 2) * 1024;
        at0a = *(const float4*)(arp + na0);
        at0b = *(const float4*)(arp + na0 + 4);
      }
    }
    wave_barrier();                          // u2_1 visible; all Shi/Slo reads done

    short8 uh1, ul1;
#pragma unroll
    for (int j = 0; j < 8; ++j) {
      float f = u2L1[lquad * 8 + j][l16];
      ushort_t hi = f2bf(f);
      uh1[j] = (short)hi;
      ul1[j] = (short)f2bf(f - bf2f(hi));
    }
#pragma unroll
    for (int i = 0; i < 4; ++i) {
      Sacc[i]  = __builtin_amdgcn_mfma_f32_16x16x32_bf16(k1[i], uh1, Sacc[i], 0, 0, 0);
      SaccL[i] = __builtin_amdgcn_mfma_f32_16x16x32_bf16(k1[i], ul1, SaccL[i], 0, 0, 0);
    }
    if (!isU) {
      short8 ath, atl;
      cvt8(at1a, at1b, ath, atl);
      acc1 = __builtin_amdgcn_mfma_f32_16x16x32_bf16(ath, uh1, acc1, 0, 0, 0);
      acc1 = __builtin_amdgcn_mfma_f32_16x16x32_bf16(ath, ul1, acc1, 0, 0, 0);
      acc1 = __builtin_amdgcn_mfma_f32_16x16x32_bf16(atl, uh1, acc1, 0, 0, 0);
#pragma unroll
      for (int r = 0; r < 4; ++r) {
        int l = sc * 64 + 32 + Mt * 16 + lquad * 4 + r;
        delta_g[(((size_t)b * Ls + l) * NH + h) * 256 + j0 + l16] = acc1[r];
      }
    }
    // S write-back (once per 64 tokens)
#pragma unroll
    for (int i = 0; i < 4; ++i) {
      int dk0 = (wv * 4 + i) * 16 + lquad * 4;
      ushort4 h4, l4;
      ushort_t* hp = (ushort_t*)&h4;
      ushort_t* lp = (ushort_t*)&l4;
#pragma unroll
      for (int r = 0; r < 4; ++r) {
        float sv = Sacc[i][r] + SaccL[i][r];
        ushort_t hi = f2bf(sv);
        hp[r] = hi;
        lp[r] = f2bf(sv - bf2f(hi));
      }
      *(ushort4*)&Shi[l16][dk0] = h4;
      *(ushort4*)&Slo[l16][dk0] = l4;
    }
    wave_barrier();                          // S visible
  }
}

// ------- gate_in: x copy + delta stats only --------------------------------
__global__ __launch_bounds__(256) void build_gate_in_bf(
    const float* __restrict__ x, const float* __restrict__ delta,
    ushort_t* __restrict__ gin)
{
  int mtok = blockIdx.x, t = threadIdx.x;
  float4 xv = *(const float4*)(x + (size_t)mtok * 1024 + t * 4);
  ushort4 xo = make_ushort4(f2bf(xv.x), f2bf(xv.y), f2bf(xv.z), f2bf(xv.w));
  *(ushort4*)(gin + (size_t)mtok * 1056 + t * 4) = xo;
  int w = t >> 6, lane = t & 63;
  float s = 0.f, s2 = 0.f;
#pragma unroll
  for (int r = 0; r < 4; ++r) {
    int d = lane + r * 64;
    float val = delta[(size_t)mtok * 1024 + w * 256 + d];
    s += val; s2 = fmaf(val, val, s2);
  }
#pragma unroll
  for (int off = 32; off; off >>= 1) {
    s += __shfl_down(s, off);
    s2 += __shfl_down(s2, off);
  }
  if (lane == 0) {
    float mean = s * (1.f / 256.f);
    float var = s2 * (1.f / 256.f) - mean * mean;
    gin[(size_t)mtok * 1056 + 1040 + w] = f2bf(mean);
    gin[(size_t)mtok * 1056 + 1044 + w] = f2bf(sqrtf(fmaxf(var, 1e-6f)));
  }
}

// ------- logits -> gates (bf16 hidden input) -------------------------------
__global__ __launch_bounds__(256) void mlp2_gates(
    const ushort_t* __restrict__ mh, const float* __restrict__ W2,
    const float* __restrict__ b2, const float* __restrict__ glt,
    float* __restrict__ gates)
{
  int mtok = blockIdx.x, t = threadIdx.x;
  float p[16];
#pragma unroll
  for (int j = 0; j < 16; ++j) p[j] = 0.f;
  for (int k = t; k < 2048; k += 256) {
    float hv = bf2f(mh[(size_t)mtok * 2048 + k]);
    const float* wr = W2 + (size_t)k * 16;
#pragma unroll
    for (int j4 = 0; j4 < 4; ++j4) {
      float4 w4 = *(const float4*)(wr + j4 * 4);
      p[j4*4+0] = fmaf(hv, w4.x, p[j4*4+0]);
      p[j4*4+1] = fmaf(hv, w4.y, p[j4*4+1]);
      p[j4*4+2] = fmaf(hv, w4.z, p[j4*4+2]);
      p[j4*4+3] = fmaf(hv, w4.w, p[j4*4+3]);
    }
  }
#pragma unroll
  for (int j = 0; j < 16; ++j)
#pragma unroll
    for (int off = 32; off; off >>= 1) p[j] += __shfl_down(p[j], off);
  __shared__ float red[4][16];
  __shared__ float zl[16];
  int w = t >> 6;
  if ((t & 63) == 0) {
#pragma unroll
    for (int j = 0; j < 16; ++j) red[w][j] = p[j];
  }
  __syncthreads();
  if (t < 16) {
    float tot = red[0][t] + red[1][t] + red[2][t] + red[3][t] + b2[t];
    float tempv = log1pf(expf(glt[t >> 2])) + 1e-4f;
    zl[t] = tot / tempv;
  }
  __syncthreads();
  if (t < 4) {
    float z0 = zl[t*4], z1 = zl[t*4+1], z2 = zl[t*4+2], z3 = zl[t*4+3];
    float mx = fmaxf(fmaxf(z0, z1), fmaxf(z2, z3));
    float e0 = expf(z0 - mx), e1 = expf(z1 - mx), e2 = expf(z2 - mx), e3 = expf(z3 - mx);
    float inv = 1.f / (e0 + e1 + e2 + e3);
    gates[(size_t)mtok * 16 + t * 4 + 0] = e0 * inv;
    gates[(size_t)mtok * 16 + t * 4 + 1] = e1 * inv;
    gates[(size_t)mtok * 16 + t * 4 + 2] = e2 * inv;
    gates[(size_t)mtok * 16 + t * 4 + 3] = e3 * inv;
  }
}

// ------- o = gated mix, RMSNorm -> bf16 ------------------------------------
__global__ __launch_bounds__(256) void combine_norm_bf(
    const float* __restrict__ firs, const float* __restrict__ firl,
    const float* __restrict__ delta, const float* __restrict__ v,
    const float* __restrict__ gates, const float* __restrict__ onw,
    ushort_t* __restrict__ o)
{
  int mh = blockIdx.x;
  int mtok = mh >> 2, h = mh & 3;
  int t = threadIdx.x;
  int b = mtok >> 11, l = mtok & 2047;
  const float* g = gates + (size_t)mtok * 16 + h * 4;
  float w0 = g[0], w1 = g[1], w2 = g[2], w3 = g[3];
  size_t tb = (size_t)mtok * 1024 + h * 256 + t;
  float val = w0 * firs[tb] + w1 * firl[tb] + w2 * delta[tb]
            + w3 * v[(((size_t)(b * NH + h)) * Ls + l) * 256 + t];
  float s2 = val * val;
#pragma unroll
  for (int off = 32; off; off >>= 1) s2 += __shfl_down(s2, off);
  __shared__ float r4[4];
  if ((t & 63) == 0) r4[t >> 6] = s2;
  __syncthreads();
  float tot = r4[0] + r4[1] + r4[2] + r4[3];
  float rms = rsqrtf(tot * (1.f / 256.f) + 1e-5f);
  o[tb] = f2bf(val * rms * onw[t]);
}

// ---------------------------------------------------------------------------
extern "C" void kernel_launch(void* const* d_in, const int* in_sizes, int n_in,
                              void* d_out, int out_size, void* d_ws, size_t ws_size,
                              hipStream_t stream) {
  const float* x     = (const float*)d_in[0];
  const float* Wq    = (const float*)d_in[1];
  const float* Wk    = (const float*)d_in[2];
  const float* Wv    = (const float*)d_in[3];
  const float* Wb    = (const float*)d_in[4];
  const float* convq = (const float*)d_in[5];
  const float* convk = (const float*)d_in[6];
  const float* convv = (const float*)d_in[7];
  const float* firsw = (const float*)d_in[8];
  const float* firlw = (const float*)d_in[9];
  const float* mlpw1 = (const float*)d_in[10];
  const float* mlpb1 = (const float*)d_in[11];
  const float* mlpw2 = (const float*)d_in[12];
  const float* mlpb2 = (const float*)d_in[13];
  const float* glt   = (const float*)d_in[14];
  const float* onw   = (const float*)d_in[15];
  const float* Wo    = (const float*)d_in[16];
  float* ws = (float*)d_ws;

  ushort_t* x_bf   = (ushort_t*)(ws + off_firs);
  ushort_t* Wqkv_t = (ushort_t*)(ws + off_firl);  // 3 x [1024][1024] contiguous
  ushort_t* gin_bf = (ushort_t*)(ws + off_gin2);  // never-aliased window
  ushort_t* w1_t   = (ushort_t*)(ws + off_k);     // kn dead after chunk_prep
  ushort_t* o_bf   = (ushort_t*)(ws + off_xv);
  ushort_t* Wo_t   = (ushort_t*)(ws + off_wot);   // never-aliased window
  ushort_t* mlph_bf= (ushort_t*)(ws + off_mlph);
  ushort_t* wn_bf  = (ushort_t*)(ws + off_firs);
  ushort_t* q_bf   = (ushort_t*)(ws + off_firs + 2097152);
  ushort_t* knT_bf = (ushort_t*)(ws + off_firl);
  ushort_t* kn_bf  = (ushort_t*)(ws + off_xq);    // x3 dead after conv_prep
  float* x3   = ws + off_xq;     // fused [4096][3072] spans xq/xk/xv
  float* kb_f = ws + off_gin;
  float* vb_f = ws + off_mlph;
  float* X_g  = ws + off_gin;            // kb dead after chunk_prep; 8*32*1024 f32
  float* Y_g  = ws + off_gin + 262144;
  float* firs_f = ws + off_xq;   // x3/kn_bf dead after cross_prep
  float* firl_f = ws + off_xk;

  dim3 blk(256);
  // fused q/k/v projection (one N=3072 GEMM) + beta
  to_bf16<<<2048, blk, 0, stream>>>(x, x_bf, 4194304);
  convT<<<dim3(32, 32), blk, 0, stream>>>(Wq, Wqkv_t, 1024, 1024);
  convT<<<dim3(32, 32), blk, 0, stream>>>(Wk, Wqkv_t + 1048576, 1024, 1024);
  convT<<<dim3(32, 32), blk, 0, stream>>>(Wv, Wqkv_t + 2097152, 1024, 1024);
  gemm_bf16<<<dim3(24, 32), blk, 0, stream>>>(x_bf, Wqkv_t, x3, 3072, 1024, nullptr, 0, 0);
  beta_sigmoid<<<4096, blk, 0, stream>>>(x, Wb, ws + off_beta);
  // fused conv4+silu + l2norm + beta products + v-stats (producer-side)
  conv_prep<<<16384, blk, 0, stream>>>(x3, convq, convk, convv, ws + off_beta,
                                       ws + off_q, ws + off_k, kb_f, vb_f,
                                       ws + off_v, gin_bf);
  // per-chunk T inverse, attn, u (->xv), bf16 {-w, q, knT, kn}
  chunk_prep<<<512, blk, 0, stream>>>(kb_f, ws + off_k, ws + off_q, vb_f,
                                      ws + off_attn, ws + off_xv, wn_bf, q_bf,
                                      knT_bf, kn_bf);
  // 32x32 cross matrices per super-chunk (X = wn1 kn0^T, Y = q1 kn0^T)
  cross_prep<<<256, blk, 0, stream>>>(wn_bf, q_bf, kn_bf, X_g, Y_g);
  // merged: chain + FIR(+firs/firl stats) + weight transposes (shadow)
  delta_fir<<<5312, blk, 0, stream>>>(wn_bf, q_bf, knT_bf, ws + off_attn,
                                      ws + off_xv, X_g, Y_g, ws + off_q,
                                      ws + off_v, firlw, firsw, firl_f, firs_f,
                                      mlpw1, w1_t, Wo, Wo_t, gin_bf);
  // gate input: x copy + delta stats only (firs/firl/v stats done upstream)
  build_gate_in_bf<<<4096, blk, 0, stream>>>(x, ws + off_q, gin_bf);
  gemm_bf16<<<dim3(16, 32), blk, 0, stream>>>(gin_bf, w1_t, (float*)mlph_bf,
                                              2048, 1056, mlpb1, 1, 1);
  mlp2_gates<<<4096, blk, 0, stream>>>(mlph_bf, mlpw2, mlpb2, glt, ws + off_gates);
  // combine + RMSNorm -> bf16, output projection (MFMA)
  combine_norm_bf<<<16384, blk, 0, stream>>>(firs_f, firl_f, ws + off_q,
                                             ws + off_v, ws + off_gates, onw, o_bf);
  gemm_bf16<<<dim3(8, 32), blk, 0, stream>>>(o_bf, Wo_t, (float*)d_out, 1024, 1024, nullptr, 0, 0);
}

// Round 13
// 540.823 us; speedup vs baseline: 1.1716x; 1.0056x over previous
//
#include <hip/hip_runtime.h>
#include <hip/hip_bf16.h>

// ---------------------------------------------------------------------------
// DeltaNet forward, round 20:
//  - Base: r19 (543.8us; producer-side stats validated -72us vs r18 in a
//    same-speed session).
//  - NEW: to_bf16 dual-writes x_bf AND gin[0:1024] (x's bf16 copy) --
//    elementwise-identical values, so build_gate_in_bf drops its 16MB x
//    re-read + 8.6MB gin write and shrinks to delta-stats only.
//    gin byte ranges remain disjoint across writers (x:0-1023,
//    firs:1024-1031, firl:1032-1039, delta:1040-1047, v:1048-1055).
// ---------------------------------------------------------------------------

#define DEVI __device__ __forceinline__
typedef unsigned int u32;
typedef unsigned short ushort_t;
typedef __attribute__((ext_vector_type(8))) short short8;
typedef __attribute__((ext_vector_type(4))) float floatx4;

constexpr int Ls = 2048, NH = 4;

// workspace offsets (floats)
constexpr size_t off_xq   = 0;         // x3 [m][3072] cols 0-1023 -> kn_bf -> firs
constexpr size_t off_xk   = 4194304;   // x3 cols 1024-2047 -> firl
constexpr size_t off_xv   = 8388608;   // x3 cols 2048-3071 -> u -> o_bf
constexpr size_t off_q    = 12582912;  // qn -> delta
constexpr size_t off_k    = 16777216;  // kn (dead after chunk_prep) -> w1_t
constexpr size_t off_v    = 20971520;  // v (alive to the end)
constexpr size_t off_beta = 25165824;  // beta (dead after conv_prep)
constexpr size_t off_attn = 25182208;  // attn (read by chain)
constexpr size_t off_firs = 25706496;  // x_bf -> {wn_bf, q_bf} (bf16)
constexpr size_t off_firl = 29900800;  // Wqkv_t -> knT_bf (bf16)
constexpr size_t off_gin  = 34095104;  // kb (f32) -> {X_g, Y_g}
constexpr size_t off_mlph = 38420480;  // vb (f32) -> mlph_bf
constexpr size_t off_wot  = 42614784;  // Wo_t (bf16, 0.52M fl) - never-aliased
constexpr size_t off_gin2 = 43139072;  // gin_bf (2.16M fl) - never-aliased
constexpr size_t off_gates= 46809088;  // gates

DEVI float sigmoidf_(float x) { return 1.f / (1.f + expf(-x)); }
DEVI float siluf_(float x) { return x / (1.f + expf(-x)); }
DEVI float geluf_(float x) { return 0.5f * x * (1.f + erff(x * 0.7071067811865476f)); }
DEVI ushort_t f2bf(float f) {
  union { float f; u32 u; } c{f};
  u32 r = (c.u + 0x7fffu + ((c.u >> 16) & 1u)) >> 16;
  return (ushort_t)r;
}
DEVI float bf2f(ushort_t h) {
  union { u32 u; float f; } c; c.u = ((u32)h) << 16; return c.f;
}
DEVI void cvt8(float4 a, float4 b, short8& hi, short8& lo) {
  float f[8] = {a.x,a.y,a.z,a.w,b.x,b.y,b.z,b.w};
#pragma unroll
  for (int j = 0; j < 8; ++j) {
    ushort_t h = f2bf(f[j]);
    hi[j] = (short)h;
    lo[j] = (short)f2bf(f[j] - bf2f(h));
  }
}
DEVI void async16(const void* g, void* l) {
  __builtin_amdgcn_global_load_lds(
      (const u32 __attribute__((address_space(1)))*)g,
      (u32 __attribute__((address_space(3)))*)l, 16, 0, 0);
}
// Raw workgroup barrier: waits LDS ops only (lgkmcnt), leaves global
// loads/stores (vmcnt) in flight. All cross-wave deps in the chain loop are
// LDS-only, and global data has no in-kernel consumers.
DEVI void wave_barrier() {
  __builtin_amdgcn_sched_barrier(0);
  asm volatile("s_waitcnt lgkmcnt(0)" ::: "memory");
  __builtin_amdgcn_s_barrier();
  __builtin_amdgcn_sched_barrier(0);
}

// ---------------- f32 -> bf16 (dual-write: x_bf + gin x-section) -----------
__global__ __launch_bounds__(256) void to_bf16(
    const float* __restrict__ in, ushort_t* __restrict__ out,
    ushort_t* __restrict__ gin, int n)
{
  int i = (blockIdx.x * 256 + threadIdx.x) * 8;
  if (i >= n) return;
  float4 a = *(const float4*)(in + i);
  float4 b = *(const float4*)(in + i + 4);
  ushort_t o[8] = { f2bf(a.x), f2bf(a.y), f2bf(a.z), f2bf(a.w),
                    f2bf(b.x), f2bf(b.y), f2bf(b.z), f2bf(b.w) };
  *(uint4*)(out + i) = *(uint4*)o;
  int mtok = i >> 10, col = i & 1023;
  *(uint4*)(gin + (size_t)mtok * 1056 + col) = *(uint4*)o;
}

// ---------------- f32 [K][N] -> bf16 [N][K] --------------------------------
__global__ __launch_bounds__(256) void convT(
    const float* __restrict__ W, ushort_t* __restrict__ out, int Kq, int Nq)
{
  __shared__ ushort_t tile[32][33];
  int n0 = blockIdx.x * 32, k0 = blockIdx.y * 32;
  int tx = threadIdx.x & 31, ty = threadIdx.x >> 5;
#pragma unroll
  for (int r = 0; r < 32; r += 8)
    tile[ty + r][tx] = f2bf(W[(size_t)(k0 + ty + r) * Nq + n0 + tx]);
  __syncthreads();
#pragma unroll
  for (int r = 0; r < 32; r += 8)
    out[(size_t)(n0 + ty + r) * Kq + k0 + tx] = tile[tx][ty + r];
}

// ---------------- bf16 MFMA GEMM -------------------------------------------
__global__ __launch_bounds__(256) void gemm_bf16(
    const ushort_t* __restrict__ A, const ushort_t* __restrict__ Bt,
    float* __restrict__ C, int Nq, int Kq,
    const float* __restrict__ bias, int act, int outbf)
{
  __shared__ ushort_t As[128 * 32];
  __shared__ ushort_t Bs[128 * 32];
  int t = threadIdx.x;
  int w = t >> 6, lane = t & 63;
  int m0 = blockIdx.y * 128, n0 = blockIdx.x * 128;
  floatx4 acc[4][4];
#pragma unroll
  for (int i = 0; i < 4; ++i)
#pragma unroll
    for (int j = 0; j < 4; ++j)
#pragma unroll
      for (int r = 0; r < 4; ++r) acc[i][j][r] = 0.f;

  int lrow = lane >> 2, lk8 = (lane & 3) * 8;
  for (int kt = 0; kt < Kq; kt += 32) {
#pragma unroll
    for (int r = 0; r < 2; ++r) {
      int seg = w * 2 + r;
      int row = seg * 16 + lrow;
      async16(A  + (size_t)(m0 + row) * Kq + kt + lk8, &As[seg * 512]);
      async16(Bt + (size_t)(n0 + row) * Kq + kt + lk8, &Bs[seg * 512]);
    }
    __syncthreads();
    short8 af[4], bf[4];
#pragma unroll
    for (int i = 0; i < 4; ++i) {
      int row = (w >> 1) * 64 + i * 16 + (lane & 15);
      af[i] = *(const short8*)&As[row * 32 + (lane >> 4) * 8];
    }
#pragma unroll
    for (int j = 0; j < 4; ++j) {
      int col = (w & 1) * 64 + j * 16 + (lane & 15);
      bf[j] = *(const short8*)&Bs[col * 32 + (lane >> 4) * 8];
    }
#pragma unroll
    for (int i = 0; i < 4; ++i)
#pragma unroll
      for (int j = 0; j < 4; ++j)
        acc[i][j] = __builtin_amdgcn_mfma_f32_16x16x32_bf16(af[i], bf[j], acc[i][j], 0, 0, 0);
    __syncthreads();
  }
#pragma unroll
  for (int i = 0; i < 4; ++i) {
    int rbase = m0 + (w >> 1) * 64 + i * 16 + ((lane >> 4) << 2);
#pragma unroll
    for (int j = 0; j < 4; ++j) {
      int col = n0 + (w & 1) * 64 + j * 16 + (lane & 15);
      float bv = act ? bias[col] : 0.f;
#pragma unroll
      for (int r = 0; r < 4; ++r) {
        float v = acc[i][j][r];
        if (act) v = geluf_(v + bv);
        if (outbf) ((ushort_t*)C)[(size_t)(rbase + r) * Nq + col] = f2bf(v);
        else       C[(size_t)(rbase + r) * Nq + col] = v;
      }
    }
  }
}

// ---------------- beta = sigmoid(x @ Wb) -----------------------------------
__global__ __launch_bounds__(256) void beta_sigmoid(
    const float* __restrict__ x, const float* __restrict__ Wb,
    float* __restrict__ beta)
{
  int mtok = blockIdx.x, t = threadIdx.x;
  int b = mtok >> 11, l = mtok & 2047;
  float a0 = 0, a1 = 0, a2 = 0, a3 = 0;
  for (int k = t; k < 1024; k += 256) {
    float xv = x[(size_t)mtok * 1024 + k];
    float4 w4 = *(const float4*)(Wb + k * 4);
    a0 = fmaf(xv, w4.x, a0); a1 = fmaf(xv, w4.y, a1);
    a2 = fmaf(xv, w4.z, a2); a3 = fmaf(xv, w4.w, a3);
  }
#pragma unroll
  for (int off = 32; off; off >>= 1) {
    a0 += __shfl_down(a0, off); a1 += __shfl_down(a1, off);
    a2 += __shfl_down(a2, off); a3 += __shfl_down(a3, off);
  }
  __shared__ float red[4][4];
  int w = t >> 6;
  if ((t & 63) == 0) { red[w][0] = a0; red[w][1] = a1; red[w][2] = a2; red[w][3] = a3; }
  __syncthreads();
  if (t < 4) {
    float s = red[0][t] + red[1][t] + red[2][t] + red[3][t];
    beta[((size_t)(b * NH + t)) * Ls + l] = sigmoidf_(s);
  }
}

// ------- fused conv4+silu + l2norm + beta + v-stats ------------------------
__global__ __launch_bounds__(256) void conv_prep(
    const float* __restrict__ x3, const float* __restrict__ wq,
    const float* __restrict__ wk, const float* __restrict__ wv,
    const float* __restrict__ beta_g,
    float* __restrict__ qn, float* __restrict__ kn,
    float* __restrict__ kb, float* __restrict__ vb,
    float* __restrict__ v_out, ushort_t* __restrict__ gin)
{
  int i = blockIdx.x;              // bh*Ls + l
  int t = threadIdx.x;
  int l = i & 2047, bh = i >> 11;
  int b = bh >> 2, h = bh & 3;
  int c = h * 256 + t;
  const float* p = x3 + ((size_t)b * Ls) * 3072 + c;
  float4 wq4 = *(const float4*)(wq + c * 4);
  float4 wk4 = *(const float4*)(wk + c * 4);
  float4 wv4 = *(const float4*)(wv + c * 4);
  float qw[4] = {wq4.x, wq4.y, wq4.z, wq4.w};
  float kw[4] = {wk4.x, wk4.y, wk4.z, wk4.w};
  float vw[4] = {wv4.x, wv4.y, wv4.z, wv4.w};
  float aq = 0.f, ak = 0.f, av = 0.f;
#pragma unroll
  for (int j = 0; j < 4; ++j) {
    int ls = l - 3 + j;
    if (ls >= 0) {
      size_t rb = (size_t)ls * 3072;
      aq = fmaf(qw[j], p[rb], aq);
      ak = fmaf(kw[j], p[rb + 1024], ak);
      av = fmaf(vw[j], p[rb + 2048], av);
    }
  }
  float qv = siluf_(aq), kv = siluf_(ak), vv = siluf_(av);
  float sq = qv * qv, sk = kv * kv;
  float sv = vv, s2v = vv * vv;
#pragma unroll
  for (int off = 32; off; off >>= 1) {
    sq += __shfl_down(sq, off);
    sk += __shfl_down(sk, off);
    sv += __shfl_down(sv, off);
    s2v += __shfl_down(s2v, off);
  }
  __shared__ float rq_[4], rk_[4], rv_[4][2];
  int w = t >> 6;
  if ((t & 63) == 0) {
    rq_[w] = sq; rk_[w] = sk;
    rv_[w][0] = sv; rv_[w][1] = s2v;
  }
  __syncthreads();
  sq = rq_[0] + rq_[1] + rq_[2] + rq_[3];
  sk = rk_[0] + rk_[1] + rk_[2] + rk_[3];
  float rq = rsqrtf(sq + 1e-6f), rk = rsqrtf(sk + 1e-6f);
  float bt = beta_g[i];
  size_t base = (size_t)i * 256 + t;
  qn[base] = qv * rq;
  kn[base] = kv * rk;
  kb[base] = kv * rk * bt;
  vb[base] = vv * bt;
  v_out[base] = vv;
  if (t == 0) {
    float svt  = rv_[0][0] + rv_[1][0] + rv_[2][0] + rv_[3][0];
    float s2vt = rv_[0][1] + rv_[1][1] + rv_[2][1] + rv_[3][1];
    float mean = svt * (1.f / 256.f);
    float var  = s2vt * (1.f / 256.f) - mean * mean;
    size_t gb = (size_t)(b * Ls + l) * 1056 + 1024;
    gin[gb + 24 + h] = f2bf(mean);
    gin[gb + 28 + h] = f2bf(sqrtf(fmaxf(var, 1e-6f)));
  }
}

// ------- per (b,h,chunk) MFMA: Gram, substitution, w/u applies -------------
__global__ __launch_bounds__(256) void chunk_prep(
    const float* __restrict__ kb, const float* __restrict__ kn,
    const float* __restrict__ qn, const float* __restrict__ vb,
    float* __restrict__ attn_g, float* __restrict__ u_out,
    ushort_t* __restrict__ wn_bf, ushort_t* __restrict__ q_bf,
    ushort_t* __restrict__ knT_bf, ushort_t* __restrict__ kn_bf)
{
  __shared__ float Am[32][33];
  __shared__ float Tm[32][36];
  __shared__ ushort_t KT_hi[256][40];
  __shared__ ushort_t KT_lo[256][40];
  int t = threadIdx.x;
  int cc = blockIdx.x & 63, bh = blockIdx.x >> 6;
  size_t gbase = ((size_t)bh * Ls + cc * 32) * 256;
  int wv = t >> 6, lane = t & 63;
  int l16 = lane & 15, quad = lane >> 4;
  int mi = wv >> 1, ni = wv & 1;

  floatx4 Aacc = {0.f,0.f,0.f,0.f}, Qacc = {0.f,0.f,0.f,0.f};
  {
    int mrow = mi * 16 + l16, nrow = ni * 16 + l16;
    const float* kbp = kb + gbase + (size_t)mrow * 256;
    const float* qnp = qn + gbase + (size_t)mrow * 256;
    const float* knp = kn + gbase + (size_t)nrow * 256;
#pragma unroll
    for (int ks = 0; ks < 8; ++ks) {
      int koff = ks * 32 + quad * 8;
      short8 kbh, kbl, qnh, qnl, knh, knl;
      cvt8(*(const float4*)(kbp + koff), *(const float4*)(kbp + koff + 4), kbh, kbl);
      cvt8(*(const float4*)(qnp + koff), *(const float4*)(qnp + koff + 4), qnh, qnl);
      cvt8(*(const float4*)(knp + koff), *(const float4*)(knp + koff + 4), knh, knl);
      Aacc = __builtin_amdgcn_mfma_f32_16x16x32_bf16(kbh, knh, Aacc, 0, 0, 0);
      Aacc = __builtin_amdgcn_mfma_f32_16x16x32_bf16(kbh, knl, Aacc, 0, 0, 0);
      Aacc = __builtin_amdgcn_mfma_f32_16x16x32_bf16(kbl, knh, Aacc, 0, 0, 0);
      Qacc = __builtin_amdgcn_mfma_f32_16x16x32_bf16(qnh, knh, Qacc, 0, 0, 0);
      Qacc = __builtin_amdgcn_mfma_f32_16x16x32_bf16(qnh, knl, Qacc, 0, 0, 0);
      Qacc = __builtin_amdgcn_mfma_f32_16x16x32_bf16(qnl, knh, Qacc, 0, 0, 0);
      if (ni == 0)
        *(uint4*)(q_bf + gbase + (size_t)mrow * 256 + koff) = *(uint4*)&qnh;
      if (mi == 0)
        *(uint4*)(kn_bf + gbase + (size_t)nrow * 256 + koff) = *(uint4*)&knh;
    }
  }
  float* ag = attn_g + ((size_t)bh * 64 + cc) * 1024;
#pragma unroll
  for (int r = 0; r < 4; ++r) {
    int row = mi * 16 + quad * 4 + r, col = ni * 16 + l16;
    Am[row][col] = (col < row) ? Aacc[r] : 0.f;
    ag[row * 32 + col] = (col <= row) ? Qacc[r] : 0.f;
  }
  __syncthreads();

  if (wv == 0) {
    if (t < 32) {
#pragma unroll
      for (int i = 0; i < 32; ++i) Tm[i][t] = (i == t) ? 1.f : 0.f;
      for (int i2 = 1; i2 < 32; ++i2) {
        if (t < i2) {
          float s = 0.f;
          for (int m2 = t; m2 < i2; ++m2) s = fmaf(Am[i2][m2], Tm[m2][t], s);
          Tm[i2][t] = -s;
        }
      }
    }
  } else {
    int base = t - 64;
#pragma unroll
    for (int pass = 0; pass < 2; ++pass) {
      int d = base + pass * 192;
      if (d < 256) {
        u32 hp[16], lp[16], kp2[16];
#pragma unroll
        for (int m2 = 0; m2 < 16; ++m2) {
          float f0 = kb[gbase + (size_t)(2 * m2) * 256 + d];
          float f1 = kb[gbase + (size_t)(2 * m2 + 1) * 256 + d];
          ushort_t h0 = f2bf(f0), h1 = f2bf(f1);
          hp[m2] = (u32)h0 | ((u32)h1 << 16);
          lp[m2] = (u32)f2bf(f0 - bf2f(h0)) | ((u32)f2bf(f1 - bf2f(h1)) << 16);
          float g0 = kn[gbase + (size_t)(2 * m2) * 256 + d];
          float g1 = kn[gbase + (size_t)(2 * m2 + 1) * 256 + d];
          kp2[m2] = (u32)f2bf(g0) | ((u32)f2bf(g1) << 16);
        }
#pragma unroll
        for (int q2 = 0; q2 < 4; ++q2) {
          *(uint4*)&KT_hi[d][q2 * 8] = *(uint4*)&hp[q2 * 4];
          *(uint4*)&KT_lo[d][q2 * 8] = *(uint4*)&lp[q2 * 4];
          *(uint4*)(knT_bf + gbase + (size_t)d * 32 + q2 * 8) = *(uint4*)&kp2[q2 * 4];
        }
      }
    }
  }
  __syncthreads();

  int lt = wv & 1, dgrp = wv >> 1;
  short8 Th, Tl;
  {
    int lrow = lt * 16 + l16;
    cvt8(*(const float4*)&Tm[lrow][quad * 8],
         *(const float4*)&Tm[lrow][quad * 8 + 4], Th, Tl);
  }
#pragma unroll
  for (int j = 0; j < 8; ++j) {
    int dt = dgrp * 8 + j;
    short8 Bh = *(const short8*)&KT_hi[dt * 16 + l16][quad * 8];
    short8 Bl = *(const short8*)&KT_lo[dt * 16 + l16][quad * 8];
    floatx4 acc = {0.f,0.f,0.f,0.f};
    acc = __builtin_amdgcn_mfma_f32_16x16x32_bf16(Th, Bh, acc, 0, 0, 0);
    acc = __builtin_amdgcn_mfma_f32_16x16x32_bf16(Th, Bl, acc, 0, 0, 0);
    acc = __builtin_amdgcn_mfma_f32_16x16x32_bf16(Tl, Bh, acc, 0, 0, 0);
#pragma unroll
    for (int r = 0; r < 4; ++r) {
      int row = lt * 16 + quad * 4 + r;
      wn_bf[gbase + (size_t)row * 256 + dt * 16 + l16] = f2bf(-acc[r]);
    }
  }
  __syncthreads();

  {
    int d = t;
    u32 hp[16], lp[16];
#pragma unroll
    for (int m2 = 0; m2 < 16; ++m2) {
      float f0 = vb[gbase + (size_t)(2 * m2) * 256 + d];
      float f1 = vb[gbase + (size_t)(2 * m2 + 1) * 256 + d];
      ushort_t h0 = f2bf(f0), h1 = f2bf(f1);
      hp[m2] = (u32)h0 | ((u32)h1 << 16);
      lp[m2] = (u32)f2bf(f0 - bf2f(h0)) | ((u32)f2bf(f1 - bf2f(h1)) << 16);
    }
#pragma unroll
    for (int q2 = 0; q2 < 4; ++q2) {
      *(uint4*)&KT_hi[d][q2 * 8] = *(uint4*)&hp[q2 * 4];
      *(uint4*)&KT_lo[d][q2 * 8] = *(uint4*)&lp[q2 * 4];
    }
  }
  __syncthreads();

#pragma unroll
  for (int j = 0; j < 8; ++j) {
    int dt = dgrp * 8 + j;
    short8 Bh = *(const short8*)&KT_hi[dt * 16 + l16][quad * 8];
    short8 Bl = *(const short8*)&KT_lo[dt * 16 + l16][quad * 8];
    floatx4 acc = {0.f,0.f,0.f,0.f};
    acc = __builtin_amdgcn_mfma_f32_16x16x32_bf16(Th, Bh, acc, 0, 0, 0);
    acc = __builtin_amdgcn_mfma_f32_16x16x32_bf16(Th, Bl, acc, 0, 0, 0);
    acc = __builtin_amdgcn_mfma_f32_16x16x32_bf16(Tl, Bh, acc, 0, 0, 0);
#pragma unroll
    for (int r = 0; r < 4; ++r) {
      int row = lt * 16 + quad * 4 + r;
      u_out[gbase + (size_t)row * 256 + dt * 16 + l16] = acc[r];
    }
  }
}

// ------- cross matrices per super-chunk: X = wn1 @ kn0^T, Y = q1 @ kn0^T ---
__global__ __launch_bounds__(256) void cross_prep(
    const ushort_t* __restrict__ wn_bf, const ushort_t* __restrict__ q_bf,
    const ushort_t* __restrict__ kn_bf,
    float* __restrict__ X_g, float* __restrict__ Y_g)
{
  int t = threadIdx.x;
  int sc = blockIdx.x & 31, bh = blockIdx.x >> 5;
  int wv = t >> 6, lane = t & 63;
  int l16 = lane & 15, quad = lane >> 4;
  int mi = wv >> 1, ni = wv & 1;
  size_t base = (size_t)bh * Ls * 256;
  size_t r1 = base + (size_t)(sc * 64 + 32 + mi * 16 + l16) * 256;  // chunk 2sc+1 rows
  size_t r0 = base + (size_t)(sc * 64 + ni * 16 + l16) * 256;       // chunk 2sc rows
  floatx4 Xacc = {0.f,0.f,0.f,0.f}, Yacc = {0.f,0.f,0.f,0.f};
#pragma unroll
  for (int ks = 0; ks < 8; ++ks) {
    int ko = ks * 32 + quad * 8;
    short8 aw = *(const short8*)(wn_bf + r1 + ko);
    short8 aq = *(const short8*)(q_bf  + r1 + ko);
    short8 bk = *(const short8*)(kn_bf + r0 + ko);
    Xacc = __builtin_amdgcn_mfma_f32_16x16x32_bf16(aw, bk, Xacc, 0, 0, 0);
    Yacc = __builtin_amdgcn_mfma_f32_16x16x32_bf16(aq, bk, Yacc, 0, 0, 0);
  }
  float* xo = X_g + ((size_t)bh * 32 + sc) * 1024;
  float* yo = Y_g + ((size_t)bh * 32 + sc) * 1024;
#pragma unroll
  for (int r = 0; r < 4; ++r) {
    int row = mi * 16 + quad * 4 + r, col = ni * 16 + l16;
    xo[row * 32 + col] = Xacc[r];
    yo[row * 32 + col] = Yacc[r];
  }
}

// ------- merged: chain (0-127) + FIR+stats (128-2175) + weight convT -------
__global__ __launch_bounds__(256, 1) void delta_fir(
    const ushort_t* __restrict__ wn_bf, const ushort_t* __restrict__ q_bf,
    const ushort_t* __restrict__ knT_bf, const float* __restrict__ attn_g,
    const float* __restrict__ u_g, const float* __restrict__ X_g,
    const float* __restrict__ Y_g, float* __restrict__ delta_g,
    const float* __restrict__ v, const float* __restrict__ wlg,
    const float* __restrict__ wsg, float* __restrict__ firl,
    float* __restrict__ firs,
    const float* __restrict__ mlpw1, ushort_t* __restrict__ w1_t,
    const float* __restrict__ Wo, ushort_t* __restrict__ wo_t,
    ushort_t* __restrict__ gin)
{
  __shared__ __attribute__((aligned(16))) char smem[72704];
  int t = threadIdx.x;

  if (blockIdx.x >= 2176) {
    // -------- input-only weight transposes on idle CUs --------
    ushort_t (*tile)[33] = (ushort_t(*)[33])smem;
    const float* W; ushort_t* out; int Kq, Nq, n0, k0;
    if (blockIdx.x < 4288) {          // mlpw1 [1056][2048] -> w1_t [2048][1056]
      int local = blockIdx.x - 2176;  // 64 x 33
      W = mlpw1; out = w1_t; Kq = 1056; Nq = 2048;
      n0 = (local & 63) * 32; k0 = (local >> 6) * 32;
    } else {                          // Wo [1024][1024] -> wo_t [1024][1024]
      int local = blockIdx.x - 4288;  // 32 x 32
      W = Wo; out = wo_t; Kq = 1024; Nq = 1024;
      n0 = (local & 31) * 32; k0 = (local >> 5) * 32;
    }
    int tx = t & 31, ty = t >> 5;
#pragma unroll
    for (int r = 0; r < 32; r += 8)
      tile[ty + r][tx] = f2bf(W[(size_t)(k0 + ty + r) * Nq + n0 + tx]);
    __syncthreads();
#pragma unroll
    for (int r = 0; r < 32; r += 8)
      out[(size_t)(n0 + ty + r) * Kq + k0 + tx] = tile[tx][ty + r];
    return;
  }

  if (blockIdx.x >= 128) {
    // ---------------- FIR part + firs/firl stats ----------------
    float (*vt)[71] = (float(*)[71])smem;
    int bid = blockIdx.x - 128;
    int lt = bid & 255;
    int bh = bid >> 8;
    int b = bh >> 2, h = bh & 3;
    int l0 = lt * 8;
    const float* vp = v + (size_t)bh * Ls * 256;
    for (int r = 0; r < 70; ++r) {
      int ls = l0 - 62 + r;
      vt[t][r] = (ls >= 0) ? vp[(size_t)ls * 256 + t] : 0.f;
    }
    float TL[63], TS3[3];
#pragma unroll
    for (int j = 0; j < 63; ++j) TL[j] = wlg[((size_t)h * 256 + t) * 63 + j];
#pragma unroll
    for (int j = 0; j < 3; ++j) TS3[j] = wsg[((size_t)h * 256 + t) * 3 + j];
    __syncthreads();
    float aL[8] = {0,0,0,0,0,0,0,0}, aS[8] = {0,0,0,0,0,0,0,0};
#pragma unroll
    for (int r = 0; r < 70; ++r) {
      float vm = vt[t][r];
#pragma unroll
      for (int p = 0; p < 8; ++p) {
        int jl = r - p;
        if (jl >= 0 && jl < 63) aL[p] = fmaf(vm, TL[jl], aL[p]);
        int jssrc = r - 60 - p;
        if (jssrc >= 0 && jssrc < 3) aS[p] = fmaf(vm, TS3[jssrc], aS[p]);
      }
    }
#pragma unroll
    for (int p = 0; p < 8; ++p) {
      int l = l0 + p;
      size_t ob = (((size_t)b * Ls + l) * NH + h) * 256 + t;
      firl[ob] = aL[p];
      firs[ob] = aS[p];
    }
    // ---- producer-side stats (values in regs; vt dead -> reuse smem) ----
    __syncthreads();
    float (*red)[8][2][2] = (float(*)[8][2][2])smem;  // [wave][p][br][moment]
    int wv_ = t >> 6, lane_ = t & 63;
#pragma unroll
    for (int p = 0; p < 8; ++p) {
      float sS = aS[p], s2S = aS[p] * aS[p];
      float sL = aL[p], s2L = aL[p] * aL[p];
#pragma unroll
      for (int off = 32; off; off >>= 1) {
        sS += __shfl_down(sS, off);   s2S += __shfl_down(s2S, off);
        sL += __shfl_down(sL, off);   s2L += __shfl_down(s2L, off);
      }
      if (lane_ == 0) {
        red[wv_][p][0][0] = sS; red[wv_][p][0][1] = s2S;
        red[wv_][p][1][0] = sL; red[wv_][p][1][1] = s2L;
      }
    }
    __syncthreads();
    if (t < 16) {
      int p = t >> 1, br = t & 1;    // br0 = firs, br1 = firl
      float s = red[0][p][br][0] + red[1][p][br][0]
              + red[2][p][br][0] + red[3][p][br][0];
      float s2 = red[0][p][br][1] + red[1][p][br][1]
               + red[2][p][br][1] + red[3][p][br][1];
      float mean = s * (1.f / 256.f);
      float var = s2 * (1.f / 256.f) - mean * mean;
      int l = l0 + p;
      size_t gb = (size_t)(b * Ls + l) * 1056 + 1024 + br * 8;
      gin[gb + h] = f2bf(mean);
      gin[gb + 4 + h] = f2bf(sqrtf(fmaxf(var, 1e-6f)));
    }
    return;
  }

  // ---------------- chain part (m=2 super-chunks) ----------------
  ushort_t (*Shi)[264] = (ushort_t(*)[264])(smem);
  ushort_t (*Slo)[264] = (ushort_t(*)[264])(smem + 8448);
  float (*u2L0)[17] = (float(*)[17])(smem + 16896);
  float (*u2L1)[17] = (float(*)[17])(smem + 19072);
  int bh = blockIdx.x & 7, g = blockIdx.x >> 3;
  int b = bh >> 2, h = bh & 3;
  int wv = t >> 6, lane = t & 63;
  int lquad = lane >> 4, l16 = lane & 15;
  int j0 = g * 16;
  int Mt = wv & 1;
  bool isU = (wv < 2);
  const ushort_t* wp = wn_bf + (size_t)bh * Ls * 256;
  const ushort_t* qp = q_bf  + (size_t)bh * Ls * 256;
  const ushort_t* ap = (isU ? wp : qp) + (size_t)(Mt * 16 + l16) * 256;
  const ushort_t* kr = knT_bf + (size_t)bh * Ls * 256 + (size_t)l16 * 32 + lquad * 8;
  const float* urow = u_g + (size_t)bh * Ls * 256
                    + (size_t)(Mt * 16 + lquad * 4) * 256 + j0 + l16;
  const float* arp = attn_g + (size_t)bh * 64 * 1024
                   + (size_t)(Mt * 16 + l16) * 32 + lquad * 8;
  const float* xrp = (isU ? X_g : Y_g) + (size_t)bh * 32768
                   + (size_t)(Mt * 16 + l16) * 32 + lquad * 8;

  floatx4 Sacc[4], SaccL[4];
#pragma unroll
  for (int i = 0; i < 4; ++i)
#pragma unroll
    for (int r = 0; r < 4; ++r) { Sacc[i][r] = 0.f; SaccL[i][r] = 0.f; }
  for (int i = t; i < 4224; i += 256) ((u32*)smem)[i] = 0;

  // prologue: super-chunk 0, sub-chunk 0 operands
  short8 a0[8], k0[4];
  floatx4 u0 = {0.f, 0.f, 0.f, 0.f};
  float4 at0a = {0,0,0,0}, at0b = {0,0,0,0};
#pragma unroll
  for (int ks = 0; ks < 8; ++ks)
    a0[ks] = *(const short8*)(ap + ks * 32 + lquad * 8);
#pragma unroll
  for (int i = 0; i < 4; ++i)
    k0[i] = *(const short8*)(kr + (size_t)(wv * 4 + i) * 512);
  if (isU) {
#pragma unroll
    for (int r = 0; r < 4; ++r) u0[r] = urow[(size_t)r * 256];
  } else {
    at0a = *(const float4*)(arp);
    at0b = *(const float4*)(arp + 4);
  }
  wave_barrier();

  for (int sc = 0; sc < 32; ++sc) {
    size_t cb1 = (size_t)sc * 16384 + 8192;
    size_t nb0 = (size_t)(sc + 1) * 16384;
    bool hasN = (sc + 1 < 32);

    // sub-chunk1 operands + cross matrix (used mid-iteration; latency covered)
    short8 a1[8], k1[4];
    floatx4 u1 = {0.f, 0.f, 0.f, 0.f};
    float4 at1a = {0,0,0,0}, at1b = {0,0,0,0};
#pragma unroll
    for (int ks = 0; ks < 8; ++ks)
      a1[ks] = *(const short8*)(ap + cb1 + ks * 32 + lquad * 8);
#pragma unroll
    for (int i = 0; i < 4; ++i)
      k1[i] = *(const short8*)(kr + cb1 + (size_t)(wv * 4 + i) * 512);
    if (isU) {
#pragma unroll
      for (int r = 0; r < 4; ++r) u1[r] = urow[cb1 + (size_t)r * 256];
    } else {
      size_t na = (size_t)(2 * sc + 1) * 1024;
      at1a = *(const float4*)(arp + na);
      at1b = *(const float4*)(arp + na + 4);
    }
    float4 xa = *(const float4*)(xrp + (size_t)sc * 1024);
    float4 xb = *(const float4*)(xrp + (size_t)sc * 1024 + 4);

    // ---- sub-chunk 0: u2_0 (isU) / po_0 (o) against S0 ----
    floatx4 acc0;
    if (isU) {
      floatx4 A0 = u0, A1 = {0,0,0,0}, A2 = {0,0,0,0}, A3 = {0,0,0,0};
#pragma unroll
      for (int ks = 0; ks < 8; ++ks) {
        short8 sh = *(const short8*)&Shi[l16][ks * 32 + lquad * 8];
        short8 sl = *(const short8*)&Slo[l16][ks * 32 + lquad * 8];
        if (ks & 1) {
          A1 = __builtin_amdgcn_mfma_f32_16x16x32_bf16(a0[ks], sh, A1, 0, 0, 0);
          A3 = __builtin_amdgcn_mfma_f32_16x16x32_bf16(a0[ks], sl, A3, 0, 0, 0);
        } else {
          A0 = __builtin_amdgcn_mfma_f32_16x16x32_bf16(a0[ks], sh, A0, 0, 0, 0);
          A2 = __builtin_amdgcn_mfma_f32_16x16x32_bf16(a0[ks], sl, A2, 0, 0, 0);
        }
      }
#pragma unroll
      for (int r = 0; r < 4; ++r) acc0[r] = (A0[r] + A1[r]) + (A2[r] + A3[r]);
#pragma unroll
      for (int r = 0; r < 4; ++r)
        u2L0[Mt * 16 + lquad * 4 + r][l16] = acc0[r];
    } else {
      floatx4 A0 = {0,0,0,0}, A1 = {0,0,0,0};
#pragma unroll
      for (int ks = 0; ks < 8; ++ks) {
        short8 sh = *(const short8*)&Shi[l16][ks * 32 + lquad * 8];
        if (ks & 1) A1 = __builtin_amdgcn_mfma_f32_16x16x32_bf16(a0[ks], sh, A1, 0, 0, 0);
        else        A0 = __builtin_amdgcn_mfma_f32_16x16x32_bf16(a0[ks], sh, A0, 0, 0, 0);
      }
#pragma unroll
      for (int r = 0; r < 4; ++r) acc0[r] = A0[r] + A1[r];
    }
    // prefetch next-super-chunk a0 (a0 regs dead; stays in flight across
    // the raw barriers below -> ~full iteration of latency cover)
    if (hasN) {
#pragma unroll
      for (int ks = 0; ks < 8; ++ks)
        a0[ks] = *(const short8*)(ap + nb0 + ks * 32 + lquad * 8);
    }
    wave_barrier();                          // u2_0 visible

    short8 uh0, ul0;
#pragma unroll
    for (int j = 0; j < 8; ++j) {
      float f = u2L0[lquad * 8 + j][l16];
      ushort_t hi = f2bf(f);
      uh0[j] = (short)hi;
      ul0[j] = (short)f2bf(f - bf2f(hi));
    }
#pragma unroll
    for (int i = 0; i < 4; ++i) {
      Sacc[i]  = __builtin_amdgcn_mfma_f32_16x16x32_bf16(k0[i], uh0, Sacc[i], 0, 0, 0);
      SaccL[i] = __builtin_amdgcn_mfma_f32_16x16x32_bf16(k0[i], ul0, SaccL[i], 0, 0, 0);
    }
    if (hasN) {
#pragma unroll
      for (int i = 0; i < 4; ++i)
        k0[i] = *(const short8*)(kr + nb0 + (size_t)(wv * 4 + i) * 512);
    }

    // ---- sub-chunk 1: u2_1 = u1 + wn1@S0 + X@u2_0 / o path ----
    floatx4 acc1;
    if (isU) {
      floatx4 A0 = u1, A1 = {0,0,0,0}, A2 = {0,0,0,0}, A3 = {0,0,0,0};
#pragma unroll
      for (int ks = 0; ks < 8; ++ks) {
        short8 sh = *(const short8*)&Shi[l16][ks * 32 + lquad * 8];
        short8 sl = *(const short8*)&Slo[l16][ks * 32 + lquad * 8];
        if (ks & 1) {
          A1 = __builtin_amdgcn_mfma_f32_16x16x32_bf16(a1[ks], sh, A1, 0, 0, 0);
          A3 = __builtin_amdgcn_mfma_f32_16x16x32_bf16(a1[ks], sl, A3, 0, 0, 0);
        } else {
          A0 = __builtin_amdgcn_mfma_f32_16x16x32_bf16(a1[ks], sh, A0, 0, 0, 0);
          A2 = __builtin_amdgcn_mfma_f32_16x16x32_bf16(a1[ks], sl, A2, 0, 0, 0);
        }
      }
      short8 Xh, Xl;
      cvt8(xa, xb, Xh, Xl);
      A0 = __builtin_amdgcn_mfma_f32_16x16x32_bf16(Xh, uh0, A0, 0, 0, 0);
      A1 = __builtin_amdgcn_mfma_f32_16x16x32_bf16(Xh, ul0, A1, 0, 0, 0);
      A2 = __builtin_amdgcn_mfma_f32_16x16x32_bf16(Xl, uh0, A2, 0, 0, 0);
#pragma unroll
      for (int r = 0; r < 4; ++r) acc1[r] = (A0[r] + A1[r]) + (A2[r] + A3[r]);
#pragma unroll
      for (int r = 0; r < 4; ++r)
        u2L1[Mt * 16 + lquad * 4 + r][l16] = acc1[r];
      if (hasN) {
#pragma unroll
        for (int r = 0; r < 4; ++r) u0[r] = urow[nb0 + (size_t)r * 256];
      }
    } else {
      // o_0 = po_0 + attn_0 @ u2_0 -> store
      short8 ath, atl;
      cvt8(at0a, at0b, ath, atl);
      acc0 = __builtin_amdgcn_mfma_f32_16x16x32_bf16(ath, uh0, acc0, 0, 0, 0);
      acc0 = __builtin_amdgcn_mfma_f32_16x16x32_bf16(ath, ul0, acc0, 0, 0, 0);
      acc0 = __builtin_amdgcn_mfma_f32_16x16x32_bf16(atl, uh0, acc0, 0, 0, 0);
#pragma unroll
      for (int r = 0; r < 4; ++r) {
        int l = sc * 64 + Mt * 16 + lquad * 4 + r;
        delta_g[(((size_t)b * Ls + l) * NH + h) * 256 + j0 + l16] = acc0[r];
      }
      // po_1 = q1 @ Shi(S0) + Y @ u2_0
      floatx4 A0 = {0,0,0,0}, A1 = {0,0,0,0};
#pragma unroll
      for (int ks = 0; ks < 8; ++ks) {
        short8 sh = *(const short8*)&Shi[l16][ks * 32 + lquad * 8];
        if (ks & 1) A1 = __builtin_amdgcn_mfma_f32_16x16x32_bf16(a1[ks], sh, A1, 0, 0, 0);
        else        A0 = __builtin_amdgcn_mfma_f32_16x16x32_bf16(a1[ks], sh, A0, 0, 0, 0);
      }
      short8 Yh, Yl;
      cvt8(xa, xb, Yh, Yl);
      A0 = __builtin_amdgcn_mfma_f32_16x16x32_bf16(Yh, uh0, A0, 0, 0, 0);
      A1 = __builtin_amdgcn_mfma_f32_16x16x32_bf16(Yh, ul0, A1, 0, 0, 0);
      A0 = __builtin_amdgcn_mfma_f32_16x16x32_bf16(Yl, uh0, A0, 0, 0, 0);
#pragma unroll
      for (int r = 0; r < 4; ++r) acc1[r] = A0[r] + A1[r];
      if (hasN) {
        size_t na0 = (size_t)(2 * sc + 2) * 1024;
        at0a = *(const float4*)(arp + na0);
        at0b = *(const float4*)(arp + na0 + 4);
      }
    }
    wave_barrier();                          // u2_1 visible; all Shi/Slo reads done

    short8 uh1, ul1;
#pragma unroll
    for (int j = 0; j < 8; ++j) {
      float f = u2L1[lquad * 8 + j][l16];
      ushort_t hi = f2bf(f);
      uh1[j] = (short)hi;
      ul1[j] = (short)f2bf(f - bf2f(hi));
    }
#pragma unroll
    for (int i = 0; i < 4; ++i) {
      Sacc[i]  = __builtin_amdgcn_mfma_f32_16x16x32_bf16(k1[i], uh1, Sacc[i], 0, 0, 0);
      SaccL[i] = __builtin_amdgcn_mfma_f32_16x16x32_bf16(k1[i], ul1, SaccL[i], 0, 0, 0);
    }
    if (!isU) {
      short8 ath, atl;
      cvt8(at1a, at1b, ath, atl);
      acc1 = __builtin_amdgcn_mfma_f32_16x16x32_bf16(ath, uh1, acc1, 0, 0, 0);
      acc1 = __builtin_amdgcn_mfma_f32_16x16x32_bf16(ath, ul1, acc1, 0, 0, 0);
      acc1 = __builtin_amdgcn_mfma_f32_16x16x32_bf16(atl, uh1, acc1, 0, 0, 0);
#pragma unroll
      for (int r = 0; r < 4; ++r) {
        int l = sc * 64 + 32 + Mt * 16 + lquad * 4 + r;
        delta_g[(((size_t)b * Ls + l) * NH + h) * 256 + j0 + l16] = acc1[r];
      }
    }
    // S write-back (once per 64 tokens)
#pragma unroll
    for (int i = 0; i < 4; ++i) {
      int dk0 = (wv * 4 + i) * 16 + lquad * 4;
      ushort4 h4, l4;
      ushort_t* hp = (ushort_t*)&h4;
      ushort_t* lp = (ushort_t*)&l4;
#pragma unroll
      for (int r = 0; r < 4; ++r) {
        float sv = Sacc[i][r] + SaccL[i][r];
        ushort_t hi = f2bf(sv);
        hp[r] = hi;
        lp[r] = f2bf(sv - bf2f(hi));
      }
      *(ushort4*)&Shi[l16][dk0] = h4;
      *(ushort4*)&Slo[l16][dk0] = l4;
    }
    wave_barrier();                          // S visible
  }
}

// ------- gate_in: delta stats only -----------------------------------------
__global__ __launch_bounds__(256) void build_gate_in_bf(
    const float* __restrict__ delta, ushort_t* __restrict__ gin)
{
  int mtok = blockIdx.x, t = threadIdx.x;
  int w = t >> 6, lane = t & 63;
  float s = 0.f, s2 = 0.f;
#pragma unroll
  for (int r = 0; r < 4; ++r) {
    int d = lane + r * 64;
    float val = delta[(size_t)mtok * 1024 + w * 256 + d];
    s += val; s2 = fmaf(val, val, s2);
  }
#pragma unroll
  for (int off = 32; off; off >>= 1) {
    s += __shfl_down(s, off);
    s2 += __shfl_down(s2, off);
  }
  if (lane == 0) {
    float mean = s * (1.f / 256.f);
    float var = s2 * (1.f / 256.f) - mean * mean;
    gin[(size_t)mtok * 1056 + 1040 + w] = f2bf(mean);
    gin[(size_t)mtok * 1056 + 1044 + w] = f2bf(sqrtf(fmaxf(var, 1e-6f)));
  }
}

// ------- logits -> gates (bf16 hidden input) -------------------------------
__global__ __launch_bounds__(256) void mlp2_gates(
    const ushort_t* __restrict__ mh, const float* __restrict__ W2,
    const float* __restrict__ b2, const float* __restrict__ glt,
    float* __restrict__ gates)
{
  int mtok = blockIdx.x, t = threadIdx.x;
  float p[16];
#pragma unroll
  for (int j = 0; j < 16; ++j) p[j] = 0.f;
  for (int k = t; k < 2048; k += 256) {
    float hv = bf2f(mh[(size_t)mtok * 2048 + k]);
    const float* wr = W2 + (size_t)k * 16;
#pragma unroll
    for (int j4 = 0; j4 < 4; ++j4) {
      float4 w4 = *(const float4*)(wr + j4 * 4);
      p[j4*4+0] = fmaf(hv, w4.x, p[j4*4+0]);
      p[j4*4+1] = fmaf(hv, w4.y, p[j4*4+1]);
      p[j4*4+2] = fmaf(hv, w4.z, p[j4*4+2]);
      p[j4*4+3] = fmaf(hv, w4.w, p[j4*4+3]);
    }
  }
#pragma unroll
  for (int j = 0; j < 16; ++j)
#pragma unroll
    for (int off = 32; off; off >>= 1) p[j] += __shfl_down(p[j], off);
  __shared__ float red[4][16];
  __shared__ float zl[16];
  int w = t >> 6;
  if ((t & 63) == 0) {
#pragma unroll
    for (int j = 0; j < 16; ++j) red[w][j] = p[j];
  }
  __syncthreads();
  if (t < 16) {
    float tot = red[0][t] + red[1][t] + red[2][t] + red[3][t] + b2[t];
    float tempv = log1pf(expf(glt[t >> 2])) + 1e-4f;
    zl[t] = tot / tempv;
  }
  __syncthreads();
  if (t < 4) {
    float z0 = zl[t*4], z1 = zl[t*4+1], z2 = zl[t*4+2], z3 = zl[t*4+3];
    float mx = fmaxf(fmaxf(z0, z1), fmaxf(z2, z3));
    float e0 = expf(z0 - mx), e1 = expf(z1 - mx), e2 = expf(z2 - mx), e3 = expf(z3 - mx);
    float inv = 1.f / (e0 + e1 + e2 + e3);
    gates[(size_t)mtok * 16 + t * 4 + 0] = e0 * inv;
    gates[(size_t)mtok * 16 + t * 4 + 1] = e1 * inv;
    gates[(size_t)mtok * 16 + t * 4 + 2] = e2 * inv;
    gates[(size_t)mtok * 16 + t * 4 + 3] = e3 * inv;
  }
}

// ------- o = gated mix, RMSNorm -> bf16 ------------------------------------
__global__ __launch_bounds__(256) void combine_norm_bf(
    const float* __restrict__ firs, const float* __restrict__ firl,
    const float* __restrict__ delta, const float* __restrict__ v,
    const float* __restrict__ gates, const float* __restrict__ onw,
    ushort_t* __restrict__ o)
{
  int mh = blockIdx.x;
  int mtok = mh >> 2, h = mh & 3;
  int t = threadIdx.x;
  int b = mtok >> 11, l = mtok & 2047;
  const float* g = gates + (size_t)mtok * 16 + h * 4;
  float w0 = g[0], w1 = g[1], w2 = g[2], w3 = g[3];
  size_t tb = (size_t)mtok * 1024 + h * 256 + t;
  float val = w0 * firs[tb] + w1 * firl[tb] + w2 * delta[tb]
            + w3 * v[(((size_t)(b * NH + h)) * Ls + l) * 256 + t];
  float s2 = val * val;
#pragma unroll
  for (int off = 32; off; off >>= 1) s2 += __shfl_down(s2, off);
  __shared__ float r4[4];
  if ((t & 63) == 0) r4[t >> 6] = s2;
  __syncthreads();
  float tot = r4[0] + r4[1] + r4[2] + r4[3];
  float rms = rsqrtf(tot * (1.f / 256.f) + 1e-5f);
  o[tb] = f2bf(val * rms * onw[t]);
}

// ---------------------------------------------------------------------------
extern "C" void kernel_launch(void* const* d_in, const int* in_sizes, int n_in,
                              void* d_out, int out_size, void* d_ws, size_t ws_size,
                              hipStream_t stream) {
  const float* x     = (const float*)d_in[0];
  const float* Wq    = (const float*)d_in[1];
  const float* Wk    = (const float*)d_in[2];
  const float* Wv    = (const float*)d_in[3];
  const float* Wb    = (const float*)d_in[4];
  const float* convq = (const float*)d_in[5];
  const float* convk = (const float*)d_in[6];
  const float* convv = (const float*)d_in[7];
  const float* firsw = (const float*)d_in[8];
  const float* firlw = (const float*)d_in[9];
  const float* mlpw1 = (const float*)d_in[10];
  const float* mlpb1 = (const float*)d_in[11];
  const float* mlpw2 = (const float*)d_in[12];
  const float* mlpb2 = (const float*)d_in[13];
  const float* glt   = (const float*)d_in[14];
  const float* onw   = (const float*)d_in[15];
  const float* Wo    = (const float*)d_in[16];
  float* ws = (float*)d_ws;

  ushort_t* x_bf   = (ushort_t*)(ws + off_firs);
  ushort_t* Wqkv_t = (ushort_t*)(ws + off_firl);  // 3 x [1024][1024] contiguous
  ushort_t* gin_bf = (ushort_t*)(ws + off_gin2);  // never-aliased window
  ushort_t* w1_t   = (ushort_t*)(ws + off_k);     // kn dead after chunk_prep
  ushort_t* o_bf   = (ushort_t*)(ws + off_xv);
  ushort_t* Wo_t   = (ushort_t*)(ws + off_wot);   // never-aliased window
  ushort_t* mlph_bf= (ushort_t*)(ws + off_mlph);
  ushort_t* wn_bf  = (ushort_t*)(ws + off_firs);
  ushort_t* q_bf   = (ushort_t*)(ws + off_firs + 2097152);
  ushort_t* knT_bf = (ushort_t*)(ws + off_firl);
  ushort_t* kn_bf  = (ushort_t*)(ws + off_xq);    // x3 dead after conv_prep
  float* x3   = ws + off_xq;     // fused [4096][3072] spans xq/xk/xv
  float* kb_f = ws + off_gin;
  float* vb_f = ws + off_mlph;
  float* X_g  = ws + off_gin;            // kb dead after chunk_prep; 8*32*1024 f32
  float* Y_g  = ws + off_gin + 262144;
  float* firs_f = ws + off_xq;   // x3/kn_bf dead after cross_prep
  float* firl_f = ws + off_xk;

  dim3 blk(256);
  // fused q/k/v projection (one N=3072 GEMM) + beta; x->bf16 dual-writes gin
  to_bf16<<<2048, blk, 0, stream>>>(x, x_bf, gin_bf, 4194304);
  convT<<<dim3(32, 32), blk, 0, stream>>>(Wq, Wqkv_t, 1024, 1024);
  convT<<<dim3(32, 32), blk, 0, stream>>>(Wk, Wqkv_t + 1048576, 1024, 1024);
  convT<<<dim3(32, 32), blk, 0, stream>>>(Wv, Wqkv_t + 2097152, 1024, 1024);
  gemm_bf16<<<dim3(24, 32), blk, 0, stream>>>(x_bf, Wqkv_t, x3, 3072, 1024, nullptr, 0, 0);
  beta_sigmoid<<<4096, blk, 0, stream>>>(x, Wb, ws + off_beta);
  // fused conv4+silu + l2norm + beta products + v-stats (producer-side)
  conv_prep<<<16384, blk, 0, stream>>>(x3, convq, convk, convv, ws + off_beta,
                                       ws + off_q, ws + off_k, kb_f, vb_f,
                                       ws + off_v, gin_bf);
  // per-chunk T inverse, attn, u (->xv), bf16 {-w, q, knT, kn}
  chunk_prep<<<512, blk, 0, stream>>>(kb_f, ws + off_k, ws + off_q, vb_f,
                                      ws + off_attn, ws + off_xv, wn_bf, q_bf,
                                      knT_bf, kn_bf);
  // 32x32 cross matrices per super-chunk (X = wn1 kn0^T, Y = q1 kn0^T)
  cross_prep<<<256, blk, 0, stream>>>(wn_bf, q_bf, kn_bf, X_g, Y_g);
  // merged: chain + FIR(+firs/firl stats) + weight transposes (shadow)
  delta_fir<<<5312, blk, 0, stream>>>(wn_bf, q_bf, knT_bf, ws + off_attn,
                                      ws + off_xv, X_g, Y_g, ws + off_q,
                                      ws + off_v, firlw, firsw, firl_f, firs_f,
                                      mlpw1, w1_t, Wo, Wo_t, gin_bf);
  // gate input: delta stats only (x copy + firs/firl/v stats done upstream)
  build_gate_in_bf<<<4096, blk, 0, stream>>>(ws + off_q, gin_bf);
  gemm_bf16<<<dim3(16, 32), blk, 0, stream>>>(gin_bf, w1_t, (float*)mlph_bf,
                                              2048, 1056, mlpb1, 1, 1);
  mlp2_gates<<<4096, blk, 0, stream>>>(mlph_bf, mlpw2, mlpb2, glt, ws + off_gates);
  // combine + RMSNorm -> bf16, output projection (MFMA)
  combine_norm_bf<<<16384, blk, 0, stream>>>(firs_f, firl_f, ws + off_q,
                                             ws + off_v, ws + off_gates, onw, o_bf);
  gemm_bf16<<<dim3(8, 32), blk, 0, stream>>>(o_bf, Wo_t, (float*)d_out, 1024, 1024, nullptr, 0, 0);
}